// Round 9
// baseline (641.475 us; speedup 1.0000x reference)
//
#include <hip/hip_runtime.h>
#include <hip/hip_bf16.h>

#define DEV __device__ __forceinline__

namespace {

constexpr int cB = 2, cT = 8, cH = 32, cW = 32, cC = 192;
constexpr int cDI = 384, cN = 16, cK = 4, cDTR = 12, cLT = 77, cHID = 768;
constexpr int cL  = cT * cH * cW;      // 8192
constexpr int cBL = cB * cL;           // 16384
constexpr int SEG = 128, SEGLEN = cL / SEG;   // 128 segments x 64 steps
constexpr int XROW = cDTR + 2 * cN;    // 44 live cols
constexpr int XSTR = 48;               // padded row stride (float4-aligned)

typedef __attribute__((ext_vector_type(8))) short bf16x8;
typedef __attribute__((ext_vector_type(4))) float f32x4;
typedef __attribute__((ext_vector_type(4))) short short4v;

// ---------- scalar helpers ----------
DEV float bfu2f(unsigned short u) { return __uint_as_float(((unsigned)u) << 16); }
DEV float ldsel(const void* p, size_t i, int f32) {
  return f32 ? ((const float*)p)[i] : bfu2f(((const unsigned short*)p)[i]);
}
template <int F32>
DEV float4 ld4(const void* p, size_t e) {   // e: element index, multiple of 4
  if (F32) return *(const float4*)((const float*)p + e);
  ushort4 u = *(const ushort4*)((const unsigned short*)p + e);
  return make_float4(bfu2f(u.x), bfu2f(u.y), bfu2f(u.z), bfu2f(u.w));
}
DEV short f2bf(float f) {   // RNE float->bf16 bits
  unsigned u = __float_as_uint(f);
  u += 0x7fffu + ((u >> 16) & 1u);
  return (short)(u >> 16);
}
DEV float siluf(float x) { return x / (1.f + __expf(-x)); }
DEV float softplusf(float x) { return (x > 20.f) ? x : __logf(1.f + __expf(x)); }
DEV float gelut(float x) {            // tanh-approx gelu (JAX default)
  float u = 0.7978845608028654f * (x + 0.044715f * x * x * x);
  float e = __expf(2.f * u);
  float th = 1.f - 2.f / (e + 1.f);
  return 0.5f * x * (1.f + th);
}

// power tree: pw[n] = a1^(n+1), depth 4
DEV void pow16(float a1, float (&pw)[cN]) {
  float a2 = a1*a1, a3 = a2*a1, a4 = a2*a2;
  float a5 = a4*a1, a6 = a4*a2, a7 = a4*a3, a8 = a4*a4;
  pw[0]=a1; pw[1]=a2; pw[2]=a3; pw[3]=a4; pw[4]=a5; pw[5]=a6; pw[6]=a7; pw[7]=a8;
  pw[8]=a8*a1; pw[9]=a8*a2; pw[10]=a8*a3; pw[11]=a8*a4;
  pw[12]=a8*a5; pw[13]=a8*a6; pw[14]=a8*a7; pw[15]=a8*a8;
}

template <int BS>
DEV void blkreduce2(float& a, float& b) {
  __shared__ float ra[BS], rb[BS];
  int t = threadIdx.x;
  ra[t] = a; rb[t] = b; __syncthreads();
#pragma unroll
  for (int s = BS / 2; s > 0; s >>= 1) {
    if (t < s) { ra[t] += ra[t + s]; rb[t] += rb[t + s]; }
    __syncthreads();
  }
  a = ra[0]; b = rb[0];
  __syncthreads();
}

// ---------- dtype detector (validated: inputs are fp32) ----------
__global__ void __launch_bounds__(256) detect_kernel(
    const unsigned short* __restrict__ xa, const unsigned short* __restrict__ wp,
    int* __restrict__ flg) {
  __shared__ int cnt[2];
  if (threadIdx.x < 2) cnt[threadIdx.x] = 0;
  __syncthreads();
  int l0 = 0, l1 = 0;
  for (int i = threadIdx.x; i < 1024; i += 256) {
    float v = bfu2f(xa[2 * i]); float a = fabsf(v);
    if (v == 0.f || (a > 1e-8f && a < 1e4f)) l0++;
    float u = bfu2f(wp[2 * i]); float bq = fabsf(u);
    if (u == 0.f || (bq > 1e-8f && bq < 1e4f)) l1++;
  }
  atomicAdd(&cnt[0], l0); atomicAdd(&cnt[1], l1);
  __syncthreads();
  if (threadIdx.x == 0) {
    flg[0] = (cnt[0] < 614) ? 1 : 0;
    flg[1] = (cnt[1] < 614) ? 1 : 0;
    flg[2] = 1;
  }
}

// ---------- conv weight prep: transpose [Ch][27] -> [27][Ch] fp32, decode biases ----------
__global__ void __launch_bounds__(256) prep_kernel(
    const void* __restrict__ cvw, const void* __restrict__ cvb,
    const void* __restrict__ c1w, const void* __restrict__ c1b,
    const void* __restrict__ c2w, const void* __restrict__ c2b,
    const int* __restrict__ flg,
    float* __restrict__ wcv, float* __restrict__ bcv,
    float* __restrict__ w1, float* __restrict__ b1,
    float* __restrict__ w2, float* __restrict__ b2) {
  int pf = flg[1];
  int i = blockIdx.x * 256 + threadIdx.x;
  int r = i;
  if (r < 27 * cDI) { int j = r / cDI, d = r % cDI; wcv[r] = ldsel(cvw, (size_t)d * 27 + j, pf); return; }
  r -= 27 * cDI;
  if (r < cDI) { bcv[r] = ldsel(cvb, r, pf); return; }
  r -= cDI;
  if (r < 27 * cC) { int j = r / cC, c = r % cC; w1[r] = ldsel(c1w, (size_t)c * 27 + j, pf); return; }
  r -= 27 * cC;
  if (r < cC) { b1[r] = ldsel(c1b, r, pf); return; }
  r -= cC;
  if (r < 27 * cC) { int j = r / cC, c = r % cC; w2[r] = ldsel(c2w, (size_t)c * 27 + j, pf); return; }
  r -= 27 * cC;
  if (r < cC) { b2[r] = ldsel(c2b, r, pf); return; }
}

// ---------- CPE (depthwise 3x3x3 + residual), 4-channel vectorized ----------
template <int F32>
DEV void cpe_body(const void* __restrict__ xin, const float* __restrict__ wT,
                  const float* __restrict__ bs, int idx, float* __restrict__ out) {
  int c = (idx % (cC / 4)) * 4; int bv = idx / (cC / 4);
  int v = bv & (cL - 1); int b = bv >> 13;
  int t = v >> 10, q = v & 1023, h = q >> 5, w = q & 31;
  float4 acc = *(const float4*)(bs + c);
#pragma unroll
  for (int dz = 0; dz < 3; ++dz) {
    int tt = t + dz - 1; if ((unsigned)tt >= (unsigned)cT) continue;
#pragma unroll
    for (int dy = 0; dy < 3; ++dy) {
      int hh = h + dy - 1; if ((unsigned)hh >= (unsigned)cH) continue;
#pragma unroll
      for (int dx = 0; dx < 3; ++dx) {
        int ww = w + dx - 1; if ((unsigned)ww >= (unsigned)cW) continue;
        int vv = (tt << 10) + (hh << 5) + ww;
        float4 wv = *(const float4*)(wT + (dz * 9 + dy * 3 + dx) * cC + c);
        float4 xv = ld4<F32>(xin, ((size_t)b * cL + vv) * cC + c);
        acc.x += wv.x * xv.x; acc.y += wv.y * xv.y;
        acc.z += wv.z * xv.z; acc.w += wv.w * xv.w;
      }
    }
  }
  float4 x0 = ld4<F32>(xin, (size_t)bv * cC + c);
  float4 o = make_float4(x0.x + acc.x, x0.y + acc.y, x0.z + acc.z, x0.w + acc.w);
  *(float4*)(out + (size_t)bv * cC + c) = o;
}

__global__ void __launch_bounds__(256) cpe_kernel(
    const void* __restrict__ xin, const float* __restrict__ wT,
    const float* __restrict__ bs, const int* __restrict__ flg, int afidx,
    float* __restrict__ out) {
  int idx = blockIdx.x * 256 + threadIdx.x;
  if (idx >= cBL * cC / 4) return;
  if (flg[afidx]) cpe_body<1>(xin, wT, bs, idx, out);
  else            cpe_body<0>(xin, wT, bs, idx, out);
}

// ---------- depthwise conv on DI + SiLU: bf16 in -> bf16 out ----------
__global__ void __launch_bounds__(256) dwconv_silu_kernel(
    const unsigned short* __restrict__ xin, const float* __restrict__ wT,
    const float* __restrict__ bs, unsigned short* __restrict__ out) {
  int idx = blockIdx.x * 256 + threadIdx.x;
  if (idx >= cBL * cDI / 4) return;
  int d = (idx % (cDI / 4)) * 4; int bv = idx / (cDI / 4);
  int v = bv & (cL - 1); int b = bv >> 13;
  int t = v >> 10, q = v & 1023, h = q >> 5, w = q & 31;
  float4 acc = *(const float4*)(bs + d);
#pragma unroll
  for (int dz = 0; dz < 3; ++dz) {
    int tt = t + dz - 1; if ((unsigned)tt >= (unsigned)cT) continue;
#pragma unroll
    for (int dy = 0; dy < 3; ++dy) {
      int hh = h + dy - 1; if ((unsigned)hh >= (unsigned)cH) continue;
#pragma unroll
      for (int dx = 0; dx < 3; ++dx) {
        int ww = w + dx - 1; if ((unsigned)ww >= (unsigned)cW) continue;
        int vv = (tt << 10) + (hh << 5) + ww;
        float4 wv = *(const float4*)(wT + (dz * 9 + dy * 3 + dx) * cDI + d);
        ushort4 u4 = *(const ushort4*)(xin + ((size_t)b * cL + vv) * cDI + d);
        acc.x += wv.x * bfu2f(u4.x); acc.y += wv.y * bfu2f(u4.y);
        acc.z += wv.z * bfu2f(u4.z); acc.w += wv.w * bfu2f(u4.w);
      }
    }
  }
  ushort4 o;
  o.x = (unsigned short)f2bf(siluf(acc.x));
  o.y = (unsigned short)f2bf(siluf(acc.y));
  o.z = (unsigned short)f2bf(siluf(acc.z));
  o.w = (unsigned short)f2bf(siluf(acc.w));
  *(ushort4*)(out + (size_t)bv * cDI + d) = o;
}

// ---------- wave-per-row LayerNorm (C=192): no LDS, no barriers, bf16 out ----------
__global__ void __launch_bounds__(256) lnb_kernel(
    const float* __restrict__ in, const void* __restrict__ g,
    const void* __restrict__ bb, const int* __restrict__ flg,
    unsigned short* __restrict__ out) {
  int pf = flg[1];
  int row = blockIdx.x * 4 + (threadIdx.x >> 6);
  int lane = threadIdx.x & 63;
  const float* x = in + (size_t)row * cC;
  float v0 = x[lane], v1 = x[lane + 64], v2 = x[lane + 128];
  float s1 = v0 + v1 + v2;
  float s2 = v0 * v0 + v1 * v1 + v2 * v2;
#pragma unroll
  for (int off = 32; off > 0; off >>= 1) {
    s1 += __shfl_xor(s1, off);
    s2 += __shfl_xor(s2, off);
  }
  float mean = s1 * (1.f / cC);
  float var = s2 * (1.f / cC) - mean * mean;
  float rstd = rsqrtf(var + 1e-6f);
  unsigned short* o = out + (size_t)row * cC;
  o[lane]       = (unsigned short)f2bf((v0 - mean) * rstd * ldsel(g, lane, pf)       + ldsel(bb, lane, pf));
  o[lane + 64]  = (unsigned short)f2bf((v1 - mean) * rstd * ldsel(g, lane + 64, pf)  + ldsel(bb, lane + 64, pf));
  o[lane + 128] = (unsigned short)f2bf((v2 - mean) * rstd * ldsel(g, lane + 128, pf) + ldsel(bb, lane + 128, pf));
}

// ---------- text conditioning ----------
__global__ void __launch_bounds__(384) text_cond_kernel(
    const void* __restrict__ text, const void* __restrict__ tw,
    const void* __restrict__ tb, const int* __restrict__ flg,
    float* __restrict__ cond) {
  int af = flg[0], pf = flg[1];
  __shared__ float mean[cC];
  int b = blockIdx.x;
  for (int c = threadIdx.x; c < cC; c += 384) {
    float s = 0.f;
    for (int t = 0; t < cLT; ++t) s += ldsel(text, ((size_t)b * cLT + t) * cC + c, af);
    mean[c] = s * (1.f / cLT);
  }
  __syncthreads();
  int di = threadIdx.x;
  float a = ldsel(tb, di, pf);
  for (int c = 0; c < cC; ++c) a += mean[c] * ldsel(tw, di * cC + c, pf);
  cond[b * cDI + di] = siluf(a);
}

// ---------- MFMA GEMM: out = epilogue(A[M,K] @ W[N,K]^T), bf16 compute ----------
template <int MODE, int ABF>
__global__ void __launch_bounds__(256) gemm_mfma_kernel(
    const void* __restrict__ A, const void* __restrict__ W,
    int N, int K, const void* __restrict__ bias, const int* __restrict__ flg,
    const float* __restrict__ extra, float* __restrict__ out,
    unsigned short* __restrict__ out2) {
  constexpr int BM = 128, BN = 64, BK = 32, PK = 40;
  __shared__ short As[BM * PK];
  __shared__ short Bs[BN * PK];
  int pf = flg[1];
  int tid = threadIdx.x;
  int m0 = blockIdx.y * BM, n0 = blockIdx.x * BN;
  int lane = tid & 63, wv = tid >> 6;
  int wm = (wv >> 1) * 64, wn = (wv & 1) * 32;
  int lr = lane & 15, quad = lane >> 4;
  f32x4 acc[4][2];
#pragma unroll
  for (int mi = 0; mi < 4; ++mi)
#pragma unroll
    for (int ni = 0; ni < 2; ++ni) { acc[mi][ni][0]=0.f; acc[mi][ni][1]=0.f; acc[mi][ni][2]=0.f; acc[mi][ni][3]=0.f; }
  int ar = tid >> 1, aks = (tid & 1) * 16;
  int wr = tid >> 2, wks = (tid & 3) * 8;
  for (int k0 = 0; k0 < K; k0 += BK) {
    if (ABF) {
      const unsigned short* ap = (const unsigned short*)A + (size_t)(m0 + ar) * K + k0 + aks;
      short* da = &As[ar * PK + aks];
#pragma unroll
      for (int i = 0; i < 4; ++i)
        *(short4v*)(da + i * 4) = *(const short4v*)(ap + i * 4);
    } else {
      const float* ap = (const float*)A + (size_t)(m0 + ar) * K + k0 + aks;
      short* da = &As[ar * PK + aks];
#pragma unroll
      for (int i = 0; i < 4; ++i) {
        float4 v = ((const float4*)ap)[i];
        short4v h; h.x = f2bf(v.x); h.y = f2bf(v.y); h.z = f2bf(v.z); h.w = f2bf(v.w);
        *(short4v*)(da + i * 4) = h;
      }
    }
    {
      int nr = n0 + wr;
      short hb[8];
      if (nr < N) {
        size_t wi = (size_t)nr * K + k0 + wks;
        if (pf) {
#pragma unroll
          for (int i = 0; i < 8; ++i) hb[i] = f2bf(((const float*)W)[wi + i]);
        } else {
#pragma unroll
          for (int i = 0; i < 8; ++i) hb[i] = (short)((const unsigned short*)W)[wi + i];
        }
      } else {
#pragma unroll
        for (int i = 0; i < 8; ++i) hb[i] = 0;
      }
      short* db = &Bs[wr * PK + wks];
#pragma unroll
      for (int i = 0; i < 8; i += 4) {
        short4v h; h.x = hb[i]; h.y = hb[i+1]; h.z = hb[i+2]; h.w = hb[i+3];
        *(short4v*)(db + i) = h;
      }
    }
    __syncthreads();
    bf16x8 af[4], bfr[2];
#pragma unroll
    for (int mi = 0; mi < 4; ++mi)
      af[mi] = *(const bf16x8*)&As[(wm + mi * 16 + lr) * PK + quad * 8];
#pragma unroll
    for (int ni = 0; ni < 2; ++ni)
      bfr[ni] = *(const bf16x8*)&Bs[(wn + ni * 16 + lr) * PK + quad * 8];
#pragma unroll
    for (int mi = 0; mi < 4; ++mi)
#pragma unroll
      for (int ni = 0; ni < 2; ++ni)
        acc[mi][ni] = __builtin_amdgcn_mfma_f32_16x16x32_bf16(af[mi], bfr[ni], acc[mi][ni], 0, 0, 0);
    __syncthreads();
  }
#pragma unroll
  for (int mi = 0; mi < 4; ++mi) {
#pragma unroll
    for (int ni = 0; ni < 2; ++ni) {
#pragma unroll
      for (int r = 0; r < 4; ++r) {
        int m = m0 + wm + mi * 16 + quad * 4 + r;
        int n = n0 + wn + ni * 16 + lr;
        float v = acc[mi][ni][r];
        if (MODE == 0) {
          float bvv = ldsel(bias, n, pf);
          int b = m >> 13;
          if (n < cDI)
            ((unsigned short*)out)[(size_t)m * cDI + n] =
                (unsigned short)f2bf(v + bvv + extra[b * cDI + n]);
          else
            out2[(size_t)m * cDI + (n - cDI)] = (unsigned short)f2bf(v + bvv);
        } else if (MODE == 1) {
          if (n < cK * XROW) {
            int k = n / XROW, c = n - k * XROW;
            int b = m >> 13, vv = m & (cL - 1);
            int t = vv >> 10, q = vv & 1023, h = q >> 5, w = q & 31;
            int l1 = (t << 10) + (w << 5) + h;
            int lk = (k == 0) ? vv : (k == 1) ? l1 : (k == 2) ? (cL - 1 - vv) : (cL - 1 - l1);
            out[((size_t)(b * cK + k) * cL + lk) * XSTR + c] = v;
          }
        } else if (MODE == 2) {
          out[(size_t)m * cC + n] = v + extra[(size_t)m * cC + n];
        } else if (MODE == 3) {
          ((unsigned short*)out)[(size_t)m * cHID + n] =
              (unsigned short)f2bf(gelut(v + ldsel(bias, n, pf)));
        } else {
          out[(size_t)m * cC + n] = v + ldsel(bias, n, pf) + extra[(size_t)m * cC + n];
        }
      }
    }
  }
}

// voxel index for scan position l in direction k
DEV int scan_voxel(int k, int l) {
  if (k == 0) return l;
  if (k == 2) return cL - 1 - l;
  int ll = (k == 1) ? l : (cL - 1 - l);
  int t = ll >> 10, q = ll & 1023, w = q >> 5, h = q & 31;
  return (t << 10) + (h << 5) + w;
}

// ---------- scan pass 1 ----------
// 192 threads cover all 384 channels (2 adjacent/thread): rows staged ONCE per
// (b,k,s) (was 3x), dual independent recurrences share each LDS row read (2x
// ILP for the latency gap), ushort2 u-loads and y-stores stay fully coalesced
// (the r6 regression was the ATOMIC stream, which r7 removed).
__global__ void __launch_bounds__(192, 3) scan1_kernel(
    const unsigned short* __restrict__ xch, const float* __restrict__ xdbl,
    const void* __restrict__ dtw, const void* __restrict__ dtbv,
    const void* __restrict__ alog, const void* __restrict__ dsv,
    const int* __restrict__ flg,
    unsigned short* __restrict__ ys0, unsigned short* __restrict__ ys1,
    unsigned short* __restrict__ ys2, unsigned short* __restrict__ ys3,
    unsigned short* __restrict__ hend, unsigned short* __restrict__ pend) {
  __shared__ float rows[SEGLEN * XSTR];   // 64 x 48 floats = 12 KB
  int pf = flg[1];
  int tid = threadIdx.x;
  int d0 = tid * 2;
  int bks = blockIdx.x;
  int s = bks & (SEG - 1); int bk = bks >> 7; int k = bk & 3; int b = bk >> 2;
  int l0 = s * SEGLEN;
  {
    const float4* src = (const float4*)(xdbl + ((size_t)bk * cL + l0) * XSTR);
    float4* dst = (float4*)rows;
#pragma unroll
    for (int i = 0; i < 4; ++i)   // 768 float4 / 192 threads
      dst[tid + i * 192] = src[tid + i * 192];
  }
  float wdtA[cDTR], wdtB[cDTR];
#pragma unroll
  for (int r = 0; r < cDTR; ++r) {
    wdtA[r] = ldsel(dtw, (size_t)(k * cDI + d0) * cDTR + r, pf);
    wdtB[r] = ldsel(dtw, (size_t)(k * cDI + d0 + 1) * cDTR + r, pf);
  }
  float dtbA = ldsel(dtbv, k * cDI + d0, pf);
  float dtbB = ldsel(dtbv, k * cDI + d0 + 1, pf);
  float acA[cN], acB[cN];
#pragma unroll
  for (int n = 0; n < cN; ++n) {
    acA[n] = -__expf(ldsel(alog, (size_t)(k * cDI + d0) * cN + n, pf)) * 1.4426950408889634f;
    acB[n] = -__expf(ldsel(alog, (size_t)(k * cDI + d0 + 1) * cN + n, pf)) * 1.4426950408889634f;
  }
  bool fast = true;
#pragma unroll
  for (int n = 1; n < cN; ++n) {
    fast = fast && (fabsf(acA[n] - (float)(n + 1) * acA[0]) <= 1e-3f * fabsf(acA[n]));
    fast = fast && (fabsf(acB[n] - (float)(n + 1) * acB[0]) <= 1e-3f * fabsf(acB[n]));
  }
  float DsA = ldsel(dsv, k * cDI + d0, pf);
  float DsB = ldsel(dsv, k * cDI + d0 + 1, pf);
  float hA[cN], hB[cN];
#pragma unroll
  for (int n = 0; n < cN; ++n) { hA[n] = 0.f; hB[n] = 0.f; }
  size_t so = ((size_t)bks * cDI + d0) * cN;   // chan A at so, chan B at so+cN
  const unsigned short* xcb = xch + (size_t)b * cL * cDI + d0;
  unsigned short* ysk = (k == 0) ? ys0 : (k == 1) ? ys1 : (k == 2) ? ys2 : ys3;
  unsigned short* ysrow = ysk + ((size_t)b * cL + l0) * cDI + d0;
  __syncthreads();
  if (fast) {
    float ac0A = acA[0], ac0B = acB[0];
    float P1A = 1.f, P1B = 1.f;
    ushort2 uu = *(const ushort2*)(xcb + (size_t)scan_voxel(k, l0) * cDI);
    for (int st = 0; st < SEGLEN; ++st) {
      const float4* rp = (const float4*)(rows + st * XSTR);
      float4 q0 = rp[0], q1 = rp[1], q2 = rp[2];
      float sA0 = dtbA + q0.x*wdtA[0] + q0.z*wdtA[2] + q1.x*wdtA[4] + q1.z*wdtA[6] + q2.x*wdtA[8] + q2.z*wdtA[10];
      float sA1 = q0.y*wdtA[1] + q0.w*wdtA[3] + q1.y*wdtA[5] + q1.w*wdtA[7] + q2.y*wdtA[9] + q2.w*wdtA[11];
      float sB0 = dtbB + q0.x*wdtB[0] + q0.z*wdtB[2] + q1.x*wdtB[4] + q1.z*wdtB[6] + q2.x*wdtB[8] + q2.z*wdtB[10];
      float sB1 = q0.y*wdtB[1] + q0.w*wdtB[3] + q1.y*wdtB[5] + q1.w*wdtB[7] + q2.y*wdtB[9] + q2.w*wdtB[11];
      float dtA = softplusf(sA0 + sA1);
      float dtB = softplusf(sB0 + sB1);
      float a1A = exp2f(dtA * ac0A), a1B = exp2f(dtB * ac0B);
      int stn = (st + 1 < SEGLEN) ? st + 1 : SEGLEN - 1;
      ushort2 uun = *(const ushort2*)(xcb + (size_t)scan_voxel(k, l0 + stn) * cDI);
      float pwA[cN], pwB[cN];
      pow16(a1A, pwA); pow16(a1B, pwB);
      float Bv[cN], Cv[cN];
      {
        float4 t3 = rp[3], t4 = rp[4], t5 = rp[5], t6 = rp[6];
        Bv[0]=t3.x; Bv[1]=t3.y; Bv[2]=t3.z; Bv[3]=t3.w;
        Bv[4]=t4.x; Bv[5]=t4.y; Bv[6]=t4.z; Bv[7]=t4.w;
        Bv[8]=t5.x; Bv[9]=t5.y; Bv[10]=t5.z; Bv[11]=t5.w;
        Bv[12]=t6.x; Bv[13]=t6.y; Bv[14]=t6.z; Bv[15]=t6.w;
        float4 t7 = rp[7], t8 = rp[8], t9 = rp[9], t10 = rp[10];
        Cv[0]=t7.x; Cv[1]=t7.y; Cv[2]=t7.z; Cv[3]=t7.w;
        Cv[4]=t8.x; Cv[5]=t8.y; Cv[6]=t8.z; Cv[7]=t8.w;
        Cv[8]=t9.x; Cv[9]=t9.y; Cv[10]=t9.z; Cv[11]=t9.w;
        Cv[12]=t10.x; Cv[13]=t10.y; Cv[14]=t10.z; Cv[15]=t10.w;
      }
      float uA = bfu2f(uu.x), uB = bfu2f(uu.y);
      float dtuA = dtA * uA, dtuB = dtB * uB;
      P1A *= a1A; P1B *= a1B;
      float yA0 = DsA * uA, yA1 = 0.f, yA2 = 0.f, yA3 = 0.f;
      float yB0 = DsB * uB, yB1 = 0.f, yB2 = 0.f, yB3 = 0.f;
#pragma unroll
      for (int n = 0; n < cN; n += 4) {
        hA[n+0] = hA[n+0] * pwA[n+0] + dtuA * Bv[n+0]; yA0 += hA[n+0] * Cv[n+0];
        hA[n+1] = hA[n+1] * pwA[n+1] + dtuA * Bv[n+1]; yA1 += hA[n+1] * Cv[n+1];
        hA[n+2] = hA[n+2] * pwA[n+2] + dtuA * Bv[n+2]; yA2 += hA[n+2] * Cv[n+2];
        hA[n+3] = hA[n+3] * pwA[n+3] + dtuA * Bv[n+3]; yA3 += hA[n+3] * Cv[n+3];
        hB[n+0] = hB[n+0] * pwB[n+0] + dtuB * Bv[n+0]; yB0 += hB[n+0] * Cv[n+0];
        hB[n+1] = hB[n+1] * pwB[n+1] + dtuB * Bv[n+1]; yB1 += hB[n+1] * Cv[n+1];
        hB[n+2] = hB[n+2] * pwB[n+2] + dtuB * Bv[n+2]; yB2 += hB[n+2] * Cv[n+2];
        hB[n+3] = hB[n+3] * pwB[n+3] + dtuB * Bv[n+3]; yB3 += hB[n+3] * Cv[n+3];
      }
      ushort2 yo;
      yo.x = (unsigned short)f2bf((yA0 + yA1) + (yA2 + yA3));
      yo.y = (unsigned short)f2bf((yB0 + yB1) + (yB2 + yB3));
      *(ushort2*)(ysrow + (size_t)st * cDI) = yo;
      uu = uun;
    }
    float ppA = P1A, ppB = P1B;
#pragma unroll
    for (int n = 0; n < cN; ++n) {
      hend[so + n] = (unsigned short)f2bf(hA[n]);
      pend[so + n] = (unsigned short)f2bf(ppA); ppA *= P1A;
      hend[so + cN + n] = (unsigned short)f2bf(hB[n]);
      pend[so + cN + n] = (unsigned short)f2bf(ppB); ppB *= P1B;
    }
  } else {
    float PA[cN], PB[cN];
#pragma unroll
    for (int n = 0; n < cN; ++n) { PA[n] = 1.f; PB[n] = 1.f; }
    for (int st = 0; st < SEGLEN; ++st) {
      const float4* rp = (const float4*)(rows + st * XSTR);
      float4 q0 = rp[0], q1 = rp[1], q2 = rp[2];
      float sA0 = dtbA + q0.x*wdtA[0] + q0.z*wdtA[2] + q1.x*wdtA[4] + q1.z*wdtA[6] + q2.x*wdtA[8] + q2.z*wdtA[10];
      float sA1 = q0.y*wdtA[1] + q0.w*wdtA[3] + q1.y*wdtA[5] + q1.w*wdtA[7] + q2.y*wdtA[9] + q2.w*wdtA[11];
      float sB0 = dtbB + q0.x*wdtB[0] + q0.z*wdtB[2] + q1.x*wdtB[4] + q1.z*wdtB[6] + q2.x*wdtB[8] + q2.z*wdtB[10];
      float sB1 = q0.y*wdtB[1] + q0.w*wdtB[3] + q1.y*wdtB[5] + q1.w*wdtB[7] + q2.y*wdtB[9] + q2.w*wdtB[11];
      float dtA = softplusf(sA0 + sA1);
      float dtB = softplusf(sB0 + sB1);
      float Bv[cN], Cv[cN];
      {
        float4 t3 = rp[3], t4 = rp[4], t5 = rp[5], t6 = rp[6];
        Bv[0]=t3.x; Bv[1]=t3.y; Bv[2]=t3.z; Bv[3]=t3.w;
        Bv[4]=t4.x; Bv[5]=t4.y; Bv[6]=t4.z; Bv[7]=t4.w;
        Bv[8]=t5.x; Bv[9]=t5.y; Bv[10]=t5.z; Bv[11]=t5.w;
        Bv[12]=t6.x; Bv[13]=t6.y; Bv[14]=t6.z; Bv[15]=t6.w;
        float4 t7 = rp[7], t8 = rp[8], t9 = rp[9], t10 = rp[10];
        Cv[0]=t7.x; Cv[1]=t7.y; Cv[2]=t7.z; Cv[3]=t7.w;
        Cv[4]=t8.x; Cv[5]=t8.y; Cv[6]=t8.z; Cv[7]=t8.w;
        Cv[8]=t9.x; Cv[9]=t9.y; Cv[10]=t9.z; Cv[11]=t9.w;
        Cv[12]=t10.x; Cv[13]=t10.y; Cv[14]=t10.z; Cv[15]=t10.w;
      }
      int v = scan_voxel(k, l0 + st);
      ushort2 uu = *(const ushort2*)(xcb + (size_t)v * cDI);
      float uA = bfu2f(uu.x), uB = bfu2f(uu.y);
      float dtuA = dtA * uA, dtuB = dtB * uB;
      float yA = DsA * uA, yB = DsB * uB;
#pragma unroll
      for (int n = 0; n < cN; ++n) {
        float aA = exp2f(dtA * acA[n]);
        hA[n] = hA[n] * aA + dtuA * Bv[n]; PA[n] *= aA; yA += hA[n] * Cv[n];
        float aB = exp2f(dtB * acB[n]);
        hB[n] = hB[n] * aB + dtuB * Bv[n]; PB[n] *= aB; yB += hB[n] * Cv[n];
      }
      ushort2 yo;
      yo.x = (unsigned short)f2bf(yA);
      yo.y = (unsigned short)f2bf(yB);
      *(ushort2*)(ysrow + (size_t)st * cDI) = yo;
    }
#pragma unroll
    for (int n = 0; n < cN; ++n) {
      hend[so + n] = (unsigned short)f2bf(hA[n]);
      pend[so + n] = (unsigned short)f2bf(PA[n]);
      hend[so + cN + n] = (unsigned short)f2bf(hB[n]);
      pend[so + cN + n] = (unsigned short)f2bf(PB[n]);
    }
  }
}

// ---------- scan pass 2 (serial prefix over segments; fp32 recurrence, bf16 storage) ----------
__global__ void __launch_bounds__(256) scan2_kernel(
    unsigned short* __restrict__ hend, const unsigned short* __restrict__ pend) {
  int tid = blockIdx.x * 256 + threadIdx.x;
  int bk = tid / (cDI * cN); int r = tid - bk * (cDI * cN);
  float g = 0.f;
  for (int s = 0; s < SEG; ++s) {
    size_t o = ((size_t)(bk * SEG + s) * cDI * cN) + r;
    float he = bfu2f(hend[o]), pe = bfu2f(pend[o]);
    hend[o] = (unsigned short)f2bf(g);
    g = pe * g + he;
  }
}

// ---------- scan pass 3 (owned read-add-store, 2 channels/thread) ----------
__global__ void __launch_bounds__(192, 3) scan3_kernel(
    const float* __restrict__ xdbl,
    const void* __restrict__ dtw, const void* __restrict__ dtbv,
    const void* __restrict__ alog, const int* __restrict__ flg,
    const unsigned short* __restrict__ hin,
    unsigned short* __restrict__ ys0, unsigned short* __restrict__ ys1,
    unsigned short* __restrict__ ys2, unsigned short* __restrict__ ys3) {
  int bks = blockIdx.x;
  int s = bks & (SEG - 1);
  if (s == 0) return;
  __shared__ float rows[SEGLEN * XSTR];
  int pf = flg[1];
  int tid = threadIdx.x;
  int d0 = tid * 2;
  int bk = bks >> 7; int k = bk & 3; int b = bk >> 2;
  int l0 = s * SEGLEN;
  {
    const float4* src = (const float4*)(xdbl + ((size_t)bk * cL + l0) * XSTR);
    float4* dst = (float4*)rows;
#pragma unroll
    for (int i = 0; i < 4; ++i)
      dst[tid + i * 192] = src[tid + i * 192];
  }
  float wdtA[cDTR], wdtB[cDTR];
#pragma unroll
  for (int r = 0; r < cDTR; ++r) {
    wdtA[r] = ldsel(dtw, (size_t)(k * cDI + d0) * cDTR + r, pf);
    wdtB[r] = ldsel(dtw, (size_t)(k * cDI + d0 + 1) * cDTR + r, pf);
  }
  float dtbA = ldsel(dtbv, k * cDI + d0, pf);
  float dtbB = ldsel(dtbv, k * cDI + d0 + 1, pf);
  float acA[cN], acB[cN];
#pragma unroll
  for (int n = 0; n < cN; ++n) {
    acA[n] = -__expf(ldsel(alog, (size_t)(k * cDI + d0) * cN + n, pf)) * 1.4426950408889634f;
    acB[n] = -__expf(ldsel(alog, (size_t)(k * cDI + d0 + 1) * cN + n, pf)) * 1.4426950408889634f;
  }
  bool fast = true;
#pragma unroll
  for (int n = 1; n < cN; ++n) {
    fast = fast && (fabsf(acA[n] - (float)(n + 1) * acA[0]) <= 1e-3f * fabsf(acA[n]));
    fast = fast && (fabsf(acB[n] - (float)(n + 1) * acB[0]) <= 1e-3f * fabsf(acB[n]));
  }
  float gA[cN], gB[cN];
  size_t so = ((size_t)bks * cDI + d0) * cN;
#pragma unroll
  for (int n = 0; n < cN; ++n) {
    gA[n] = bfu2f(hin[so + n]);
    gB[n] = bfu2f(hin[so + cN + n]);
  }
  unsigned short* ysk = (k == 0) ? ys0 : (k == 1) ? ys1 : (k == 2) ? ys2 : ys3;
  unsigned short* ysrow = ysk + ((size_t)b * cL + l0) * cDI + d0;
  __syncthreads();
  if (fast) {
    float ac0A = acA[0], ac0B = acB[0];
    for (int st = 0; st < SEGLEN; ++st) {
      const float4* rp = (const float4*)(rows + st * XSTR);
      ushort2 cur = *(const ushort2*)(ysrow + (size_t)st * cDI);
      float4 q0 = rp[0], q1 = rp[1], q2 = rp[2];
      float sA0 = dtbA + q0.x*wdtA[0] + q0.z*wdtA[2] + q1.x*wdtA[4] + q1.z*wdtA[6] + q2.x*wdtA[8] + q2.z*wdtA[10];
      float sA1 = q0.y*wdtA[1] + q0.w*wdtA[3] + q1.y*wdtA[5] + q1.w*wdtA[7] + q2.y*wdtA[9] + q2.w*wdtA[11];
      float sB0 = dtbB + q0.x*wdtB[0] + q0.z*wdtB[2] + q1.x*wdtB[4] + q1.z*wdtB[6] + q2.x*wdtB[8] + q2.z*wdtB[10];
      float sB1 = q0.y*wdtB[1] + q0.w*wdtB[3] + q1.y*wdtB[5] + q1.w*wdtB[7] + q2.y*wdtB[9] + q2.w*wdtB[11];
      float dtA = softplusf(sA0 + sA1);
      float dtB = softplusf(sB0 + sB1);
      float a1A = exp2f(dtA * ac0A), a1B = exp2f(dtB * ac0B);
      float pwA[cN], pwB[cN];
      pow16(a1A, pwA); pow16(a1B, pwB);
      float Cv[cN];
      {
        float4 t7 = rp[7], t8 = rp[8], t9 = rp[9], t10 = rp[10];
        Cv[0]=t7.x; Cv[1]=t7.y; Cv[2]=t7.z; Cv[3]=t7.w;
        Cv[4]=t8.x; Cv[5]=t8.y; Cv[6]=t8.z; Cv[7]=t8.w;
        Cv[8]=t9.x; Cv[9]=t9.y; Cv[10]=t9.z; Cv[11]=t9.w;
        Cv[12]=t10.x; Cv[13]=t10.y; Cv[14]=t10.z; Cv[15]=t10.w;
      }
      float yA0 = 0.f, yA1 = 0.f, yA2 = 0.f, yA3 = 0.f;
      float yB0 = 0.f, yB1 = 0.f, yB2 = 0.f, yB3 = 0.f;
#pragma unroll
      for (int n = 0; n < cN; n += 4) {
        gA[n+0] *= pwA[n+0]; yA0 += gA[n+0] * Cv[n+0];
        gA[n+1] *= pwA[n+1]; yA1 += gA[n+1] * Cv[n+1];
        gA[n+2] *= pwA[n+2]; yA2 += gA[n+2] * Cv[n+2];
        gA[n+3] *= pwA[n+3]; yA3 += gA[n+3] * Cv[n+3];
        gB[n+0] *= pwB[n+0]; yB0 += gB[n+0] * Cv[n+0];
        gB[n+1] *= pwB[n+1]; yB1 += gB[n+1] * Cv[n+1];
        gB[n+2] *= pwB[n+2]; yB2 += gB[n+2] * Cv[n+2];
        gB[n+3] *= pwB[n+3]; yB3 += gB[n+3] * Cv[n+3];
      }
      ushort2 yo;
      yo.x = (unsigned short)f2bf(bfu2f(cur.x) + (yA0 + yA1) + (yA2 + yA3));
      yo.y = (unsigned short)f2bf(bfu2f(cur.y) + (yB0 + yB1) + (yB2 + yB3));
      *(ushort2*)(ysrow + (size_t)st * cDI) = yo;
    }
  } else {
    for (int st = 0; st < SEGLEN; ++st) {
      const float4* rp = (const float4*)(rows + st * XSTR);
      ushort2 cur = *(const ushort2*)(ysrow + (size_t)st * cDI);
      float4 q0 = rp[0], q1 = rp[1], q2 = rp[2];
      float sA0 = dtbA + q0.x*wdtA[0] + q0.z*wdtA[2] + q1.x*wdtA[4] + q1.z*wdtA[6] + q2.x*wdtA[8] + q2.z*wdtA[10];
      float sA1 = q0.y*wdtA[1] + q0.w*wdtA[3] + q1.y*wdtA[5] + q1.w*wdtA[7] + q2.y*wdtA[9] + q2.w*wdtA[11];
      float sB0 = dtbB + q0.x*wdtB[0] + q0.z*wdtB[2] + q1.x*wdtB[4] + q1.z*wdtB[6] + q2.x*wdtB[8] + q2.z*wdtB[10];
      float sB1 = q0.y*wdtB[1] + q0.w*wdtB[3] + q1.y*wdtB[5] + q1.w*wdtB[7] + q2.y*wdtB[9] + q2.w*wdtB[11];
      float dtA = softplusf(sA0 + sA1);
      float dtB = softplusf(sB0 + sB1);
      float Cv[cN];
      {
        float4 t7 = rp[7], t8 = rp[8], t9 = rp[9], t10 = rp[10];
        Cv[0]=t7.x; Cv[1]=t7.y; Cv[2]=t7.z; Cv[3]=t7.w;
        Cv[4]=t8.x; Cv[5]=t8.y; Cv[6]=t8.z; Cv[7]=t8.w;
        Cv[8]=t9.x; Cv[9]=t9.y; Cv[10]=t9.z; Cv[11]=t9.w;
        Cv[12]=t10.x; Cv[13]=t10.y; Cv[14]=t10.z; Cv[15]=t10.w;
      }
      float yA = 0.f, yB = 0.f;
#pragma unroll
      for (int n = 0; n < cN; ++n) {
        float aA = exp2f(dtA * acA[n]); gA[n] *= aA; yA += gA[n] * Cv[n];
        float aB = exp2f(dtB * acB[n]); gB[n] *= aB; yB += gB[n] * Cv[n];
      }
      ushort2 yo;
      yo.x = (unsigned short)f2bf(bfu2f(cur.x) + yA);
      yo.y = (unsigned short)f2bf(bfu2f(cur.y) + yB);
      *(ushort2*)(ysrow + (size_t)st * cDI) = yo;
    }
  }
}

// ---------- merge: gather 4 directions + out_norm LN + silu(z) gate ----------
__global__ void __launch_bounds__(128) merge_kernel(
    const unsigned short* __restrict__ ys0, const unsigned short* __restrict__ ys1,
    const unsigned short* __restrict__ ys2, const unsigned short* __restrict__ ys3,
    const unsigned short* __restrict__ zh,
    const void* __restrict__ ong, const void* __restrict__ onb,
    const int* __restrict__ flg, unsigned short* __restrict__ yg) {
  int pf = flg[1];
  int bv = blockIdx.x;
  int v = bv & (cL - 1); int b = bv >> 13;
  int t = v >> 10, q = v & 1023, hh = q >> 5, ww = q & 31;
  int l1 = (t << 10) + (ww << 5) + hh;
  size_t r0 = ((size_t)b * cL + v) * cDI;
  size_t r1 = ((size_t)b * cL + l1) * cDI;
  size_t r2 = ((size_t)b * cL + (cL - 1 - v)) * cDI;
  size_t r3 = ((size_t)b * cL + (cL - 1 - l1)) * cDI;
  float vals[3]; float s1 = 0.f, s2 = 0.f;
#pragma unroll
  for (int i = 0; i < 3; ++i) {
    int d = threadIdx.x + i * 128;
    float x = bfu2f(ys0[r0 + d]) + bfu2f(ys1[r1 + d]) +
              bfu2f(ys2[r2 + d]) + bfu2f(ys3[r3 + d]);
    vals[i] = x; s1 += x; s2 += x * x;
  }
  blkreduce2<128>(s1, s2);
  float mean = s1 * (1.f / cDI);
  float var = s2 * (1.f / cDI) - mean * mean;
  float rstd = rsqrtf(var + 1e-6f);
  const unsigned short* zr = zh + (size_t)bv * cDI;
  unsigned short* og = yg + (size_t)bv * cDI;
#pragma unroll
  for (int i = 0; i < 3; ++i) {
    int d = threadIdx.x + i * 128;
    float xn = (vals[i] - mean) * rstd * ldsel(ong, d, pf) + ldsel(onb, d, pf);
    og[d] = (unsigned short)f2bf(xn * siluf(bfu2f(zr[d])));
  }
}

}  // namespace

extern "C" void kernel_launch(void* const* d_in, const int* in_sizes, int n_in,
                              void* d_out, int out_size, void* d_ws, size_t ws_size,
                              hipStream_t stream) {
  (void)in_sizes; (void)n_in; (void)out_size; (void)ws_size;
  const void* x    = d_in[0];
  const void* text = d_in[1];
  const void* c1w  = d_in[2];
  const void* c1b  = d_in[3];
  const void* c2w  = d_in[4];
  const void* c2b  = d_in[5];
  const void* n1g  = d_in[6];
  const void* n1b  = d_in[7];
  const void* n2g  = d_in[8];
  const void* n2b  = d_in[9];
  const void* ipw  = d_in[10];
  const void* ipb  = d_in[11];
  const void* tpw  = d_in[12];
  const void* tpb  = d_in[13];
  const void* cvw  = d_in[14];
  const void* cvb  = d_in[15];
  const void* xpw  = d_in[16];
  const void* dtw  = d_in[17];
  const void* dtb  = d_in[18];
  const void* alog = d_in[19];
  const void* dsv  = d_in[20];
  const void* ong  = d_in[21];
  const void* onb  = d_in[22];
  const void* opw  = d_in[23];
  const void* f1w  = d_in[24];
  const void* f1b  = d_in[25];
  const void* f2w  = d_in[26];
  const void* f2b  = d_in[27];

  float* Wf = (float*)d_ws;

  // ---- slot arena (~125.9 MB), atomic-free scan + bf16 activations ----
  constexpr size_t oC  = 0;                              // 6,291,456
  constexpr size_t oD  = 6291456;                        // 3,145,728
  constexpr size_t oG  = 9437184;                        // 3,145,728
  constexpr size_t oA  = 12582912;                       // 6,291,456
  constexpr size_t oB  = 18874368;                       // 6,291,456
  constexpr size_t oE  = 25165824;                       // 3,145,728
  constexpr size_t oF  = 28311552;                       // 3,145,728
  constexpr size_t oCO = 31457280;                       // 768 (cond)
  constexpr size_t oFL = 31458048;                       // 4 ints (flags)
  constexpr size_t oWCV = 31458052;                      // 27*384
  constexpr size_t oBCV = 31468420;                      // 384
  constexpr size_t oW1  = 31468804;                      // 27*192
  constexpr size_t oB1  = 31473988;                      // 192
  constexpr size_t oW2  = 31474180;                      // 5184
  constexpr size_t oB2  = 31479364;                      // 192 -> end 31479556
  unsigned short* xch = (unsigned short*)(Wf + oC);            // bf16 silu(dwconv)
  unsigned short* ysd2 = (unsigned short*)(Wf + oC + 3145728); // ystream dir 2
  unsigned short* hbufh = (unsigned short*)(Wf + oC);          // fc1 out bf16
  float* xdbl = Wf + oD;
  unsigned short* ygh  = (unsigned short*)(Wf + oD);           // yg bf16 (after xdbl dead)
  unsigned short* xnh  = (unsigned short*)(Wf + oG);           // LN1 out bf16
  unsigned short* pendp = (unsigned short*)(Wf + oG);          // bf16, after xnh dead
  unsigned short* xib  = (unsigned short*)(Wf + oA);           // in_proj x-half bf16
  unsigned short* ysd0 = (unsigned short*)(Wf + oA);           // ystream dir 0 (xib dead)
  unsigned short* ysd1 = (unsigned short*)(Wf + oA + 3145728); // ystream dir 1
  float* x2   = Wf + oA;   // out_proj output (after ystream dead)
  unsigned short* zh   = (unsigned short*)(Wf + oB);           // z bf16
  unsigned short* ysd3 = (unsigned short*)(Wf + oB + 3145728); // ystream dir 3
  float* x3   = Wf + oB;
  float* x1   = Wf + oE;
  unsigned short* hendp = (unsigned short*)(Wf + oF);          // bf16
  unsigned short* xn2h = (unsigned short*)(Wf + oF);           // LN2 out bf16 (hend dead)
  float* cond = Wf + oCO;
  int*   flg  = (int*)(Wf + oFL);
  float* wcv = Wf + oWCV; float* bcv = Wf + oBCV;
  float* w1t = Wf + oW1;  float* b1t = Wf + oB1;
  float* w2t = Wf + oW2;  float* b2t = Wf + oB2;

  const int cpeBlocks = (cBL * cC / 4) / 256;     // 3072
  const int dwBlocks  = (cBL * cDI / 4) / 256;    // 6144

  // 0. dtype detection + conv weight prep
  hipLaunchKernelGGL(detect_kernel, dim3(1), dim3(256), 0, stream,
                     (const unsigned short*)x, (const unsigned short*)ipw, flg);
  hipLaunchKernelGGL(prep_kernel, dim3(85), dim3(256), 0, stream,
                     cvw, cvb, c1w, c1b, c2w, c2b, flg, wcv, bcv, w1t, b1t, w2t, b2t);
  // 1. x1 = x + cpe1(x)
  hipLaunchKernelGGL(cpe_kernel, dim3(cpeBlocks), dim3(256), 0, stream,
                     x, w1t, b1t, flg, 0, x1);
  // 2. xnh = bf16(LN1(x1))  (wave-per-row, no barriers)
  hipLaunchKernelGGL(lnb_kernel, dim3(cBL / 4), dim3(256), 0, stream, x1, n1g, n1b, flg, xnh);
  // 3. cond
  hipLaunchKernelGGL(text_cond_kernel, dim3(cB), dim3(384), 0, stream, text, tpw, tpb, flg, cond);
  // 4. in_proj (MFMA, bf16 A): xnh -> xib bf16 (+cond), zh bf16
  hipLaunchKernelGGL((gemm_mfma_kernel<0, 1>), dim3(2 * cDI / 64, cBL / 128), dim3(256), 0, stream,
                     xnh, ipw, 2 * cDI, cC, ipb, flg, cond, (float*)xib, zh);
  // 5. xch = bf16(silu(dwconv(xib)))
  hipLaunchKernelGGL(dwconv_silu_kernel, dim3(dwBlocks), dim3(256), 0, stream,
                     xib, wcv, bcv, xch);
  // 6. x_proj (MFMA, bf16 A, scatter to padded scan rows)
  hipLaunchKernelGGL((gemm_mfma_kernel<1, 1>), dim3((cK * XROW + 63) / 64, cBL / 128), dim3(256), 0, stream,
                     xch, xpw, cK * XROW, cDI, (const void*)nullptr, flg,
                     (const float*)nullptr, xdbl, (unsigned short*)nullptr);
  // 7-9. chunked selective scan (2 channels/thread, single staging, coalesced
  //      ushort2 streams)
  hipLaunchKernelGGL(scan1_kernel, dim3(cB * cK * SEG), dim3(192), 0, stream,
                     xch, xdbl, dtw, dtb, alog, dsv, flg,
                     ysd0, ysd1, ysd2, ysd3, hendp, pendp);
  hipLaunchKernelGGL(scan2_kernel, dim3(cB * cK * cDI * cN / 256), dim3(256), 0, stream,
                     hendp, pendp);
  hipLaunchKernelGGL(scan3_kernel, dim3(cB * cK * SEG), dim3(192), 0, stream,
                     xdbl, dtw, dtb, alog, flg, hendp, ysd0, ysd1, ysd2, ysd3);
  // 10. merge: gather 4 dirs + out_norm + gate -> yg bf16
  hipLaunchKernelGGL(merge_kernel, dim3(cBL), dim3(128), 0, stream,
                     ysd0, ysd1, ysd2, ysd3, zh, ong, onb, flg, ygh);
  // 11. out_proj (bf16 A) + residual(x1) -> x2 fp32
  hipLaunchKernelGGL((gemm_mfma_kernel<2, 1>), dim3(cC / 64, cBL / 128), dim3(256), 0, stream,
                     ygh, opw, cC, cDI, (const void*)nullptr, flg, x1, x2,
                     (unsigned short*)nullptr);
  // 12. x3 = x2 + cpe2(x2)  (flg[2]=1 -> fp32 input path)
  hipLaunchKernelGGL(cpe_kernel, dim3(cpeBlocks), dim3(256), 0, stream,
                     x2, w2t, b2t, flg, 2, x3);
  // 13. xn2h = bf16(LN2(x3))
  hipLaunchKernelGGL(lnb_kernel, dim3(cBL / 4), dim3(256), 0, stream, x3, n2g, n2b, flg, xn2h);
  // 14. fc1 + gelu -> hbufh bf16 (MFMA, bf16 A)
  hipLaunchKernelGGL((gemm_mfma_kernel<3, 1>), dim3(cHID / 64, cBL / 128), dim3(256), 0, stream,
                     xn2h, f1w, cHID, cC, f1b, flg, (const float*)nullptr, (float*)hbufh,
                     (unsigned short*)nullptr);
  // 15. fc2 (bf16 A) + bias + residual(x3) -> d_out fp32 (MFMA)
  hipLaunchKernelGGL((gemm_mfma_kernel<4, 1>), dim3(cC / 64, cBL / 128), dim3(256), 0, stream,
                     hbufh, f2w, cC, cHID, f2b, flg, x3, (float*)d_out,
                     (unsigned short*)nullptr);
}

// Round 10
// 563.379 us; speedup vs baseline: 1.1386x; 1.1386x over previous
//
#include <hip/hip_runtime.h>
#include <hip/hip_bf16.h>

#define DEV __device__ __forceinline__

namespace {

constexpr int cB = 2, cT = 8, cH = 32, cW = 32, cC = 192;
constexpr int cDI = 384, cN = 16, cK = 4, cDTR = 12, cLT = 77, cHID = 768;
constexpr int cL  = cT * cH * cW;      // 8192
constexpr int cBL = cB * cL;           // 16384
constexpr int SEG = 128, SEGLEN = cL / SEG;   // 128 segments x 64 steps
constexpr int XROW = cDTR + 2 * cN;    // 44 live cols
constexpr int XSTR = 48;               // padded row stride (float4-aligned)

typedef __attribute__((ext_vector_type(8))) short bf16x8;
typedef __attribute__((ext_vector_type(4))) float f32x4;
typedef __attribute__((ext_vector_type(4))) short short4v;

// ---------- scalar helpers ----------
DEV float bfu2f(unsigned short u) { return __uint_as_float(((unsigned)u) << 16); }
DEV float ldsel(const void* p, size_t i, int f32) {
  return f32 ? ((const float*)p)[i] : bfu2f(((const unsigned short*)p)[i]);
}
template <int F32>
DEV float4 ld4(const void* p, size_t e) {   // e: element index, multiple of 4
  if (F32) return *(const float4*)((const float*)p + e);
  ushort4 u = *(const ushort4*)((const unsigned short*)p + e);
  return make_float4(bfu2f(u.x), bfu2f(u.y), bfu2f(u.z), bfu2f(u.w));
}
DEV short f2bf(float f) {   // RNE float->bf16 bits
  unsigned u = __float_as_uint(f);
  u += 0x7fffu + ((u >> 16) & 1u);
  return (short)(u >> 16);
}
DEV float siluf(float x) { return x / (1.f + __expf(-x)); }
DEV float softplusf(float x) { return (x > 20.f) ? x : __logf(1.f + __expf(x)); }
DEV float gelut(float x) {            // tanh-approx gelu (JAX default)
  float u = 0.7978845608028654f * (x + 0.044715f * x * x * x);
  float e = __expf(2.f * u);
  float th = 1.f - 2.f / (e + 1.f);
  return 0.5f * x * (1.f + th);
}

// ---------- dtype detector (validated: inputs are fp32) ----------
__global__ void __launch_bounds__(256) detect_kernel(
    const unsigned short* __restrict__ xa, const unsigned short* __restrict__ wp,
    int* __restrict__ flg) {
  __shared__ int cnt[2];
  if (threadIdx.x < 2) cnt[threadIdx.x] = 0;
  __syncthreads();
  int l0 = 0, l1 = 0;
  for (int i = threadIdx.x; i < 1024; i += 256) {
    float v = bfu2f(xa[2 * i]); float a = fabsf(v);
    if (v == 0.f || (a > 1e-8f && a < 1e4f)) l0++;
    float u = bfu2f(wp[2 * i]); float bq = fabsf(u);
    if (u == 0.f || (bq > 1e-8f && bq < 1e4f)) l1++;
  }
  atomicAdd(&cnt[0], l0); atomicAdd(&cnt[1], l1);
  __syncthreads();
  if (threadIdx.x == 0) {
    flg[0] = (cnt[0] < 614) ? 1 : 0;
    flg[1] = (cnt[1] < 614) ? 1 : 0;
    flg[2] = 1;
  }
}

// ---------- conv weight prep: transpose [Ch][27] -> [27][Ch] fp32, decode biases ----------
__global__ void __launch_bounds__(256) prep_kernel(
    const void* __restrict__ cvw, const void* __restrict__ cvb,
    const void* __restrict__ c1w, const void* __restrict__ c1b,
    const void* __restrict__ c2w, const void* __restrict__ c2b,
    const int* __restrict__ flg,
    float* __restrict__ wcv, float* __restrict__ bcv,
    float* __restrict__ w1, float* __restrict__ b1,
    float* __restrict__ w2, float* __restrict__ b2) {
  int pf = flg[1];
  int i = blockIdx.x * 256 + threadIdx.x;
  int r = i;
  if (r < 27 * cDI) { int j = r / cDI, d = r % cDI; wcv[r] = ldsel(cvw, (size_t)d * 27 + j, pf); return; }
  r -= 27 * cDI;
  if (r < cDI) { bcv[r] = ldsel(cvb, r, pf); return; }
  r -= cDI;
  if (r < 27 * cC) { int j = r / cC, c = r % cC; w1[r] = ldsel(c1w, (size_t)c * 27 + j, pf); return; }
  r -= 27 * cC;
  if (r < cC) { b1[r] = ldsel(c1b, r, pf); return; }
  r -= cC;
  if (r < 27 * cC) { int j = r / cC, c = r % cC; w2[r] = ldsel(c2w, (size_t)c * 27 + j, pf); return; }
  r -= 27 * cC;
  if (r < cC) { b2[r] = ldsel(c2b, r, pf); return; }
}

// ---------- CPE (depthwise 3x3x3 + residual), 2 adjacent-w voxels/thread ----------
// The 3-tap w-window overlaps between the two outputs: 4 column loads + 3
// weight loads per (dz,dy) serve both (was 6+6) -> ~40% less L2 traffic.
template <int F32>
DEV void cpe_body(const void* __restrict__ xin, const float* __restrict__ wT,
                  const float* __restrict__ bs, int idx, float* __restrict__ out) {
  int c = (idx % (cC / 4)) * 4; int pv = idx / (cC / 4);   // pv in [0, cBL/2)
  int w0 = (pv & 15) << 1;
  int rest = pv >> 4;
  int h = rest & 31; int bt = rest >> 5; int t = bt & 7; int b = bt >> 3;
  float4 bias = *(const float4*)(bs + c);
  float4 acc0 = bias, acc1 = bias;
  const float4 zero = make_float4(0.f, 0.f, 0.f, 0.f);
#pragma unroll
  for (int dz = 0; dz < 3; ++dz) {
    int tt = t + dz - 1; if ((unsigned)tt >= (unsigned)cT) continue;
#pragma unroll
    for (int dy = 0; dy < 3; ++dy) {
      int hh = h + dy - 1; if ((unsigned)hh >= (unsigned)cH) continue;
      int base = (tt << 10) + (hh << 5);
      const float* wr = wT + (dz * 9 + dy * 3) * cC + c;
      float4 wv0 = *(const float4*)(wr);
      float4 wv1 = *(const float4*)(wr + cC);
      float4 wv2 = *(const float4*)(wr + 2 * cC);
      size_t rb = ((size_t)b * cL + base) * cC + c;
      float4 xm1 = (w0 > 0)  ? ld4<F32>(xin, rb + (size_t)(w0 - 1) * cC) : zero;
      float4 x0v = ld4<F32>(xin, rb + (size_t)w0 * cC);
      float4 x1v = ld4<F32>(xin, rb + (size_t)(w0 + 1) * cC);
      float4 x2v = (w0 < 30) ? ld4<F32>(xin, rb + (size_t)(w0 + 2) * cC) : zero;
      acc0.x += wv0.x*xm1.x + wv1.x*x0v.x + wv2.x*x1v.x;
      acc0.y += wv0.y*xm1.y + wv1.y*x0v.y + wv2.y*x1v.y;
      acc0.z += wv0.z*xm1.z + wv1.z*x0v.z + wv2.z*x1v.z;
      acc0.w += wv0.w*xm1.w + wv1.w*x0v.w + wv2.w*x1v.w;
      acc1.x += wv0.x*x0v.x + wv1.x*x1v.x + wv2.x*x2v.x;
      acc1.y += wv0.y*x0v.y + wv1.y*x1v.y + wv2.y*x2v.y;
      acc1.z += wv0.z*x0v.z + wv1.z*x1v.z + wv2.z*x2v.z;
      acc1.w += wv0.w*x0v.w + wv1.w*x1v.w + wv2.w*x2v.w;
    }
  }
  size_t bv0 = (size_t)b * cL + (t << 10) + (h << 5) + w0;
  float4 r0 = ld4<F32>(xin, bv0 * cC + c);
  float4 r1 = ld4<F32>(xin, (bv0 + 1) * cC + c);
  *(float4*)(out + bv0 * cC + c) =
      make_float4(r0.x + acc0.x, r0.y + acc0.y, r0.z + acc0.z, r0.w + acc0.w);
  *(float4*)(out + (bv0 + 1) * cC + c) =
      make_float4(r1.x + acc1.x, r1.y + acc1.y, r1.z + acc1.z, r1.w + acc1.w);
}

__global__ void __launch_bounds__(256) cpe_kernel(
    const void* __restrict__ xin, const float* __restrict__ wT,
    const float* __restrict__ bs, const int* __restrict__ flg, int afidx,
    float* __restrict__ out) {
  int idx = blockIdx.x * 256 + threadIdx.x;
  if (idx >= cBL * cC / 8) return;
  if (flg[afidx]) cpe_body<1>(xin, wT, bs, idx, out);
  else            cpe_body<0>(xin, wT, bs, idx, out);
}

// ---------- depthwise conv on DI + SiLU: bf16 in/out, 2 adjacent-w voxels/thread ----------
__global__ void __launch_bounds__(256) dwconv_silu_kernel(
    const unsigned short* __restrict__ xin, const float* __restrict__ wT,
    const float* __restrict__ bs, unsigned short* __restrict__ out) {
  int idx = blockIdx.x * 256 + threadIdx.x;
  if (idx >= cBL * cDI / 8) return;
  int d = (idx % (cDI / 4)) * 4; int pv = idx / (cDI / 4);
  int w0 = (pv & 15) << 1;
  int rest = pv >> 4;
  int h = rest & 31; int bt = rest >> 5; int t = bt & 7; int b = bt >> 3;
  float4 bias = *(const float4*)(bs + d);
  float4 acc0 = bias, acc1 = bias;
  const float4 zero = make_float4(0.f, 0.f, 0.f, 0.f);
#pragma unroll
  for (int dz = 0; dz < 3; ++dz) {
    int tt = t + dz - 1; if ((unsigned)tt >= (unsigned)cT) continue;
#pragma unroll
    for (int dy = 0; dy < 3; ++dy) {
      int hh = h + dy - 1; if ((unsigned)hh >= (unsigned)cH) continue;
      int base = (tt << 10) + (hh << 5);
      const float* wr = wT + (dz * 9 + dy * 3) * cDI + d;
      float4 wv0 = *(const float4*)(wr);
      float4 wv1 = *(const float4*)(wr + cDI);
      float4 wv2 = *(const float4*)(wr + 2 * cDI);
      size_t rb = ((size_t)b * cL + base) * cDI + d;
      float4 xm1 = (w0 > 0)  ? ld4<0>(xin, rb + (size_t)(w0 - 1) * cDI) : zero;
      float4 x0v = ld4<0>(xin, rb + (size_t)w0 * cDI);
      float4 x1v = ld4<0>(xin, rb + (size_t)(w0 + 1) * cDI);
      float4 x2v = (w0 < 30) ? ld4<0>(xin, rb + (size_t)(w0 + 2) * cDI) : zero;
      acc0.x += wv0.x*xm1.x + wv1.x*x0v.x + wv2.x*x1v.x;
      acc0.y += wv0.y*xm1.y + wv1.y*x0v.y + wv2.y*x1v.y;
      acc0.z += wv0.z*xm1.z + wv1.z*x0v.z + wv2.z*x1v.z;
      acc0.w += wv0.w*xm1.w + wv1.w*x0v.w + wv2.w*x1v.w;
      acc1.x += wv0.x*x0v.x + wv1.x*x1v.x + wv2.x*x2v.x;
      acc1.y += wv0.y*x0v.y + wv1.y*x1v.y + wv2.y*x2v.y;
      acc1.z += wv0.z*x0v.z + wv1.z*x1v.z + wv2.z*x2v.z;
      acc1.w += wv0.w*x0v.w + wv1.w*x1v.w + wv2.w*x2v.w;
    }
  }
  size_t bv0 = (size_t)b * cL + (t << 10) + (h << 5) + w0;
  ushort4 o0, o1;
  o0.x = (unsigned short)f2bf(siluf(acc0.x));
  o0.y = (unsigned short)f2bf(siluf(acc0.y));
  o0.z = (unsigned short)f2bf(siluf(acc0.z));
  o0.w = (unsigned short)f2bf(siluf(acc0.w));
  o1.x = (unsigned short)f2bf(siluf(acc1.x));
  o1.y = (unsigned short)f2bf(siluf(acc1.y));
  o1.z = (unsigned short)f2bf(siluf(acc1.z));
  o1.w = (unsigned short)f2bf(siluf(acc1.w));
  *(ushort4*)(out + bv0 * cDI + d) = o0;
  *(ushort4*)(out + (bv0 + 1) * cDI + d) = o1;
}

// ---------- wave-per-row LayerNorm (C=192): no LDS, no barriers, bf16 out ----------
__global__ void __launch_bounds__(256) lnb_kernel(
    const float* __restrict__ in, const void* __restrict__ g,
    const void* __restrict__ bb, const int* __restrict__ flg,
    unsigned short* __restrict__ out) {
  int pf = flg[1];
  int row = blockIdx.x * 4 + (threadIdx.x >> 6);
  int lane = threadIdx.x & 63;
  const float* x = in + (size_t)row * cC;
  float v0 = x[lane], v1 = x[lane + 64], v2 = x[lane + 128];
  float s1 = v0 + v1 + v2;
  float s2 = v0 * v0 + v1 * v1 + v2 * v2;
#pragma unroll
  for (int off = 32; off > 0; off >>= 1) {
    s1 += __shfl_xor(s1, off);
    s2 += __shfl_xor(s2, off);
  }
  float mean = s1 * (1.f / cC);
  float var = s2 * (1.f / cC) - mean * mean;
  float rstd = rsqrtf(var + 1e-6f);
  unsigned short* o = out + (size_t)row * cC;
  o[lane]       = (unsigned short)f2bf((v0 - mean) * rstd * ldsel(g, lane, pf)       + ldsel(bb, lane, pf));
  o[lane + 64]  = (unsigned short)f2bf((v1 - mean) * rstd * ldsel(g, lane + 64, pf)  + ldsel(bb, lane + 64, pf));
  o[lane + 128] = (unsigned short)f2bf((v2 - mean) * rstd * ldsel(g, lane + 128, pf) + ldsel(bb, lane + 128, pf));
}

// ---------- text conditioning ----------
__global__ void __launch_bounds__(384) text_cond_kernel(
    const void* __restrict__ text, const void* __restrict__ tw,
    const void* __restrict__ tb, const int* __restrict__ flg,
    float* __restrict__ cond) {
  int af = flg[0], pf = flg[1];
  __shared__ float mean[cC];
  int b = blockIdx.x;
  for (int c = threadIdx.x; c < cC; c += 384) {
    float s = 0.f;
    for (int t = 0; t < cLT; ++t) s += ldsel(text, ((size_t)b * cLT + t) * cC + c, af);
    mean[c] = s * (1.f / cLT);
  }
  __syncthreads();
  int di = threadIdx.x;
  float a = ldsel(tb, di, pf);
  for (int c = 0; c < cC; ++c) a += mean[c] * ldsel(tw, di * cC + c, pf);
  cond[b * cDI + di] = siluf(a);
}

// ---------- MFMA GEMM: out = epilogue(A[M,K] @ W[N,K]^T), bf16 compute ----------
template <int MODE, int ABF>
__global__ void __launch_bounds__(256) gemm_mfma_kernel(
    const void* __restrict__ A, const void* __restrict__ W,
    int N, int K, const void* __restrict__ bias, const int* __restrict__ flg,
    const float* __restrict__ extra, float* __restrict__ out,
    unsigned short* __restrict__ out2) {
  constexpr int BM = 128, BN = 64, BK = 32, PK = 40;
  __shared__ short As[BM * PK];
  __shared__ short Bs[BN * PK];
  int pf = flg[1];
  int tid = threadIdx.x;
  int m0 = blockIdx.y * BM, n0 = blockIdx.x * BN;
  int lane = tid & 63, wv = tid >> 6;
  int wm = (wv >> 1) * 64, wn = (wv & 1) * 32;
  int lr = lane & 15, quad = lane >> 4;
  f32x4 acc[4][2];
#pragma unroll
  for (int mi = 0; mi < 4; ++mi)
#pragma unroll
    for (int ni = 0; ni < 2; ++ni) { acc[mi][ni][0]=0.f; acc[mi][ni][1]=0.f; acc[mi][ni][2]=0.f; acc[mi][ni][3]=0.f; }
  int ar = tid >> 1, aks = (tid & 1) * 16;
  int wr = tid >> 2, wks = (tid & 3) * 8;
  for (int k0 = 0; k0 < K; k0 += BK) {
    if (ABF) {
      const unsigned short* ap = (const unsigned short*)A + (size_t)(m0 + ar) * K + k0 + aks;
      short* da = &As[ar * PK + aks];
#pragma unroll
      for (int i = 0; i < 4; ++i)
        *(short4v*)(da + i * 4) = *(const short4v*)(ap + i * 4);
    } else {
      const float* ap = (const float*)A + (size_t)(m0 + ar) * K + k0 + aks;
      short* da = &As[ar * PK + aks];
#pragma unroll
      for (int i = 0; i < 4; ++i) {
        float4 v = ((const float4*)ap)[i];
        short4v h; h.x = f2bf(v.x); h.y = f2bf(v.y); h.z = f2bf(v.z); h.w = f2bf(v.w);
        *(short4v*)(da + i * 4) = h;
      }
    }
    {
      int nr = n0 + wr;
      short hb[8];
      if (nr < N) {
        size_t wi = (size_t)nr * K + k0 + wks;
        if (pf) {
#pragma unroll
          for (int i = 0; i < 8; ++i) hb[i] = f2bf(((const float*)W)[wi + i]);
        } else {
#pragma unroll
          for (int i = 0; i < 8; ++i) hb[i] = (short)((const unsigned short*)W)[wi + i];
        }
      } else {
#pragma unroll
        for (int i = 0; i < 8; ++i) hb[i] = 0;
      }
      short* db = &Bs[wr * PK + wks];
#pragma unroll
      for (int i = 0; i < 8; i += 4) {
        short4v h; h.x = hb[i]; h.y = hb[i+1]; h.z = hb[i+2]; h.w = hb[i+3];
        *(short4v*)(db + i) = h;
      }
    }
    __syncthreads();
    bf16x8 af[4], bfr[2];
#pragma unroll
    for (int mi = 0; mi < 4; ++mi)
      af[mi] = *(const bf16x8*)&As[(wm + mi * 16 + lr) * PK + quad * 8];
#pragma unroll
    for (int ni = 0; ni < 2; ++ni)
      bfr[ni] = *(const bf16x8*)&Bs[(wn + ni * 16 + lr) * PK + quad * 8];
#pragma unroll
    for (int mi = 0; mi < 4; ++mi)
#pragma unroll
      for (int ni = 0; ni < 2; ++ni)
        acc[mi][ni] = __builtin_amdgcn_mfma_f32_16x16x32_bf16(af[mi], bfr[ni], acc[mi][ni], 0, 0, 0);
    __syncthreads();
  }
#pragma unroll
  for (int mi = 0; mi < 4; ++mi) {
#pragma unroll
    for (int ni = 0; ni < 2; ++ni) {
#pragma unroll
      for (int r = 0; r < 4; ++r) {
        int m = m0 + wm + mi * 16 + quad * 4 + r;
        int n = n0 + wn + ni * 16 + lr;
        float v = acc[mi][ni][r];
        if (MODE == 0) {
          float bvv = ldsel(bias, n, pf);
          int b = m >> 13;
          if (n < cDI)
            ((unsigned short*)out)[(size_t)m * cDI + n] =
                (unsigned short)f2bf(v + bvv + extra[b * cDI + n]);
          else
            out2[(size_t)m * cDI + (n - cDI)] = (unsigned short)f2bf(v + bvv);
        } else if (MODE == 1) {
          if (n < cK * XROW) {
            int k = n / XROW, c = n - k * XROW;
            int b = m >> 13, vv = m & (cL - 1);
            int t = vv >> 10, q = vv & 1023, h = q >> 5, w = q & 31;
            int l1 = (t << 10) + (w << 5) + h;
            int lk = (k == 0) ? vv : (k == 1) ? l1 : (k == 2) ? (cL - 1 - vv) : (cL - 1 - l1);
            out[((size_t)(b * cK + k) * cL + lk) * XSTR + c] = v;
          }
        } else if (MODE == 2) {
          out[(size_t)m * cC + n] = v + extra[(size_t)m * cC + n];
        } else if (MODE == 3) {
          ((unsigned short*)out)[(size_t)m * cHID + n] =
              (unsigned short)f2bf(gelut(v + ldsel(bias, n, pf)));
        } else {
          out[(size_t)m * cC + n] = v + ldsel(bias, n, pf) + extra[(size_t)m * cC + n];
        }
      }
    }
  }
}

// voxel index for scan position l in direction k
DEV int scan_voxel(int k, int l) {
  if (k == 0) return l;
  if (k == 2) return cL - 1 - l;
  int ll = (k == 1) ? l : (cL - 1 - l);
  int t = ll >> 10, q = ll & 1023, w = q >> 5, h = q & 31;
  return (t << 10) + (h << 5) + w;
}

// ---------- register row structs (constant-indexed, SROA-friendly) ----------
struct Row11 { float4 r0, r1, r2, r3, r4, r5, r6, r7, r8, r9, r10; };
struct Row7  { float4 r0, r1, r2, r7, r8, r9, r10; };

DEV Row11 ldrow11(const float* __restrict__ rows, int st) {
  const float4* rp = (const float4*)(rows + st * XSTR);
  Row11 q;
  q.r0 = rp[0]; q.r1 = rp[1]; q.r2 = rp[2]; q.r3 = rp[3]; q.r4 = rp[4];
  q.r5 = rp[5]; q.r6 = rp[6]; q.r7 = rp[7]; q.r8 = rp[8]; q.r9 = rp[9];
  q.r10 = rp[10];
  return q;
}
DEV Row7 ldrow7(const float* __restrict__ rows, int st) {
  const float4* rp = (const float4*)(rows + st * XSTR);
  Row7 q;
  q.r0 = rp[0]; q.r1 = rp[1]; q.r2 = rp[2];
  q.r7 = rp[7]; q.r8 = rp[8]; q.r9 = rp[9]; q.r10 = rp[10];
  return q;
}

// one fast-path scan1 step: consumes q (row regs) + u, updates h/P1, returns y
DEV float s1step(const Row11& q, float u,
                 const float (&wdt)[cDTR], float dtb, float ac0, float Dsd,
                 float (&h)[cN], float& P1) {
  float s0 = dtb + q.r0.x*wdt[0] + q.r0.z*wdt[2] + q.r1.x*wdt[4] + q.r1.z*wdt[6] + q.r2.x*wdt[8] + q.r2.z*wdt[10];
  float s1 = q.r0.y*wdt[1] + q.r0.w*wdt[3] + q.r1.y*wdt[5] + q.r1.w*wdt[7] + q.r2.y*wdt[9] + q.r2.w*wdt[11];
  float dt = softplusf(s0 + s1);
  float a1 = exp2f(dt * ac0);
  float a2 = a1*a1, a3 = a2*a1, a4 = a2*a2;
  float a5 = a4*a1, a6 = a4*a2, a7 = a4*a3, a8 = a4*a4;
  float a9 = a8*a1, a10 = a8*a2, a11 = a8*a3, a12 = a8*a4;
  float a13 = a8*a5, a14 = a8*a6, a15 = a8*a7, a16 = a8*a8;
  float dtu = dt * u;
  P1 *= a1;
  float yp0 = Dsd * u, yp1 = 0.f, yp2 = 0.f, yp3 = 0.f;
  h[0]  = h[0] *a1  + dtu*q.r3.x; yp0 += h[0] *q.r7.x;
  h[1]  = h[1] *a2  + dtu*q.r3.y; yp1 += h[1] *q.r7.y;
  h[2]  = h[2] *a3  + dtu*q.r3.z; yp2 += h[2] *q.r7.z;
  h[3]  = h[3] *a4  + dtu*q.r3.w; yp3 += h[3] *q.r7.w;
  h[4]  = h[4] *a5  + dtu*q.r4.x; yp0 += h[4] *q.r8.x;
  h[5]  = h[5] *a6  + dtu*q.r4.y; yp1 += h[5] *q.r8.y;
  h[6]  = h[6] *a7  + dtu*q.r4.z; yp2 += h[6] *q.r8.z;
  h[7]  = h[7] *a8  + dtu*q.r4.w; yp3 += h[7] *q.r8.w;
  h[8]  = h[8] *a9  + dtu*q.r5.x; yp0 += h[8] *q.r9.x;
  h[9]  = h[9] *a10 + dtu*q.r5.y; yp1 += h[9] *q.r9.y;
  h[10] = h[10]*a11 + dtu*q.r5.z; yp2 += h[10]*q.r9.z;
  h[11] = h[11]*a12 + dtu*q.r5.w; yp3 += h[11]*q.r9.w;
  h[12] = h[12]*a13 + dtu*q.r6.x; yp0 += h[12]*q.r10.x;
  h[13] = h[13]*a14 + dtu*q.r6.y; yp1 += h[13]*q.r10.y;
  h[14] = h[14]*a15 + dtu*q.r6.z; yp2 += h[14]*q.r10.z;
  h[15] = h[15]*a16 + dtu*q.r6.w; yp3 += h[15]*q.r10.w;
  return (yp0 + yp1) + (yp2 + yp3);
}

// one fast-path scan3 step: evolves g, returns correction y
DEV float s3step(const Row7& q,
                 const float (&wdt)[cDTR], float dtb, float ac0,
                 float (&g)[cN]) {
  float s0 = dtb + q.r0.x*wdt[0] + q.r0.z*wdt[2] + q.r1.x*wdt[4] + q.r1.z*wdt[6] + q.r2.x*wdt[8] + q.r2.z*wdt[10];
  float s1 = q.r0.y*wdt[1] + q.r0.w*wdt[3] + q.r1.y*wdt[5] + q.r1.w*wdt[7] + q.r2.y*wdt[9] + q.r2.w*wdt[11];
  float dt = softplusf(s0 + s1);
  float a1 = exp2f(dt * ac0);
  float a2 = a1*a1, a3 = a2*a1, a4 = a2*a2;
  float a5 = a4*a1, a6 = a4*a2, a7 = a4*a3, a8 = a4*a4;
  float a9 = a8*a1, a10 = a8*a2, a11 = a8*a3, a12 = a8*a4;
  float a13 = a8*a5, a14 = a8*a6, a15 = a8*a7, a16 = a8*a8;
  float yp0 = 0.f, yp1 = 0.f, yp2 = 0.f, yp3 = 0.f;
  g[0]  *= a1;  yp0 += g[0] *q.r7.x;
  g[1]  *= a2;  yp1 += g[1] *q.r7.y;
  g[2]  *= a3;  yp2 += g[2] *q.r7.z;
  g[3]  *= a4;  yp3 += g[3] *q.r7.w;
  g[4]  *= a5;  yp0 += g[4] *q.r8.x;
  g[5]  *= a6;  yp1 += g[5] *q.r8.y;
  g[6]  *= a7;  yp2 += g[6] *q.r8.z;
  g[7]  *= a8;  yp3 += g[7] *q.r8.w;
  g[8]  *= a9;  yp0 += g[8] *q.r9.x;
  g[9]  *= a10; yp1 += g[9] *q.r9.y;
  g[10] *= a11; yp2 += g[10]*q.r9.z;
  g[11] *= a12; yp3 += g[11]*q.r9.w;
  g[12] *= a13; yp0 += g[12]*q.r10.x;
  g[13] *= a14; yp1 += g[13]*q.r10.y;
  g[14] *= a15; yp2 += g[14]*q.r10.z;
  g[15] *= a16; yp3 += g[15]*q.r10.w;
  return (yp0 + yp1) + (yp2 + yp3);
}

// ---------- scan pass 1 (r8 structure: 128 thr, 1 ch/thread, bf16 streams) ----------
__global__ void __launch_bounds__(128, 3) scan1_kernel(
    const unsigned short* __restrict__ xch, const float* __restrict__ xdbl,
    const void* __restrict__ dtw, const void* __restrict__ dtbv,
    const void* __restrict__ alog, const void* __restrict__ dsv,
    const int* __restrict__ flg,
    unsigned short* __restrict__ ys0, unsigned short* __restrict__ ys1,
    unsigned short* __restrict__ ys2, unsigned short* __restrict__ ys3,
    unsigned short* __restrict__ hend, unsigned short* __restrict__ pend) {
  __shared__ float rows[SEGLEN * XSTR];   // 64 x 48 floats = 12 KB
  int pf = flg[1];
  int tid = threadIdx.x;
  int d = blockIdx.x * 128 + tid;
  int bks = blockIdx.y;
  int s = bks & (SEG - 1); int bk = bks / SEG; int k = bk & 3; int b = bk >> 2;
  int l0 = s * SEGLEN;
  {
    const float4* src = (const float4*)(xdbl + ((size_t)bk * cL + l0) * XSTR);
    float4* dst = (float4*)rows;
#pragma unroll
    for (int i = 0; i < (SEGLEN * XSTR / 4) / 128; ++i)   // 6 iters
      dst[tid + i * 128] = src[tid + i * 128];
  }
  float wdt[cDTR];
#pragma unroll
  for (int r = 0; r < cDTR; ++r) wdt[r] = ldsel(dtw, (size_t)(k * cDI + d) * cDTR + r, pf);
  float dtb = ldsel(dtbv, k * cDI + d, pf);
  float ac[cN];
#pragma unroll
  for (int n = 0; n < cN; ++n)
    ac[n] = -__expf(ldsel(alog, (size_t)(k * cDI + d) * cN + n, pf)) * 1.4426950408889634f;
  bool fast = true;
#pragma unroll
  for (int n = 1; n < cN; ++n)
    fast = fast && (fabsf(ac[n] - (float)(n + 1) * ac[0]) <= 1e-3f * fabsf(ac[n]));
  float Dsd = ldsel(dsv, k * cDI + d, pf);
  float h[cN];
#pragma unroll
  for (int n = 0; n < cN; ++n) h[n] = 0.f;
  size_t so = ((size_t)bks * cDI + d) * cN;
  const unsigned short* xcb = xch + (size_t)b * cL * cDI + d;
  unsigned short* ysk = (k == 0) ? ys0 : (k == 1) ? ys1 : (k == 2) ? ys2 : ys3;
  unsigned short* ysrow = ysk + ((size_t)b * cL + l0) * cDI + d;
  __syncthreads();
  if (fast) {
    float ac0 = ac[0];
    float P1 = 1.f;
    Row11 qa = ldrow11(rows, 0);
    float u0 = bfu2f(xcb[(size_t)scan_voxel(k, l0) * cDI]);
    float u1 = bfu2f(xcb[(size_t)scan_voxel(k, l0 + 1) * cDI]);
    for (int st = 0; st < SEGLEN; st += 2) {
      Row11 qb = ldrow11(rows, st + 1);
      int p2 = (st + 2 < SEGLEN) ? st + 2 : SEGLEN - 1;
      int p3 = (st + 3 < SEGLEN) ? st + 3 : SEGLEN - 1;
      float nu0 = bfu2f(xcb[(size_t)scan_voxel(k, l0 + p2) * cDI]);
      float nu1 = bfu2f(xcb[(size_t)scan_voxel(k, l0 + p3) * cDI]);
      float ya = s1step(qa, u0, wdt, dtb, ac0, Dsd, h, P1);
      ysrow[(size_t)st * cDI] = (unsigned short)f2bf(ya);
      qa = ldrow11(rows, p2);
      float yb = s1step(qb, u1, wdt, dtb, ac0, Dsd, h, P1);
      ysrow[(size_t)(st + 1) * cDI] = (unsigned short)f2bf(yb);
      u0 = nu0; u1 = nu1;
    }
    float pp = P1;
#pragma unroll
    for (int n = 0; n < cN; ++n) {
      hend[so + n] = (unsigned short)f2bf(h[n]);
      pend[so + n] = (unsigned short)f2bf(pp);
      pp *= P1;
    }
  } else {
    float P[cN];
#pragma unroll
    for (int n = 0; n < cN; ++n) P[n] = 1.f;
    for (int st = 0; st < SEGLEN; ++st) {
      int l = l0 + st;
      const float4* rp = (const float4*)(rows + st * XSTR);
      float4 q0 = rp[0], q1 = rp[1], q2 = rp[2];
      float s0 = dtb + q0.x*wdt[0] + q0.z*wdt[2] + q1.x*wdt[4] + q1.z*wdt[6] + q2.x*wdt[8] + q2.z*wdt[10];
      float s1 = q0.y*wdt[1] + q0.w*wdt[3] + q1.y*wdt[5] + q1.w*wdt[7] + q2.y*wdt[9] + q2.w*wdt[11];
      float dt = softplusf(s0 + s1);
      float Bv[cN], Cv[cN];
      float4 qb0 = rp[3], qb1 = rp[4], qb2 = rp[5], qb3 = rp[6];
      float4 qc0 = rp[7], qc1 = rp[8], qc2 = rp[9], qc3 = rp[10];
      Bv[0]=qb0.x; Bv[1]=qb0.y; Bv[2]=qb0.z; Bv[3]=qb0.w;
      Bv[4]=qb1.x; Bv[5]=qb1.y; Bv[6]=qb1.z; Bv[7]=qb1.w;
      Bv[8]=qb2.x; Bv[9]=qb2.y; Bv[10]=qb2.z; Bv[11]=qb2.w;
      Bv[12]=qb3.x; Bv[13]=qb3.y; Bv[14]=qb3.z; Bv[15]=qb3.w;
      Cv[0]=qc0.x; Cv[1]=qc0.y; Cv[2]=qc0.z; Cv[3]=qc0.w;
      Cv[4]=qc1.x; Cv[5]=qc1.y; Cv[6]=qc1.z; Cv[7]=qc1.w;
      Cv[8]=qc2.x; Cv[9]=qc2.y; Cv[10]=qc2.z; Cv[11]=qc2.w;
      Cv[12]=qc3.x; Cv[13]=qc3.y; Cv[14]=qc3.z; Cv[15]=qc3.w;
      int v = scan_voxel(k, l);
      float u = bfu2f(xcb[(size_t)v * cDI]);
      float dtu = dt * u;
      float y = Dsd * u;
#pragma unroll
      for (int n = 0; n < cN; ++n) {
        float a = exp2f(dt * ac[n]);
        h[n] = h[n] * a + dtu * Bv[n];
        P[n] *= a;
        y += h[n] * Cv[n];
      }
      ysrow[(size_t)st * cDI] = (unsigned short)f2bf(y);
    }
#pragma unroll
    for (int n = 0; n < cN; ++n) {
      hend[so + n] = (unsigned short)f2bf(h[n]);
      pend[so + n] = (unsigned short)f2bf(P[n]);
    }
  }
}

// ---------- scan pass 2 (serial prefix over segments; fp32 recurrence, bf16 storage) ----------
__global__ void __launch_bounds__(256) scan2_kernel(
    unsigned short* __restrict__ hend, const unsigned short* __restrict__ pend) {
  int tid = blockIdx.x * 256 + threadIdx.x;
  int bk = tid / (cDI * cN); int r = tid - bk * (cDI * cN);
  float g = 0.f;
  for (int s = 0; s < SEG; ++s) {
    size_t o = ((size_t)(bk * SEG + s) * cDI * cN) + r;
    float he = bfu2f(hend[o]), pe = bfu2f(pend[o]);
    hend[o] = (unsigned short)f2bf(g);
    g = pe * g + he;
  }
}

// ---------- scan pass 3 (owned read-add-store on l-ordered rows; no atomics) ----------
__global__ void __launch_bounds__(128, 3) scan3_kernel(
    const float* __restrict__ xdbl,
    const void* __restrict__ dtw, const void* __restrict__ dtbv,
    const void* __restrict__ alog, const int* __restrict__ flg,
    const unsigned short* __restrict__ hin,
    unsigned short* __restrict__ ys0, unsigned short* __restrict__ ys1,
    unsigned short* __restrict__ ys2, unsigned short* __restrict__ ys3) {
  int bks = blockIdx.y;
  int s = bks & (SEG - 1);
  if (s == 0) return;
  __shared__ float rows[SEGLEN * XSTR];
  int pf = flg[1];
  int tid = threadIdx.x;
  int d = blockIdx.x * 128 + tid;
  int bk = bks / SEG; int k = bk & 3; int b = bk >> 2;
  int l0 = s * SEGLEN;
  {
    const float4* src = (const float4*)(xdbl + ((size_t)bk * cL + l0) * XSTR);
    float4* dst = (float4*)rows;
#pragma unroll
    for (int i = 0; i < (SEGLEN * XSTR / 4) / 128; ++i)
      dst[tid + i * 128] = src[tid + i * 128];
  }
  float wdt[cDTR];
#pragma unroll
  for (int r = 0; r < cDTR; ++r) wdt[r] = ldsel(dtw, (size_t)(k * cDI + d) * cDTR + r, pf);
  float dtb = ldsel(dtbv, k * cDI + d, pf);
  float ac[cN];
#pragma unroll
  for (int n = 0; n < cN; ++n)
    ac[n] = -__expf(ldsel(alog, (size_t)(k * cDI + d) * cN + n, pf)) * 1.4426950408889634f;
  bool fast = true;
#pragma unroll
  for (int n = 1; n < cN; ++n)
    fast = fast && (fabsf(ac[n] - (float)(n + 1) * ac[0]) <= 1e-3f * fabsf(ac[n]));
  float g[cN];
  size_t so = ((size_t)bks * cDI + d) * cN;
#pragma unroll
  for (int n = 0; n < cN; ++n) g[n] = bfu2f(hin[so + n]);
  unsigned short* ysk = (k == 0) ? ys0 : (k == 1) ? ys1 : (k == 2) ? ys2 : ys3;
  unsigned short* ysrow = ysk + ((size_t)b * cL + l0) * cDI + d;
  __syncthreads();
  if (fast) {
    float ac0 = ac[0];
    Row7 qa = ldrow7(rows, 0);
    for (int st = 0; st < SEGLEN; st += 2) {
      Row7 qb = ldrow7(rows, st + 1);
      int p2 = (st + 2 < SEGLEN) ? st + 2 : SEGLEN - 1;
      float ya = s3step(qa, wdt, dtb, ac0, g);
      size_t ia = (size_t)st * cDI;
      ysrow[ia] = (unsigned short)f2bf(bfu2f(ysrow[ia]) + ya);
      qa = ldrow7(rows, p2);
      float yb = s3step(qb, wdt, dtb, ac0, g);
      size_t ib = (size_t)(st + 1) * cDI;
      ysrow[ib] = (unsigned short)f2bf(bfu2f(ysrow[ib]) + yb);
    }
  } else {
    for (int st = 0; st < SEGLEN; ++st) {
      const float4* rp = (const float4*)(rows + st * XSTR);
      float4 q0 = rp[0], q1 = rp[1], q2 = rp[2];
      float s0 = dtb + q0.x*wdt[0] + q0.z*wdt[2] + q1.x*wdt[4] + q1.z*wdt[6] + q2.x*wdt[8] + q2.z*wdt[10];
      float s1 = q0.y*wdt[1] + q0.w*wdt[3] + q1.y*wdt[5] + q1.w*wdt[7] + q2.y*wdt[9] + q2.w*wdt[11];
      float dt = softplusf(s0 + s1);
      float Cv[cN];
      float4 qc0 = rp[7], qc1 = rp[8], qc2 = rp[9], qc3 = rp[10];
      Cv[0]=qc0.x; Cv[1]=qc0.y; Cv[2]=qc0.z; Cv[3]=qc0.w;
      Cv[4]=qc1.x; Cv[5]=qc1.y; Cv[6]=qc1.z; Cv[7]=qc1.w;
      Cv[8]=qc2.x; Cv[9]=qc2.y; Cv[10]=qc2.z; Cv[11]=qc2.w;
      Cv[12]=qc3.x; Cv[13]=qc3.y; Cv[14]=qc3.z; Cv[15]=qc3.w;
      float y = 0.f;
#pragma unroll
      for (int n = 0; n < cN; ++n) {
        float a = exp2f(dt * ac[n]);
        g[n] *= a;
        y += g[n] * Cv[n];
      }
      size_t ii = (size_t)st * cDI;
      ysrow[ii] = (unsigned short)f2bf(bfu2f(ysrow[ii]) + y);
    }
  }
}

// ---------- merge: wave-per-row gather of 4 dirs + out_norm LN + silu(z) gate ----------
__global__ void __launch_bounds__(256) merge_kernel(
    const unsigned short* __restrict__ ys0, const unsigned short* __restrict__ ys1,
    const unsigned short* __restrict__ ys2, const unsigned short* __restrict__ ys3,
    const unsigned short* __restrict__ zh,
    const void* __restrict__ ong, const void* __restrict__ onb,
    const int* __restrict__ flg, unsigned short* __restrict__ yg) {
  int pf = flg[1];
  int bv = blockIdx.x * 4 + (threadIdx.x >> 6);
  int lane = threadIdx.x & 63;
  int v = bv & (cL - 1); int b = bv >> 13;
  int t = v >> 10, q = v & 1023, hh = q >> 5, ww = q & 31;
  int l1 = (t << 10) + (ww << 5) + hh;
  size_t r0 = ((size_t)b * cL + v) * cDI;
  size_t r1 = ((size_t)b * cL + l1) * cDI;
  size_t r2 = ((size_t)b * cL + (cL - 1 - v)) * cDI;
  size_t r3 = ((size_t)b * cL + (cL - 1 - l1)) * cDI;
  float vals[6]; float s1 = 0.f, s2 = 0.f;
#pragma unroll
  for (int i = 0; i < 6; ++i) {
    int d = lane + i * 64;
    float x = bfu2f(ys0[r0 + d]) + bfu2f(ys1[r1 + d]) +
              bfu2f(ys2[r2 + d]) + bfu2f(ys3[r3 + d]);
    vals[i] = x; s1 += x; s2 += x * x;
  }
#pragma unroll
  for (int off = 32; off > 0; off >>= 1) {
    s1 += __shfl_xor(s1, off);
    s2 += __shfl_xor(s2, off);
  }
  float mean = s1 * (1.f / cDI);
  float var = s2 * (1.f / cDI) - mean * mean;
  float rstd = rsqrtf(var + 1e-6f);
  const unsigned short* zr = zh + (size_t)bv * cDI;
  unsigned short* og = yg + (size_t)bv * cDI;
#pragma unroll
  for (int i = 0; i < 6; ++i) {
    int d = lane + i * 64;
    float xn = (vals[i] - mean) * rstd * ldsel(ong, d, pf) + ldsel(onb, d, pf);
    og[d] = (unsigned short)f2bf(xn * siluf(bfu2f(zr[d])));
  }
}

}  // namespace

extern "C" void kernel_launch(void* const* d_in, const int* in_sizes, int n_in,
                              void* d_out, int out_size, void* d_ws, size_t ws_size,
                              hipStream_t stream) {
  (void)in_sizes; (void)n_in; (void)out_size; (void)ws_size;
  const void* x    = d_in[0];
  const void* text = d_in[1];
  const void* c1w  = d_in[2];
  const void* c1b  = d_in[3];
  const void* c2w  = d_in[4];
  const void* c2b  = d_in[5];
  const void* n1g  = d_in[6];
  const void* n1b  = d_in[7];
  const void* n2g  = d_in[8];
  const void* n2b  = d_in[9];
  const void* ipw  = d_in[10];
  const void* ipb  = d_in[11];
  const void* tpw  = d_in[12];
  const void* tpb  = d_in[13];
  const void* cvw  = d_in[14];
  const void* cvb  = d_in[15];
  const void* xpw  = d_in[16];
  const void* dtw  = d_in[17];
  const void* dtb  = d_in[18];
  const void* alog = d_in[19];
  const void* dsv  = d_in[20];
  const void* ong  = d_in[21];
  const void* onb  = d_in[22];
  const void* opw  = d_in[23];
  const void* f1w  = d_in[24];
  const void* f1b  = d_in[25];
  const void* f2w  = d_in[26];
  const void* f2b  = d_in[27];

  float* Wf = (float*)d_ws;

  // ---- slot arena (~125.9 MB), atomic-free scan + bf16 activations ----
  constexpr size_t oC  = 0;                              // 6,291,456
  constexpr size_t oD  = 6291456;                        // 3,145,728
  constexpr size_t oG  = 9437184;                        // 3,145,728
  constexpr size_t oA  = 12582912;                       // 6,291,456
  constexpr size_t oB  = 18874368;                       // 6,291,456
  constexpr size_t oE  = 25165824;                       // 3,145,728
  constexpr size_t oF  = 28311552;                       // 3,145,728
  constexpr size_t oCO = 31457280;                       // 768 (cond)
  constexpr size_t oFL = 31458048;                       // 4 ints (flags)
  constexpr size_t oWCV = 31458052;                      // 27*384
  constexpr size_t oBCV = 31468420;                      // 384
  constexpr size_t oW1  = 31468804;                      // 27*192
  constexpr size_t oB1  = 31473988;                      // 192
  constexpr size_t oW2  = 31474180;                      // 5184
  constexpr size_t oB2  = 31479364;                      // 192 -> end 31479556
  unsigned short* xch = (unsigned short*)(Wf + oC);            // bf16 silu(dwconv)
  unsigned short* ysd2 = (unsigned short*)(Wf + oC + 3145728); // ystream dir 2
  unsigned short* hbufh = (unsigned short*)(Wf + oC);          // fc1 out bf16
  float* xdbl = Wf + oD;
  unsigned short* ygh  = (unsigned short*)(Wf + oD);           // yg bf16 (after xdbl dead)
  unsigned short* xnh  = (unsigned short*)(Wf + oG);           // LN1 out bf16
  unsigned short* pendp = (unsigned short*)(Wf + oG);          // bf16, after xnh dead
  unsigned short* xib  = (unsigned short*)(Wf + oA);           // in_proj x-half bf16
  unsigned short* ysd0 = (unsigned short*)(Wf + oA);           // ystream dir 0 (xib dead)
  unsigned short* ysd1 = (unsigned short*)(Wf + oA + 3145728); // ystream dir 1
  float* x2   = Wf + oA;   // out_proj output (after ystream dead)
  unsigned short* zh   = (unsigned short*)(Wf + oB);           // z bf16
  unsigned short* ysd3 = (unsigned short*)(Wf + oB + 3145728); // ystream dir 3
  float* x3   = Wf + oB;
  float* x1   = Wf + oE;
  unsigned short* hendp = (unsigned short*)(Wf + oF);          // bf16
  unsigned short* xn2h = (unsigned short*)(Wf + oF);           // LN2 out bf16 (hend dead)
  float* cond = Wf + oCO;
  int*   flg  = (int*)(Wf + oFL);
  float* wcv = Wf + oWCV; float* bcv = Wf + oBCV;
  float* w1t = Wf + oW1;  float* b1t = Wf + oB1;
  float* w2t = Wf + oW2;  float* b2t = Wf + oB2;

  const int cpeBlocks = (cBL * cC / 8) / 256;     // 1536 (2 voxels/thread)
  const int dwBlocks  = (cBL * cDI / 8) / 256;    // 3072 (2 voxels/thread)

  // 0. dtype detection + conv weight prep
  hipLaunchKernelGGL(detect_kernel, dim3(1), dim3(256), 0, stream,
                     (const unsigned short*)x, (const unsigned short*)ipw, flg);
  hipLaunchKernelGGL(prep_kernel, dim3(85), dim3(256), 0, stream,
                     cvw, cvb, c1w, c1b, c2w, c2b, flg, wcv, bcv, w1t, b1t, w2t, b2t);
  // 1. x1 = x + cpe1(x)
  hipLaunchKernelGGL(cpe_kernel, dim3(cpeBlocks), dim3(256), 0, stream,
                     x, w1t, b1t, flg, 0, x1);
  // 2. xnh = bf16(LN1(x1))  (wave-per-row, no barriers)
  hipLaunchKernelGGL(lnb_kernel, dim3(cBL / 4), dim3(256), 0, stream, x1, n1g, n1b, flg, xnh);
  // 3. cond
  hipLaunchKernelGGL(text_cond_kernel, dim3(cB), dim3(384), 0, stream, text, tpw, tpb, flg, cond);
  // 4. in_proj (MFMA, bf16 A): xnh -> xib bf16 (+cond), zh bf16
  hipLaunchKernelGGL((gemm_mfma_kernel<0, 1>), dim3(2 * cDI / 64, cBL / 128), dim3(256), 0, stream,
                     xnh, ipw, 2 * cDI, cC, ipb, flg, cond, (float*)xib, zh);
  // 5. xch = bf16(silu(dwconv(xib)))
  hipLaunchKernelGGL(dwconv_silu_kernel, dim3(dwBlocks), dim3(256), 0, stream,
                     xib, wcv, bcv, xch);
  // 6. x_proj (MFMA, bf16 A, scatter to padded scan rows)
  hipLaunchKernelGGL((gemm_mfma_kernel<1, 1>), dim3((cK * XROW + 63) / 64, cBL / 128), dim3(256), 0, stream,
                     xch, xpw, cK * XROW, cDI, (const void*)nullptr, flg,
                     (const float*)nullptr, xdbl, (unsigned short*)nullptr);
  // 7-9. chunked selective scan (r8 structure: 128 thr, bf16 streams)
  hipLaunchKernelGGL(scan1_kernel, dim3(cDI / 128, cB * cK * SEG), dim3(128), 0, stream,
                     xch, xdbl, dtw, dtb, alog, dsv, flg,
                     ysd0, ysd1, ysd2, ysd3, hendp, pendp);
  hipLaunchKernelGGL(scan2_kernel, dim3(cB * cK * cDI * cN / 256), dim3(256), 0, stream,
                     hendp, pendp);
  hipLaunchKernelGGL(scan3_kernel, dim3(cDI / 128, cB * cK * SEG), dim3(128), 0, stream,
                     xdbl, dtw, dtb, alog, flg, hendp, ysd0, ysd1, ysd2, ysd3);
  // 10. merge: wave-per-row gather + out_norm + gate -> yg bf16
  hipLaunchKernelGGL(merge_kernel, dim3(cBL / 4), dim3(256), 0, stream,
                     ysd0, ysd1, ysd2, ysd3, zh, ong, onb, flg, ygh);
  // 11. out_proj (bf16 A) + residual(x1) -> x2 fp32
  hipLaunchKernelGGL((gemm_mfma_kernel<2, 1>), dim3(cC / 64, cBL / 128), dim3(256), 0, stream,
                     ygh, opw, cC, cDI, (const void*)nullptr, flg, x1, x2,
                     (unsigned short*)nullptr);
  // 12. x3 = x2 + cpe2(x2)  (flg[2]=1 -> fp32 input path)
  hipLaunchKernelGGL(cpe_kernel, dim3(cpeBlocks), dim3(256), 0, stream,
                     x2, w2t, b2t, flg, 2, x3);
  // 13. xn2h = bf16(LN2(x3))
  hipLaunchKernelGGL(lnb_kernel, dim3(cBL / 4), dim3(256), 0, stream, x3, n2g, n2b, flg, xn2h);
  // 14. fc1 + gelu -> hbufh bf16 (MFMA, bf16 A)
  hipLaunchKernelGGL((gemm_mfma_kernel<3, 1>), dim3(cHID / 64, cBL / 128), dim3(256), 0, stream,
                     xn2h, f1w, cHID, cC, f1b, flg, (const float*)nullptr, (float*)hbufh,
                     (unsigned short*)nullptr);
  // 15. fc2 (bf16 A) + bias + residual(x3) -> d_out fp32 (MFMA)
  hipLaunchKernelGGL((gemm_mfma_kernel<4, 1>), dim3(cC / 64, cBL / 128), dim3(256), 0, stream,
                     hbufh, f2w, cC, cHID, f2b, flg, x3, (float*)d_out,
                     (unsigned short*)nullptr);
}

// Round 11
// 552.167 us; speedup vs baseline: 1.1617x; 1.0203x over previous
//
#include <hip/hip_runtime.h>
#include <hip/hip_bf16.h>

#define DEV __device__ __forceinline__

namespace {

constexpr int cB = 2, cT = 8, cH = 32, cW = 32, cC = 192;
constexpr int cDI = 384, cN = 16, cK = 4, cDTR = 12, cLT = 77, cHID = 768;
constexpr int cL  = cT * cH * cW;      // 8192
constexpr int cBL = cB * cL;           // 16384
constexpr int SEG = 128, SEGLEN = cL / SEG;   // 128 segments x 64 steps
constexpr int XROW = cDTR + 2 * cN;    // 44 live cols
constexpr int XSTR = 48;               // padded row stride (float4-aligned)

typedef __attribute__((ext_vector_type(8))) short bf16x8;
typedef __attribute__((ext_vector_type(4))) float f32x4;
typedef __attribute__((ext_vector_type(2))) float f32x2;
typedef __attribute__((ext_vector_type(4))) short short4v;

// ---------- scalar helpers ----------
DEV float bfu2f(unsigned short u) { return __uint_as_float(((unsigned)u) << 16); }
DEV float ldsel(const void* p, size_t i, int f32) {
  return f32 ? ((const float*)p)[i] : bfu2f(((const unsigned short*)p)[i]);
}
template <int F32>
DEV float4 ld4(const void* p, size_t e) {   // e: element index, multiple of 4
  if (F32) return *(const float4*)((const float*)p + e);
  ushort4 u = *(const ushort4*)((const unsigned short*)p + e);
  return make_float4(bfu2f(u.x), bfu2f(u.y), bfu2f(u.z), bfu2f(u.w));
}
DEV short f2bf(float f) {   // RNE float->bf16 bits
  unsigned u = __float_as_uint(f);
  u += 0x7fffu + ((u >> 16) & 1u);
  return (short)(u >> 16);
}
DEV float siluf(float x) { return x / (1.f + __expf(-x)); }
DEV float softplusf(float x) { return (x > 20.f) ? x : __logf(1.f + __expf(x)); }
DEV float gelut(float x) {            // tanh-approx gelu (JAX default)
  float u = 0.7978845608028654f * (x + 0.044715f * x * x * x);
  float e = __expf(2.f * u);
  float th = 1.f - 2.f / (e + 1.f);
  return 0.5f * x * (1.f + th);
}
DEV f32x2 mk2(float a, float b) { f32x2 v; v[0] = a; v[1] = b; return v; }

// ---------- dtype detector (validated: inputs are fp32) ----------
__global__ void __launch_bounds__(256) detect_kernel(
    const unsigned short* __restrict__ xa, const unsigned short* __restrict__ wp,
    int* __restrict__ flg) {
  __shared__ int cnt[2];
  if (threadIdx.x < 2) cnt[threadIdx.x] = 0;
  __syncthreads();
  int l0 = 0, l1 = 0;
  for (int i = threadIdx.x; i < 1024; i += 256) {
    float v = bfu2f(xa[2 * i]); float a = fabsf(v);
    if (v == 0.f || (a > 1e-8f && a < 1e4f)) l0++;
    float u = bfu2f(wp[2 * i]); float bq = fabsf(u);
    if (u == 0.f || (bq > 1e-8f && bq < 1e4f)) l1++;
  }
  atomicAdd(&cnt[0], l0); atomicAdd(&cnt[1], l1);
  __syncthreads();
  if (threadIdx.x == 0) {
    flg[0] = (cnt[0] < 614) ? 1 : 0;
    flg[1] = (cnt[1] < 614) ? 1 : 0;
    flg[2] = 1;
  }
}

// ---------- conv weight prep: transpose [Ch][27] -> [27][Ch] fp32, decode biases ----------
__global__ void __launch_bounds__(256) prep_kernel(
    const void* __restrict__ cvw, const void* __restrict__ cvb,
    const void* __restrict__ c1w, const void* __restrict__ c1b,
    const void* __restrict__ c2w, const void* __restrict__ c2b,
    const int* __restrict__ flg,
    float* __restrict__ wcv, float* __restrict__ bcv,
    float* __restrict__ w1, float* __restrict__ b1,
    float* __restrict__ w2, float* __restrict__ b2) {
  int pf = flg[1];
  int i = blockIdx.x * 256 + threadIdx.x;
  int r = i;
  if (r < 27 * cDI) { int j = r / cDI, d = r % cDI; wcv[r] = ldsel(cvw, (size_t)d * 27 + j, pf); return; }
  r -= 27 * cDI;
  if (r < cDI) { bcv[r] = ldsel(cvb, r, pf); return; }
  r -= cDI;
  if (r < 27 * cC) { int j = r / cC, c = r % cC; w1[r] = ldsel(c1w, (size_t)c * 27 + j, pf); return; }
  r -= 27 * cC;
  if (r < cC) { b1[r] = ldsel(c1b, r, pf); return; }
  r -= cC;
  if (r < 27 * cC) { int j = r / cC, c = r % cC; w2[r] = ldsel(c2w, (size_t)c * 27 + j, pf); return; }
  r -= 27 * cC;
  if (r < cC) { b2[r] = ldsel(c2b, r, pf); return; }
}

// ---------- CPE (depthwise 3x3x3 + residual), 2 adjacent-w voxels/thread ----------
template <int F32>
DEV void cpe_body(const void* __restrict__ xin, const float* __restrict__ wT,
                  const float* __restrict__ bs, int idx, float* __restrict__ out) {
  int c = (idx % (cC / 4)) * 4; int pv = idx / (cC / 4);   // pv in [0, cBL/2)
  int w0 = (pv & 15) << 1;
  int rest = pv >> 4;
  int h = rest & 31; int bt = rest >> 5; int t = bt & 7; int b = bt >> 3;
  float4 bias = *(const float4*)(bs + c);
  float4 acc0 = bias, acc1 = bias;
  const float4 zero = make_float4(0.f, 0.f, 0.f, 0.f);
#pragma unroll
  for (int dz = 0; dz < 3; ++dz) {
    int tt = t + dz - 1; if ((unsigned)tt >= (unsigned)cT) continue;
#pragma unroll
    for (int dy = 0; dy < 3; ++dy) {
      int hh = h + dy - 1; if ((unsigned)hh >= (unsigned)cH) continue;
      int base = (tt << 10) + (hh << 5);
      const float* wr = wT + (dz * 9 + dy * 3) * cC + c;
      float4 wv0 = *(const float4*)(wr);
      float4 wv1 = *(const float4*)(wr + cC);
      float4 wv2 = *(const float4*)(wr + 2 * cC);
      size_t rb = ((size_t)b * cL + base) * cC + c;
      float4 xm1 = (w0 > 0)  ? ld4<F32>(xin, rb + (size_t)(w0 - 1) * cC) : zero;
      float4 x0v = ld4<F32>(xin, rb + (size_t)w0 * cC);
      float4 x1v = ld4<F32>(xin, rb + (size_t)(w0 + 1) * cC);
      float4 x2v = (w0 < 30) ? ld4<F32>(xin, rb + (size_t)(w0 + 2) * cC) : zero;
      acc0.x += wv0.x*xm1.x + wv1.x*x0v.x + wv2.x*x1v.x;
      acc0.y += wv0.y*xm1.y + wv1.y*x0v.y + wv2.y*x1v.y;
      acc0.z += wv0.z*xm1.z + wv1.z*x0v.z + wv2.z*x1v.z;
      acc0.w += wv0.w*xm1.w + wv1.w*x0v.w + wv2.w*x1v.w;
      acc1.x += wv0.x*x0v.x + wv1.x*x1v.x + wv2.x*x2v.x;
      acc1.y += wv0.y*x0v.y + wv1.y*x1v.y + wv2.y*x2v.y;
      acc1.z += wv0.z*x0v.z + wv1.z*x1v.z + wv2.z*x2v.z;
      acc1.w += wv0.w*x0v.w + wv1.w*x1v.w + wv2.w*x2v.w;
    }
  }
  size_t bv0 = (size_t)b * cL + (t << 10) + (h << 5) + w0;
  float4 r0 = ld4<F32>(xin, bv0 * cC + c);
  float4 r1 = ld4<F32>(xin, (bv0 + 1) * cC + c);
  *(float4*)(out + bv0 * cC + c) =
      make_float4(r0.x + acc0.x, r0.y + acc0.y, r0.z + acc0.z, r0.w + acc0.w);
  *(float4*)(out + (bv0 + 1) * cC + c) =
      make_float4(r1.x + acc1.x, r1.y + acc1.y, r1.z + acc1.z, r1.w + acc1.w);
}

__global__ void __launch_bounds__(256) cpe_kernel(
    const void* __restrict__ xin, const float* __restrict__ wT,
    const float* __restrict__ bs, const int* __restrict__ flg, int afidx,
    float* __restrict__ out) {
  int idx = blockIdx.x * 256 + threadIdx.x;
  if (idx >= cBL * cC / 8) return;
  if (flg[afidx]) cpe_body<1>(xin, wT, bs, idx, out);
  else            cpe_body<0>(xin, wT, bs, idx, out);
}

// ---------- depthwise conv on DI + SiLU: bf16 in/out, 2 adjacent-w voxels/thread ----------
__global__ void __launch_bounds__(256) dwconv_silu_kernel(
    const unsigned short* __restrict__ xin, const float* __restrict__ wT,
    const float* __restrict__ bs, unsigned short* __restrict__ out) {
  int idx = blockIdx.x * 256 + threadIdx.x;
  if (idx >= cBL * cDI / 8) return;
  int d = (idx % (cDI / 4)) * 4; int pv = idx / (cDI / 4);
  int w0 = (pv & 15) << 1;
  int rest = pv >> 4;
  int h = rest & 31; int bt = rest >> 5; int t = bt & 7; int b = bt >> 3;
  float4 bias = *(const float4*)(bs + d);
  float4 acc0 = bias, acc1 = bias;
  const float4 zero = make_float4(0.f, 0.f, 0.f, 0.f);
#pragma unroll
  for (int dz = 0; dz < 3; ++dz) {
    int tt = t + dz - 1; if ((unsigned)tt >= (unsigned)cT) continue;
#pragma unroll
    for (int dy = 0; dy < 3; ++dy) {
      int hh = h + dy - 1; if ((unsigned)hh >= (unsigned)cH) continue;
      int base = (tt << 10) + (hh << 5);
      const float* wr = wT + (dz * 9 + dy * 3) * cDI + d;
      float4 wv0 = *(const float4*)(wr);
      float4 wv1 = *(const float4*)(wr + cDI);
      float4 wv2 = *(const float4*)(wr + 2 * cDI);
      size_t rb = ((size_t)b * cL + base) * cDI + d;
      float4 xm1 = (w0 > 0)  ? ld4<0>(xin, rb + (size_t)(w0 - 1) * cDI) : zero;
      float4 x0v = ld4<0>(xin, rb + (size_t)w0 * cDI);
      float4 x1v = ld4<0>(xin, rb + (size_t)(w0 + 1) * cDI);
      float4 x2v = (w0 < 30) ? ld4<0>(xin, rb + (size_t)(w0 + 2) * cDI) : zero;
      acc0.x += wv0.x*xm1.x + wv1.x*x0v.x + wv2.x*x1v.x;
      acc0.y += wv0.y*xm1.y + wv1.y*x0v.y + wv2.y*x1v.y;
      acc0.z += wv0.z*xm1.z + wv1.z*x0v.z + wv2.z*x1v.z;
      acc0.w += wv0.w*xm1.w + wv1.w*x0v.w + wv2.w*x1v.w;
      acc1.x += wv0.x*x0v.x + wv1.x*x1v.x + wv2.x*x2v.x;
      acc1.y += wv0.y*x0v.y + wv1.y*x1v.y + wv2.y*x2v.y;
      acc1.z += wv0.z*x0v.z + wv1.z*x1v.z + wv2.z*x2v.z;
      acc1.w += wv0.w*x0v.w + wv1.w*x1v.w + wv2.w*x2v.w;
    }
  }
  size_t bv0 = (size_t)b * cL + (t << 10) + (h << 5) + w0;
  ushort4 o0, o1;
  o0.x = (unsigned short)f2bf(siluf(acc0.x));
  o0.y = (unsigned short)f2bf(siluf(acc0.y));
  o0.z = (unsigned short)f2bf(siluf(acc0.z));
  o0.w = (unsigned short)f2bf(siluf(acc0.w));
  o1.x = (unsigned short)f2bf(siluf(acc1.x));
  o1.y = (unsigned short)f2bf(siluf(acc1.y));
  o1.z = (unsigned short)f2bf(siluf(acc1.z));
  o1.w = (unsigned short)f2bf(siluf(acc1.w));
  *(ushort4*)(out + bv0 * cDI + d) = o0;
  *(ushort4*)(out + (bv0 + 1) * cDI + d) = o1;
}

// ---------- wave-per-row LayerNorm (C=192): no LDS, no barriers, bf16 out ----------
__global__ void __launch_bounds__(256) lnb_kernel(
    const float* __restrict__ in, const void* __restrict__ g,
    const void* __restrict__ bb, const int* __restrict__ flg,
    unsigned short* __restrict__ out) {
  int pf = flg[1];
  int row = blockIdx.x * 4 + (threadIdx.x >> 6);
  int lane = threadIdx.x & 63;
  const float* x = in + (size_t)row * cC;
  float v0 = x[lane], v1 = x[lane + 64], v2 = x[lane + 128];
  float s1 = v0 + v1 + v2;
  float s2 = v0 * v0 + v1 * v1 + v2 * v2;
#pragma unroll
  for (int off = 32; off > 0; off >>= 1) {
    s1 += __shfl_xor(s1, off);
    s2 += __shfl_xor(s2, off);
  }
  float mean = s1 * (1.f / cC);
  float var = s2 * (1.f / cC) - mean * mean;
  float rstd = rsqrtf(var + 1e-6f);
  unsigned short* o = out + (size_t)row * cC;
  o[lane]       = (unsigned short)f2bf((v0 - mean) * rstd * ldsel(g, lane, pf)       + ldsel(bb, lane, pf));
  o[lane + 64]  = (unsigned short)f2bf((v1 - mean) * rstd * ldsel(g, lane + 64, pf)  + ldsel(bb, lane + 64, pf));
  o[lane + 128] = (unsigned short)f2bf((v2 - mean) * rstd * ldsel(g, lane + 128, pf) + ldsel(bb, lane + 128, pf));
}

// ---------- text conditioning ----------
__global__ void __launch_bounds__(384) text_cond_kernel(
    const void* __restrict__ text, const void* __restrict__ tw,
    const void* __restrict__ tb, const int* __restrict__ flg,
    float* __restrict__ cond) {
  int af = flg[0], pf = flg[1];
  __shared__ float mean[cC];
  int b = blockIdx.x;
  for (int c = threadIdx.x; c < cC; c += 384) {
    float s = 0.f;
    for (int t = 0; t < cLT; ++t) s += ldsel(text, ((size_t)b * cLT + t) * cC + c, af);
    mean[c] = s * (1.f / cLT);
  }
  __syncthreads();
  int di = threadIdx.x;
  float a = ldsel(tb, di, pf);
  for (int c = 0; c < cC; ++c) a += mean[c] * ldsel(tw, di * cC + c, pf);
  cond[b * cDI + di] = siluf(a);
}

// ---------- MFMA GEMM: out = epilogue(A[M,K] @ W[N,K]^T), bf16 compute ----------
template <int MODE, int ABF>
__global__ void __launch_bounds__(256) gemm_mfma_kernel(
    const void* __restrict__ A, const void* __restrict__ W,
    int N, int K, const void* __restrict__ bias, const int* __restrict__ flg,
    const float* __restrict__ extra, float* __restrict__ out,
    unsigned short* __restrict__ out2) {
  constexpr int BM = 128, BN = 64, BK = 32, PK = 40;
  __shared__ short As[BM * PK];
  __shared__ short Bs[BN * PK];
  int pf = flg[1];
  int tid = threadIdx.x;
  int m0 = blockIdx.y * BM, n0 = blockIdx.x * BN;
  int lane = tid & 63, wv = tid >> 6;
  int wm = (wv >> 1) * 64, wn = (wv & 1) * 32;
  int lr = lane & 15, quad = lane >> 4;
  f32x4 acc[4][2];
#pragma unroll
  for (int mi = 0; mi < 4; ++mi)
#pragma unroll
    for (int ni = 0; ni < 2; ++ni) { acc[mi][ni][0]=0.f; acc[mi][ni][1]=0.f; acc[mi][ni][2]=0.f; acc[mi][ni][3]=0.f; }
  int ar = tid >> 1, aks = (tid & 1) * 16;
  int wr = tid >> 2, wks = (tid & 3) * 8;
  for (int k0 = 0; k0 < K; k0 += BK) {
    if (ABF) {
      const unsigned short* ap = (const unsigned short*)A + (size_t)(m0 + ar) * K + k0 + aks;
      short* da = &As[ar * PK + aks];
#pragma unroll
      for (int i = 0; i < 4; ++i)
        *(short4v*)(da + i * 4) = *(const short4v*)(ap + i * 4);
    } else {
      const float* ap = (const float*)A + (size_t)(m0 + ar) * K + k0 + aks;
      short* da = &As[ar * PK + aks];
#pragma unroll
      for (int i = 0; i < 4; ++i) {
        float4 v = ((const float4*)ap)[i];
        short4v h; h.x = f2bf(v.x); h.y = f2bf(v.y); h.z = f2bf(v.z); h.w = f2bf(v.w);
        *(short4v*)(da + i * 4) = h;
      }
    }
    {
      int nr = n0 + wr;
      short hb[8];
      if (nr < N) {
        size_t wi = (size_t)nr * K + k0 + wks;
        if (pf) {
#pragma unroll
          for (int i = 0; i < 8; ++i) hb[i] = f2bf(((const float*)W)[wi + i]);
        } else {
#pragma unroll
          for (int i = 0; i < 8; ++i) hb[i] = (short)((const unsigned short*)W)[wi + i];
        }
      } else {
#pragma unroll
        for (int i = 0; i < 8; ++i) hb[i] = 0;
      }
      short* db = &Bs[wr * PK + wks];
#pragma unroll
      for (int i = 0; i < 8; i += 4) {
        short4v h; h.x = hb[i]; h.y = hb[i+1]; h.z = hb[i+2]; h.w = hb[i+3];
        *(short4v*)(db + i) = h;
      }
    }
    __syncthreads();
    bf16x8 af[4], bfr[2];
#pragma unroll
    for (int mi = 0; mi < 4; ++mi)
      af[mi] = *(const bf16x8*)&As[(wm + mi * 16 + lr) * PK + quad * 8];
#pragma unroll
    for (int ni = 0; ni < 2; ++ni)
      bfr[ni] = *(const bf16x8*)&Bs[(wn + ni * 16 + lr) * PK + quad * 8];
#pragma unroll
    for (int mi = 0; mi < 4; ++mi)
#pragma unroll
      for (int ni = 0; ni < 2; ++ni)
        acc[mi][ni] = __builtin_amdgcn_mfma_f32_16x16x32_bf16(af[mi], bfr[ni], acc[mi][ni], 0, 0, 0);
    __syncthreads();
  }
#pragma unroll
  for (int mi = 0; mi < 4; ++mi) {
#pragma unroll
    for (int ni = 0; ni < 2; ++ni) {
#pragma unroll
      for (int r = 0; r < 4; ++r) {
        int m = m0 + wm + mi * 16 + quad * 4 + r;
        int n = n0 + wn + ni * 16 + lr;
        float v = acc[mi][ni][r];
        if (MODE == 0) {
          float bvv = ldsel(bias, n, pf);
          int b = m >> 13;
          if (n < cDI)
            ((unsigned short*)out)[(size_t)m * cDI + n] =
                (unsigned short)f2bf(v + bvv + extra[b * cDI + n]);
          else
            out2[(size_t)m * cDI + (n - cDI)] = (unsigned short)f2bf(v + bvv);
        } else if (MODE == 1) {
          if (n < cK * XROW) {
            int k = n / XROW, c = n - k * XROW;
            int b = m >> 13, vv = m & (cL - 1);
            int t = vv >> 10, q = vv & 1023, h = q >> 5, w = q & 31;
            int l1 = (t << 10) + (w << 5) + h;
            int lk = (k == 0) ? vv : (k == 1) ? l1 : (k == 2) ? (cL - 1 - vv) : (cL - 1 - l1);
            out[((size_t)(b * cK + k) * cL + lk) * XSTR + c] = v;
          }
        } else if (MODE == 2) {
          out[(size_t)m * cC + n] = v + extra[(size_t)m * cC + n];
        } else if (MODE == 3) {
          ((unsigned short*)out)[(size_t)m * cHID + n] =
              (unsigned short)f2bf(gelut(v + ldsel(bias, n, pf)));
        } else {
          out[(size_t)m * cC + n] = v + ldsel(bias, n, pf) + extra[(size_t)m * cC + n];
        }
      }
    }
  }
}

// voxel index for scan position l in direction k
DEV int scan_voxel(int k, int l) {
  if (k == 0) return l;
  if (k == 2) return cL - 1 - l;
  int ll = (k == 1) ? l : (cL - 1 - l);
  int t = ll >> 10, q = ll & 1023, w = q >> 5, h = q & 31;
  return (t << 10) + (h << 5) + w;
}

// ---------- register row structs (constant-indexed, SROA-friendly) ----------
struct Row11 { float4 r0, r1, r2, r3, r4, r5, r6, r7, r8, r9, r10; };
struct Row7  { float4 r0, r1, r2, r7, r8, r9, r10; };

DEV Row11 ldrow11(const float* __restrict__ rows, int st) {
  const float4* rp = (const float4*)(rows + st * XSTR);
  Row11 q;
  q.r0 = rp[0]; q.r1 = rp[1]; q.r2 = rp[2]; q.r3 = rp[3]; q.r4 = rp[4];
  q.r5 = rp[5]; q.r6 = rp[6]; q.r7 = rp[7]; q.r8 = rp[8]; q.r9 = rp[9];
  q.r10 = rp[10];
  return q;
}
DEV Row7 ldrow7(const float* __restrict__ rows, int st) {
  const float4* rp = (const float4*)(rows + st * XSTR);
  Row7 q;
  q.r0 = rp[0]; q.r1 = rp[1]; q.r2 = rp[2];
  q.r7 = rp[7]; q.r8 = rp[8]; q.r9 = rp[9]; q.r10 = rp[10];
  return q;
}

// one fast-path scan1 step, packed fp32 (f32x2 state -> v_pk_fma_f32):
// per pair {h=h*pw+dtu*B; y+=h*C} is 3 packed ops replacing 6 scalar.
DEV float s1step(const Row11& q, float u,
                 const float (&wdt)[cDTR], float dtb, float ac0, float Dsd,
                 f32x2 (&h)[8], float& P1) {
  float s0 = dtb + q.r0.x*wdt[0] + q.r0.z*wdt[2] + q.r1.x*wdt[4] + q.r1.z*wdt[6] + q.r2.x*wdt[8] + q.r2.z*wdt[10];
  float s1 = q.r0.y*wdt[1] + q.r0.w*wdt[3] + q.r1.y*wdt[5] + q.r1.w*wdt[7] + q.r2.y*wdt[9] + q.r2.w*wdt[11];
  float dt = softplusf(s0 + s1);
  float a1 = exp2f(dt * ac0);
  float a2 = a1*a1, a3 = a2*a1, a4 = a2*a2;
  float a5 = a4*a1, a6 = a4*a2, a7 = a4*a3, a8 = a4*a4;
  float a9 = a8*a1, a10 = a8*a2, a11 = a8*a3, a12 = a8*a4;
  float a13 = a8*a5, a14 = a8*a6, a15 = a8*a7, a16 = a8*a8;
  float dtu = dt * u;
  P1 *= a1;
  f32x2 dtu2 = mk2(dtu, dtu);
  f32x2 pw0 = mk2(a1,a2),  pw1 = mk2(a3,a4),  pw2 = mk2(a5,a6),  pw3 = mk2(a7,a8);
  f32x2 pw4 = mk2(a9,a10), pw5 = mk2(a11,a12), pw6 = mk2(a13,a14), pw7 = mk2(a15,a16);
  f32x2 B0 = mk2(q.r3.x,q.r3.y), B1 = mk2(q.r3.z,q.r3.w);
  f32x2 B2 = mk2(q.r4.x,q.r4.y), B3 = mk2(q.r4.z,q.r4.w);
  f32x2 B4 = mk2(q.r5.x,q.r5.y), B5 = mk2(q.r5.z,q.r5.w);
  f32x2 B6 = mk2(q.r6.x,q.r6.y), B7 = mk2(q.r6.z,q.r6.w);
  f32x2 C0 = mk2(q.r7.x,q.r7.y), C1 = mk2(q.r7.z,q.r7.w);
  f32x2 C2 = mk2(q.r8.x,q.r8.y), C3 = mk2(q.r8.z,q.r8.w);
  f32x2 C4 = mk2(q.r9.x,q.r9.y), C5 = mk2(q.r9.z,q.r9.w);
  f32x2 C6 = mk2(q.r10.x,q.r10.y), C7 = mk2(q.r10.z,q.r10.w);
  f32x2 y0 = mk2(Dsd * u, 0.f), y1 = mk2(0.f,0.f), y2 = mk2(0.f,0.f), y3 = mk2(0.f,0.f);
  h[0] = h[0]*pw0 + dtu2*B0; y0 += h[0]*C0;
  h[1] = h[1]*pw1 + dtu2*B1; y1 += h[1]*C1;
  h[2] = h[2]*pw2 + dtu2*B2; y2 += h[2]*C2;
  h[3] = h[3]*pw3 + dtu2*B3; y3 += h[3]*C3;
  h[4] = h[4]*pw4 + dtu2*B4; y0 += h[4]*C4;
  h[5] = h[5]*pw5 + dtu2*B5; y1 += h[5]*C5;
  h[6] = h[6]*pw6 + dtu2*B6; y2 += h[6]*C6;
  h[7] = h[7]*pw7 + dtu2*B7; y3 += h[7]*C7;
  f32x2 t = (y0 + y1) + (y2 + y3);
  return t[0] + t[1];
}

// one fast-path scan3 step, packed fp32
DEV float s3step(const Row7& q,
                 const float (&wdt)[cDTR], float dtb, float ac0,
                 f32x2 (&g)[8]) {
  float s0 = dtb + q.r0.x*wdt[0] + q.r0.z*wdt[2] + q.r1.x*wdt[4] + q.r1.z*wdt[6] + q.r2.x*wdt[8] + q.r2.z*wdt[10];
  float s1 = q.r0.y*wdt[1] + q.r0.w*wdt[3] + q.r1.y*wdt[5] + q.r1.w*wdt[7] + q.r2.y*wdt[9] + q.r2.w*wdt[11];
  float dt = softplusf(s0 + s1);
  float a1 = exp2f(dt * ac0);
  float a2 = a1*a1, a3 = a2*a1, a4 = a2*a2;
  float a5 = a4*a1, a6 = a4*a2, a7 = a4*a3, a8 = a4*a4;
  float a9 = a8*a1, a10 = a8*a2, a11 = a8*a3, a12 = a8*a4;
  float a13 = a8*a5, a14 = a8*a6, a15 = a8*a7, a16 = a8*a8;
  f32x2 pw0 = mk2(a1,a2),  pw1 = mk2(a3,a4),  pw2 = mk2(a5,a6),  pw3 = mk2(a7,a8);
  f32x2 pw4 = mk2(a9,a10), pw5 = mk2(a11,a12), pw6 = mk2(a13,a14), pw7 = mk2(a15,a16);
  f32x2 C0 = mk2(q.r7.x,q.r7.y), C1 = mk2(q.r7.z,q.r7.w);
  f32x2 C2 = mk2(q.r8.x,q.r8.y), C3 = mk2(q.r8.z,q.r8.w);
  f32x2 C4 = mk2(q.r9.x,q.r9.y), C5 = mk2(q.r9.z,q.r9.w);
  f32x2 C6 = mk2(q.r10.x,q.r10.y), C7 = mk2(q.r10.z,q.r10.w);
  f32x2 y0 = mk2(0.f,0.f), y1 = mk2(0.f,0.f), y2 = mk2(0.f,0.f), y3 = mk2(0.f,0.f);
  g[0] *= pw0; y0 += g[0]*C0;
  g[1] *= pw1; y1 += g[1]*C1;
  g[2] *= pw2; y2 += g[2]*C2;
  g[3] *= pw3; y3 += g[3]*C3;
  g[4] *= pw4; y0 += g[4]*C4;
  g[5] *= pw5; y1 += g[5]*C5;
  g[6] *= pw6; y2 += g[6]*C6;
  g[7] *= pw7; y3 += g[7]*C7;
  f32x2 t = (y0 + y1) + (y2 + y3);
  return t[0] + t[1];
}

// ---------- scan pass 1 (128 thr, 1 ch/thread, bf16 streams, packed fp32) ----------
__global__ void __launch_bounds__(128, 3) scan1_kernel(
    const unsigned short* __restrict__ xch, const float* __restrict__ xdbl,
    const void* __restrict__ dtw, const void* __restrict__ dtbv,
    const void* __restrict__ alog, const void* __restrict__ dsv,
    const int* __restrict__ flg,
    unsigned short* __restrict__ ys0, unsigned short* __restrict__ ys1,
    unsigned short* __restrict__ ys2, unsigned short* __restrict__ ys3,
    unsigned short* __restrict__ hend, unsigned short* __restrict__ pend) {
  __shared__ float rows[SEGLEN * XSTR];   // 64 x 48 floats = 12 KB
  int pf = flg[1];
  int tid = threadIdx.x;
  int d = blockIdx.x * 128 + tid;
  int bks = blockIdx.y;
  int s = bks & (SEG - 1); int bk = bks / SEG; int k = bk & 3; int b = bk >> 2;
  int l0 = s * SEGLEN;
  {
    const float4* src = (const float4*)(xdbl + ((size_t)bk * cL + l0) * XSTR);
    float4* dst = (float4*)rows;
#pragma unroll
    for (int i = 0; i < (SEGLEN * XSTR / 4) / 128; ++i)   // 6 iters
      dst[tid + i * 128] = src[tid + i * 128];
  }
  float wdt[cDTR];
#pragma unroll
  for (int r = 0; r < cDTR; ++r) wdt[r] = ldsel(dtw, (size_t)(k * cDI + d) * cDTR + r, pf);
  float dtb = ldsel(dtbv, k * cDI + d, pf);
  float ac[cN];
#pragma unroll
  for (int n = 0; n < cN; ++n)
    ac[n] = -__expf(ldsel(alog, (size_t)(k * cDI + d) * cN + n, pf)) * 1.4426950408889634f;
  bool fast = true;
#pragma unroll
  for (int n = 1; n < cN; ++n)
    fast = fast && (fabsf(ac[n] - (float)(n + 1) * ac[0]) <= 1e-3f * fabsf(ac[n]));
  float Dsd = ldsel(dsv, k * cDI + d, pf);
  size_t so = ((size_t)bks * cDI + d) * cN;
  const unsigned short* xcb = xch + (size_t)b * cL * cDI + d;
  unsigned short* ysk = (k == 0) ? ys0 : (k == 1) ? ys1 : (k == 2) ? ys2 : ys3;
  unsigned short* ysrow = ysk + ((size_t)b * cL + l0) * cDI + d;
  __syncthreads();
  if (fast) {
    float ac0 = ac[0];
    float P1 = 1.f;
    f32x2 h2[8];
#pragma unroll
    for (int i = 0; i < 8; ++i) h2[i] = mk2(0.f, 0.f);
    Row11 qa = ldrow11(rows, 0);
    float u0 = bfu2f(xcb[(size_t)scan_voxel(k, l0) * cDI]);
    float u1 = bfu2f(xcb[(size_t)scan_voxel(k, l0 + 1) * cDI]);
    for (int st = 0; st < SEGLEN; st += 2) {
      Row11 qb = ldrow11(rows, st + 1);
      int p2 = (st + 2 < SEGLEN) ? st + 2 : SEGLEN - 1;
      int p3 = (st + 3 < SEGLEN) ? st + 3 : SEGLEN - 1;
      float nu0 = bfu2f(xcb[(size_t)scan_voxel(k, l0 + p2) * cDI]);
      float nu1 = bfu2f(xcb[(size_t)scan_voxel(k, l0 + p3) * cDI]);
      float ya = s1step(qa, u0, wdt, dtb, ac0, Dsd, h2, P1);
      ysrow[(size_t)st * cDI] = (unsigned short)f2bf(ya);
      qa = ldrow11(rows, p2);
      float yb = s1step(qb, u1, wdt, dtb, ac0, Dsd, h2, P1);
      ysrow[(size_t)(st + 1) * cDI] = (unsigned short)f2bf(yb);
      u0 = nu0; u1 = nu1;
    }
    float pp = P1;
#pragma unroll
    for (int i = 0; i < 8; ++i) {
      hend[so + 2*i]     = (unsigned short)f2bf(h2[i][0]);
      hend[so + 2*i + 1] = (unsigned short)f2bf(h2[i][1]);
    }
#pragma unroll
    for (int n = 0; n < cN; ++n) {
      pend[so + n] = (unsigned short)f2bf(pp);
      pp *= P1;
    }
  } else {
    float h[cN], P[cN];
#pragma unroll
    for (int n = 0; n < cN; ++n) { h[n] = 0.f; P[n] = 1.f; }
    for (int st = 0; st < SEGLEN; ++st) {
      int l = l0 + st;
      const float4* rp = (const float4*)(rows + st * XSTR);
      float4 q0 = rp[0], q1 = rp[1], q2 = rp[2];
      float s0 = dtb + q0.x*wdt[0] + q0.z*wdt[2] + q1.x*wdt[4] + q1.z*wdt[6] + q2.x*wdt[8] + q2.z*wdt[10];
      float s1 = q0.y*wdt[1] + q0.w*wdt[3] + q1.y*wdt[5] + q1.w*wdt[7] + q2.y*wdt[9] + q2.w*wdt[11];
      float dt = softplusf(s0 + s1);
      float Bv[cN], Cv[cN];
      float4 qb0 = rp[3], qb1 = rp[4], qb2 = rp[5], qb3 = rp[6];
      float4 qc0 = rp[7], qc1 = rp[8], qc2 = rp[9], qc3 = rp[10];
      Bv[0]=qb0.x; Bv[1]=qb0.y; Bv[2]=qb0.z; Bv[3]=qb0.w;
      Bv[4]=qb1.x; Bv[5]=qb1.y; Bv[6]=qb1.z; Bv[7]=qb1.w;
      Bv[8]=qb2.x; Bv[9]=qb2.y; Bv[10]=qb2.z; Bv[11]=qb2.w;
      Bv[12]=qb3.x; Bv[13]=qb3.y; Bv[14]=qb3.z; Bv[15]=qb3.w;
      Cv[0]=qc0.x; Cv[1]=qc0.y; Cv[2]=qc0.z; Cv[3]=qc0.w;
      Cv[4]=qc1.x; Cv[5]=qc1.y; Cv[6]=qc1.z; Cv[7]=qc1.w;
      Cv[8]=qc2.x; Cv[9]=qc2.y; Cv[10]=qc2.z; Cv[11]=qc2.w;
      Cv[12]=qc3.x; Cv[13]=qc3.y; Cv[14]=qc3.z; Cv[15]=qc3.w;
      int v = scan_voxel(k, l);
      float u = bfu2f(xcb[(size_t)v * cDI]);
      float dtu = dt * u;
      float y = Dsd * u;
#pragma unroll
      for (int n = 0; n < cN; ++n) {
        float a = exp2f(dt * ac[n]);
        h[n] = h[n] * a + dtu * Bv[n];
        P[n] *= a;
        y += h[n] * Cv[n];
      }
      ysrow[(size_t)st * cDI] = (unsigned short)f2bf(y);
    }
#pragma unroll
    for (int n = 0; n < cN; ++n) {
      hend[so + n] = (unsigned short)f2bf(h[n]);
      pend[so + n] = (unsigned short)f2bf(P[n]);
    }
  }
}

// ---------- scan pass 2 (serial prefix over segments; fp32 recurrence, bf16 storage) ----------
__global__ void __launch_bounds__(256) scan2_kernel(
    unsigned short* __restrict__ hend, const unsigned short* __restrict__ pend) {
  int tid = blockIdx.x * 256 + threadIdx.x;
  int bk = tid / (cDI * cN); int r = tid - bk * (cDI * cN);
  float g = 0.f;
  for (int s = 0; s < SEG; ++s) {
    size_t o = ((size_t)(bk * SEG + s) * cDI * cN) + r;
    float he = bfu2f(hend[o]), pe = bfu2f(pend[o]);
    hend[o] = (unsigned short)f2bf(g);
    g = pe * g + he;
  }
}

// ---------- scan pass 3 (owned read-add-store; packed fp32) ----------
__global__ void __launch_bounds__(128, 3) scan3_kernel(
    const float* __restrict__ xdbl,
    const void* __restrict__ dtw, const void* __restrict__ dtbv,
    const void* __restrict__ alog, const int* __restrict__ flg,
    const unsigned short* __restrict__ hin,
    unsigned short* __restrict__ ys0, unsigned short* __restrict__ ys1,
    unsigned short* __restrict__ ys2, unsigned short* __restrict__ ys3) {
  int bks = blockIdx.y;
  int s = bks & (SEG - 1);
  if (s == 0) return;
  __shared__ float rows[SEGLEN * XSTR];
  int pf = flg[1];
  int tid = threadIdx.x;
  int d = blockIdx.x * 128 + tid;
  int bk = bks / SEG; int k = bk & 3; int b = bk >> 2;
  int l0 = s * SEGLEN;
  {
    const float4* src = (const float4*)(xdbl + ((size_t)bk * cL + l0) * XSTR);
    float4* dst = (float4*)rows;
#pragma unroll
    for (int i = 0; i < (SEGLEN * XSTR / 4) / 128; ++i)
      dst[tid + i * 128] = src[tid + i * 128];
  }
  float wdt[cDTR];
#pragma unroll
  for (int r = 0; r < cDTR; ++r) wdt[r] = ldsel(dtw, (size_t)(k * cDI + d) * cDTR + r, pf);
  float dtb = ldsel(dtbv, k * cDI + d, pf);
  float ac[cN];
#pragma unroll
  for (int n = 0; n < cN; ++n)
    ac[n] = -__expf(ldsel(alog, (size_t)(k * cDI + d) * cN + n, pf)) * 1.4426950408889634f;
  bool fast = true;
#pragma unroll
  for (int n = 1; n < cN; ++n)
    fast = fast && (fabsf(ac[n] - (float)(n + 1) * ac[0]) <= 1e-3f * fabsf(ac[n]));
  size_t so = ((size_t)bks * cDI + d) * cN;
  unsigned short* ysk = (k == 0) ? ys0 : (k == 1) ? ys1 : (k == 2) ? ys2 : ys3;
  unsigned short* ysrow = ysk + ((size_t)b * cL + l0) * cDI + d;
  __syncthreads();
  if (fast) {
    float ac0 = ac[0];
    f32x2 g2[8];
#pragma unroll
    for (int i = 0; i < 8; ++i)
      g2[i] = mk2(bfu2f(hin[so + 2*i]), bfu2f(hin[so + 2*i + 1]));
    Row7 qa = ldrow7(rows, 0);
    for (int st = 0; st < SEGLEN; st += 2) {
      Row7 qb = ldrow7(rows, st + 1);
      int p2 = (st + 2 < SEGLEN) ? st + 2 : SEGLEN - 1;
      float ya = s3step(qa, wdt, dtb, ac0, g2);
      size_t ia = (size_t)st * cDI;
      ysrow[ia] = (unsigned short)f2bf(bfu2f(ysrow[ia]) + ya);
      qa = ldrow7(rows, p2);
      float yb = s3step(qb, wdt, dtb, ac0, g2);
      size_t ib = (size_t)(st + 1) * cDI;
      ysrow[ib] = (unsigned short)f2bf(bfu2f(ysrow[ib]) + yb);
    }
  } else {
    float g[cN];
#pragma unroll
    for (int n = 0; n < cN; ++n) g[n] = bfu2f(hin[so + n]);
    for (int st = 0; st < SEGLEN; ++st) {
      const float4* rp = (const float4*)(rows + st * XSTR);
      float4 q0 = rp[0], q1 = rp[1], q2 = rp[2];
      float s0 = dtb + q0.x*wdt[0] + q0.z*wdt[2] + q1.x*wdt[4] + q1.z*wdt[6] + q2.x*wdt[8] + q2.z*wdt[10];
      float s1 = q0.y*wdt[1] + q0.w*wdt[3] + q1.y*wdt[5] + q1.w*wdt[7] + q2.y*wdt[9] + q2.w*wdt[11];
      float dt = softplusf(s0 + s1);
      float Cv[cN];
      float4 qc0 = rp[7], qc1 = rp[8], qc2 = rp[9], qc3 = rp[10];
      Cv[0]=qc0.x; Cv[1]=qc0.y; Cv[2]=qc0.z; Cv[3]=qc0.w;
      Cv[4]=qc1.x; Cv[5]=qc1.y; Cv[6]=qc1.z; Cv[7]=qc1.w;
      Cv[8]=qc2.x; Cv[9]=qc2.y; Cv[10]=qc2.z; Cv[11]=qc2.w;
      Cv[12]=qc3.x; Cv[13]=qc3.y; Cv[14]=qc3.z; Cv[15]=qc3.w;
      float y = 0.f;
#pragma unroll
      for (int n = 0; n < cN; ++n) {
        float a = exp2f(dt * ac[n]);
        g[n] *= a;
        y += g[n] * Cv[n];
      }
      size_t ii = (size_t)st * cDI;
      ysrow[ii] = (unsigned short)f2bf(bfu2f(ysrow[ii]) + y);
    }
  }
}

// ---------- merge: wave-per-row gather of 4 dirs + out_norm LN + silu(z) gate ----------
__global__ void __launch_bounds__(256) merge_kernel(
    const unsigned short* __restrict__ ys0, const unsigned short* __restrict__ ys1,
    const unsigned short* __restrict__ ys2, const unsigned short* __restrict__ ys3,
    const unsigned short* __restrict__ zh,
    const void* __restrict__ ong, const void* __restrict__ onb,
    const int* __restrict__ flg, unsigned short* __restrict__ yg) {
  int pf = flg[1];
  int bv = blockIdx.x * 4 + (threadIdx.x >> 6);
  int lane = threadIdx.x & 63;
  int v = bv & (cL - 1); int b = bv >> 13;
  int t = v >> 10, q = v & 1023, hh = q >> 5, ww = q & 31;
  int l1 = (t << 10) + (ww << 5) + hh;
  size_t r0 = ((size_t)b * cL + v) * cDI;
  size_t r1 = ((size_t)b * cL + l1) * cDI;
  size_t r2 = ((size_t)b * cL + (cL - 1 - v)) * cDI;
  size_t r3 = ((size_t)b * cL + (cL - 1 - l1)) * cDI;
  float vals[6]; float s1 = 0.f, s2 = 0.f;
#pragma unroll
  for (int i = 0; i < 6; ++i) {
    int d = lane + i * 64;
    float x = bfu2f(ys0[r0 + d]) + bfu2f(ys1[r1 + d]) +
              bfu2f(ys2[r2 + d]) + bfu2f(ys3[r3 + d]);
    vals[i] = x; s1 += x; s2 += x * x;
  }
#pragma unroll
  for (int off = 32; off > 0; off >>= 1) {
    s1 += __shfl_xor(s1, off);
    s2 += __shfl_xor(s2, off);
  }
  float mean = s1 * (1.f / cDI);
  float var = s2 * (1.f / cDI) - mean * mean;
  float rstd = rsqrtf(var + 1e-6f);
  const unsigned short* zr = zh + (size_t)bv * cDI;
  unsigned short* og = yg + (size_t)bv * cDI;
#pragma unroll
  for (int i = 0; i < 6; ++i) {
    int d = lane + i * 64;
    float xn = (vals[i] - mean) * rstd * ldsel(ong, d, pf) + ldsel(onb, d, pf);
    og[d] = (unsigned short)f2bf(xn * siluf(bfu2f(zr[d])));
  }
}

}  // namespace

extern "C" void kernel_launch(void* const* d_in, const int* in_sizes, int n_in,
                              void* d_out, int out_size, void* d_ws, size_t ws_size,
                              hipStream_t stream) {
  (void)in_sizes; (void)n_in; (void)out_size; (void)ws_size;
  const void* x    = d_in[0];
  const void* text = d_in[1];
  const void* c1w  = d_in[2];
  const void* c1b  = d_in[3];
  const void* c2w  = d_in[4];
  const void* c2b  = d_in[5];
  const void* n1g  = d_in[6];
  const void* n1b  = d_in[7];
  const void* n2g  = d_in[8];
  const void* n2b  = d_in[9];
  const void* ipw  = d_in[10];
  const void* ipb  = d_in[11];
  const void* tpw  = d_in[12];
  const void* tpb  = d_in[13];
  const void* cvw  = d_in[14];
  const void* cvb  = d_in[15];
  const void* xpw  = d_in[16];
  const void* dtw  = d_in[17];
  const void* dtb  = d_in[18];
  const void* alog = d_in[19];
  const void* dsv  = d_in[20];
  const void* ong  = d_in[21];
  const void* onb  = d_in[22];
  const void* opw  = d_in[23];
  const void* f1w  = d_in[24];
  const void* f1b  = d_in[25];
  const void* f2w  = d_in[26];
  const void* f2b  = d_in[27];

  float* Wf = (float*)d_ws;

  // ---- slot arena (~125.9 MB), atomic-free scan + bf16 activations ----
  constexpr size_t oC  = 0;                              // 6,291,456
  constexpr size_t oD  = 6291456;                        // 3,145,728
  constexpr size_t oG  = 9437184;                        // 3,145,728
  constexpr size_t oA  = 12582912;                       // 6,291,456
  constexpr size_t oB  = 18874368;                       // 6,291,456
  constexpr size_t oE  = 25165824;                       // 3,145,728
  constexpr size_t oF  = 28311552;                       // 3,145,728
  constexpr size_t oCO = 31457280;                       // 768 (cond)
  constexpr size_t oFL = 31458048;                       // 4 ints (flags)
  constexpr size_t oWCV = 31458052;                      // 27*384
  constexpr size_t oBCV = 31468420;                      // 384
  constexpr size_t oW1  = 31468804;                      // 27*192
  constexpr size_t oB1  = 31473988;                      // 192
  constexpr size_t oW2  = 31474180;                      // 5184
  constexpr size_t oB2  = 31479364;                      // 192 -> end 31479556
  unsigned short* xch = (unsigned short*)(Wf + oC);            // bf16 silu(dwconv)
  unsigned short* ysd2 = (unsigned short*)(Wf + oC + 3145728); // ystream dir 2
  unsigned short* hbufh = (unsigned short*)(Wf + oC);          // fc1 out bf16
  float* xdbl = Wf + oD;
  unsigned short* ygh  = (unsigned short*)(Wf + oD);           // yg bf16 (after xdbl dead)
  unsigned short* xnh  = (unsigned short*)(Wf + oG);           // LN1 out bf16
  unsigned short* pendp = (unsigned short*)(Wf + oG);          // bf16, after xnh dead
  unsigned short* xib  = (unsigned short*)(Wf + oA);           // in_proj x-half bf16
  unsigned short* ysd0 = (unsigned short*)(Wf + oA);           // ystream dir 0 (xib dead)
  unsigned short* ysd1 = (unsigned short*)(Wf + oA + 3145728); // ystream dir 1
  float* x2   = Wf + oA;   // out_proj output (after ystream dead)
  unsigned short* zh   = (unsigned short*)(Wf + oB);           // z bf16
  unsigned short* ysd3 = (unsigned short*)(Wf + oB + 3145728); // ystream dir 3
  float* x3   = Wf + oB;
  float* x1   = Wf + oE;
  unsigned short* hendp = (unsigned short*)(Wf + oF);          // bf16
  unsigned short* xn2h = (unsigned short*)(Wf + oF);           // LN2 out bf16 (hend dead)
  float* cond = Wf + oCO;
  int*   flg  = (int*)(Wf + oFL);
  float* wcv = Wf + oWCV; float* bcv = Wf + oBCV;
  float* w1t = Wf + oW1;  float* b1t = Wf + oB1;
  float* w2t = Wf + oW2;  float* b2t = Wf + oB2;

  const int cpeBlocks = (cBL * cC / 8) / 256;     // 1536 (2 voxels/thread)
  const int dwBlocks  = (cBL * cDI / 8) / 256;    // 3072 (2 voxels/thread)

  // 0. dtype detection + conv weight prep
  hipLaunchKernelGGL(detect_kernel, dim3(1), dim3(256), 0, stream,
                     (const unsigned short*)x, (const unsigned short*)ipw, flg);
  hipLaunchKernelGGL(prep_kernel, dim3(85), dim3(256), 0, stream,
                     cvw, cvb, c1w, c1b, c2w, c2b, flg, wcv, bcv, w1t, b1t, w2t, b2t);
  // 1. x1 = x + cpe1(x)
  hipLaunchKernelGGL(cpe_kernel, dim3(cpeBlocks), dim3(256), 0, stream,
                     x, w1t, b1t, flg, 0, x1);
  // 2. xnh = bf16(LN1(x1))  (wave-per-row, no barriers)
  hipLaunchKernelGGL(lnb_kernel, dim3(cBL / 4), dim3(256), 0, stream, x1, n1g, n1b, flg, xnh);
  // 3. cond
  hipLaunchKernelGGL(text_cond_kernel, dim3(cB), dim3(384), 0, stream, text, tpw, tpb, flg, cond);
  // 4. in_proj (MFMA, bf16 A): xnh -> xib bf16 (+cond), zh bf16
  hipLaunchKernelGGL((gemm_mfma_kernel<0, 1>), dim3(2 * cDI / 64, cBL / 128), dim3(256), 0, stream,
                     xnh, ipw, 2 * cDI, cC, ipb, flg, cond, (float*)xib, zh);
  // 5. xch = bf16(silu(dwconv(xib)))
  hipLaunchKernelGGL(dwconv_silu_kernel, dim3(dwBlocks), dim3(256), 0, stream,
                     xib, wcv, bcv, xch);
  // 6. x_proj (MFMA, bf16 A, scatter to padded scan rows)
  hipLaunchKernelGGL((gemm_mfma_kernel<1, 1>), dim3((cK * XROW + 63) / 64, cBL / 128), dim3(256), 0, stream,
                     xch, xpw, cK * XROW, cDI, (const void*)nullptr, flg,
                     (const float*)nullptr, xdbl, (unsigned short*)nullptr);
  // 7-9. chunked selective scan (packed fp32 inner loops)
  hipLaunchKernelGGL(scan1_kernel, dim3(cDI / 128, cB * cK * SEG), dim3(128), 0, stream,
                     xch, xdbl, dtw, dtb, alog, dsv, flg,
                     ysd0, ysd1, ysd2, ysd3, hendp, pendp);
  hipLaunchKernelGGL(scan2_kernel, dim3(cB * cK * cDI * cN / 256), dim3(256), 0, stream,
                     hendp, pendp);
  hipLaunchKernelGGL(scan3_kernel, dim3(cDI / 128, cB * cK * SEG), dim3(128), 0, stream,
                     xdbl, dtw, dtb, alog, flg, hendp, ysd0, ysd1, ysd2, ysd3);
  // 10. merge: wave-per-row gather + out_norm + gate -> yg bf16
  hipLaunchKernelGGL(merge_kernel, dim3(cBL / 4), dim3(256), 0, stream,
                     ysd0, ysd1, ysd2, ysd3, zh, ong, onb, flg, ygh);
  // 11. out_proj (bf16 A) + residual(x1) -> x2 fp32
  hipLaunchKernelGGL((gemm_mfma_kernel<2, 1>), dim3(cC / 64, cBL / 128), dim3(256), 0, stream,
                     ygh, opw, cC, cDI, (const void*)nullptr, flg, x1, x2,
                     (unsigned short*)nullptr);
  // 12. x3 = x2 + cpe2(x2)  (flg[2]=1 -> fp32 input path)
  hipLaunchKernelGGL(cpe_kernel, dim3(cpeBlocks), dim3(256), 0, stream,
                     x2, w2t, b2t, flg, 2, x3);
  // 13. xn2h = bf16(LN2(x3))
  hipLaunchKernelGGL(lnb_kernel, dim3(cBL / 4), dim3(256), 0, stream, x3, n2g, n2b, flg, xn2h);
  // 14. fc1 + gelu -> hbufh bf16 (MFMA, bf16 A)
  hipLaunchKernelGGL((gemm_mfma_kernel<3, 1>), dim3(cHID / 64, cBL / 128), dim3(256), 0, stream,
                     xn2h, f1w, cHID, cC, f1b, flg, (const float*)nullptr, (float*)hbufh,
                     (unsigned short*)nullptr);
  // 15. fc2 (bf16 A) + bias + residual(x3) -> d_out fp32 (MFMA)
  hipLaunchKernelGGL((gemm_mfma_kernel<4, 1>), dim3(cC / 64, cBL / 128), dim3(256), 0, stream,
                     hbufh, f2w, cC, cHID, f2b, flg, x3, (float*)d_out,
                     (unsigned short*)nullptr);
}

// Round 13
// 549.962 us; speedup vs baseline: 1.1664x; 1.0040x over previous
//
#include <hip/hip_runtime.h>
#include <hip/hip_bf16.h>

#define DEV __device__ __forceinline__

namespace {

constexpr int cB = 2, cT = 8, cH = 32, cW = 32, cC = 192;
constexpr int cDI = 384, cN = 16, cK = 4, cDTR = 12, cLT = 77, cHID = 768;
constexpr int cL  = cT * cH * cW;      // 8192
constexpr int cBL = cB * cL;           // 16384
constexpr int SEG = 128, SEGLEN = cL / SEG;   // 128 segments x 64 steps
constexpr int XROW = cDTR + 2 * cN;    // 44 live cols
constexpr int XSTR = 48;               // padded row stride (float4-aligned)

typedef __attribute__((ext_vector_type(8))) short bf16x8;
typedef __attribute__((ext_vector_type(4))) float f32x4;
typedef __attribute__((ext_vector_type(2))) float f32x2;
typedef __attribute__((ext_vector_type(4))) short short4v;

// ---------- scalar helpers ----------
DEV float bfu2f(unsigned short u) { return __uint_as_float(((unsigned)u) << 16); }
DEV float ldsel(const void* p, size_t i, int f32) {
  return f32 ? ((const float*)p)[i] : bfu2f(((const unsigned short*)p)[i]);
}
template <int F32>
DEV float4 ld4(const void* p, size_t e) {   // e: element index, multiple of 4
  if (F32) return *(const float4*)((const float*)p + e);
  ushort4 u = *(const ushort4*)((const unsigned short*)p + e);
  return make_float4(bfu2f(u.x), bfu2f(u.y), bfu2f(u.z), bfu2f(u.w));
}
DEV short f2bf(float f) {   // RNE float->bf16 bits
  unsigned u = __float_as_uint(f);
  u += 0x7fffu + ((u >> 16) & 1u);
  return (short)(u >> 16);
}
DEV float siluf(float x) { return x / (1.f + __expf(-x)); }
DEV float softplusf(float x) { return (x > 20.f) ? x : __logf(1.f + __expf(x)); }
DEV float gelut(float x) {            // tanh-approx gelu (JAX default)
  float u = 0.7978845608028654f * (x + 0.044715f * x * x * x);
  float e = __expf(2.f * u);
  float th = 1.f - 2.f / (e + 1.f);
  return 0.5f * x * (1.f + th);
}
DEV f32x2 mk2(float a, float b) { f32x2 v; v[0] = a; v[1] = b; return v; }

// ---------- dtype detector (validated: inputs are fp32) ----------
__global__ void __launch_bounds__(256) detect_kernel(
    const unsigned short* __restrict__ xa, const unsigned short* __restrict__ wp,
    int* __restrict__ flg) {
  __shared__ int cnt[2];
  if (threadIdx.x < 2) cnt[threadIdx.x] = 0;
  __syncthreads();
  int l0 = 0, l1 = 0;
  for (int i = threadIdx.x; i < 1024; i += 256) {
    float v = bfu2f(xa[2 * i]); float a = fabsf(v);
    if (v == 0.f || (a > 1e-8f && a < 1e4f)) l0++;
    float u = bfu2f(wp[2 * i]); float bq = fabsf(u);
    if (u == 0.f || (bq > 1e-8f && bq < 1e4f)) l1++;
  }
  atomicAdd(&cnt[0], l0); atomicAdd(&cnt[1], l1);
  __syncthreads();
  if (threadIdx.x == 0) {
    flg[0] = (cnt[0] < 614) ? 1 : 0;
    flg[1] = (cnt[1] < 614) ? 1 : 0;
    flg[2] = 1;
  }
}

// ---------- conv weight prep: transpose [Ch][27] -> [27][Ch] fp32, decode biases ----------
__global__ void __launch_bounds__(256) prep_kernel(
    const void* __restrict__ cvw, const void* __restrict__ cvb,
    const void* __restrict__ c1w, const void* __restrict__ c1b,
    const void* __restrict__ c2w, const void* __restrict__ c2b,
    const int* __restrict__ flg,
    float* __restrict__ wcv, float* __restrict__ bcv,
    float* __restrict__ w1, float* __restrict__ b1,
    float* __restrict__ w2, float* __restrict__ b2) {
  int pf = flg[1];
  int i = blockIdx.x * 256 + threadIdx.x;
  int r = i;
  if (r < 27 * cDI) { int j = r / cDI, d = r % cDI; wcv[r] = ldsel(cvw, (size_t)d * 27 + j, pf); return; }
  r -= 27 * cDI;
  if (r < cDI) { bcv[r] = ldsel(cvb, r, pf); return; }
  r -= cDI;
  if (r < 27 * cC) { int j = r / cC, c = r % cC; w1[r] = ldsel(c1w, (size_t)c * 27 + j, pf); return; }
  r -= 27 * cC;
  if (r < cC) { b1[r] = ldsel(c1b, r, pf); return; }
  r -= cC;
  if (r < 27 * cC) { int j = r / cC, c = r % cC; w2[r] = ldsel(c2w, (size_t)c * 27 + j, pf); return; }
  r -= 27 * cC;
  if (r < cC) { b2[r] = ldsel(c2b, r, pf); return; }
}

// ---------- CPE (depthwise 3x3x3 + residual), 2 adjacent-w voxels/thread ----------
template <int F32>
DEV void cpe_body(const void* __restrict__ xin, const float* __restrict__ wT,
                  const float* __restrict__ bs, int idx, float* __restrict__ out) {
  int c = (idx % (cC / 4)) * 4; int pv = idx / (cC / 4);   // pv in [0, cBL/2)
  int w0 = (pv & 15) << 1;
  int rest = pv >> 4;
  int h = rest & 31; int bt = rest >> 5; int t = bt & 7; int b = bt >> 3;
  float4 bias = *(const float4*)(bs + c);
  float4 acc0 = bias, acc1 = bias;
  const float4 zero = make_float4(0.f, 0.f, 0.f, 0.f);
#pragma unroll
  for (int dz = 0; dz < 3; ++dz) {
    int tt = t + dz - 1; if ((unsigned)tt >= (unsigned)cT) continue;
#pragma unroll
    for (int dy = 0; dy < 3; ++dy) {
      int hh = h + dy - 1; if ((unsigned)hh >= (unsigned)cH) continue;
      int base = (tt << 10) + (hh << 5);
      const float* wr = wT + (dz * 9 + dy * 3) * cC + c;
      float4 wv0 = *(const float4*)(wr);
      float4 wv1 = *(const float4*)(wr + cC);
      float4 wv2 = *(const float4*)(wr + 2 * cC);
      size_t rb = ((size_t)b * cL + base) * cC + c;
      float4 xm1 = (w0 > 0)  ? ld4<F32>(xin, rb + (size_t)(w0 - 1) * cC) : zero;
      float4 x0v = ld4<F32>(xin, rb + (size_t)w0 * cC);
      float4 x1v = ld4<F32>(xin, rb + (size_t)(w0 + 1) * cC);
      float4 x2v = (w0 < 30) ? ld4<F32>(xin, rb + (size_t)(w0 + 2) * cC) : zero;
      acc0.x += wv0.x*xm1.x + wv1.x*x0v.x + wv2.x*x1v.x;
      acc0.y += wv0.y*xm1.y + wv1.y*x0v.y + wv2.y*x1v.y;
      acc0.z += wv0.z*xm1.z + wv1.z*x0v.z + wv2.z*x1v.z;
      acc0.w += wv0.w*xm1.w + wv1.w*x0v.w + wv2.w*x1v.w;
      acc1.x += wv0.x*x0v.x + wv1.x*x1v.x + wv2.x*x2v.x;
      acc1.y += wv0.y*x0v.y + wv1.y*x1v.y + wv2.y*x2v.y;
      acc1.z += wv0.z*x0v.z + wv1.z*x1v.z + wv2.z*x2v.z;
      acc1.w += wv0.w*x0v.w + wv1.w*x1v.w + wv2.w*x2v.w;
    }
  }
  size_t bv0 = (size_t)b * cL + (t << 10) + (h << 5) + w0;
  float4 r0 = ld4<F32>(xin, bv0 * cC + c);
  float4 r1 = ld4<F32>(xin, (bv0 + 1) * cC + c);
  *(float4*)(out + bv0 * cC + c) =
      make_float4(r0.x + acc0.x, r0.y + acc0.y, r0.z + acc0.z, r0.w + acc0.w);
  *(float4*)(out + (bv0 + 1) * cC + c) =
      make_float4(r1.x + acc1.x, r1.y + acc1.y, r1.z + acc1.z, r1.w + acc1.w);
}

__global__ void __launch_bounds__(256) cpe_kernel(
    const void* __restrict__ xin, const float* __restrict__ wT,
    const float* __restrict__ bs, const int* __restrict__ flg, int afidx,
    float* __restrict__ out) {
  int idx = blockIdx.x * 256 + threadIdx.x;
  if (idx >= cBL * cC / 8) return;
  if (flg[afidx]) cpe_body<1>(xin, wT, bs, idx, out);
  else            cpe_body<0>(xin, wT, bs, idx, out);
}

// ---------- depthwise conv on DI + SiLU: bf16 in/out, 2 adjacent-w voxels/thread ----------
__global__ void __launch_bounds__(256) dwconv_silu_kernel(
    const unsigned short* __restrict__ xin, const float* __restrict__ wT,
    const float* __restrict__ bs, unsigned short* __restrict__ out) {
  int idx = blockIdx.x * 256 + threadIdx.x;
  if (idx >= cBL * cDI / 8) return;
  int d = (idx % (cDI / 4)) * 4; int pv = idx / (cDI / 4);
  int w0 = (pv & 15) << 1;
  int rest = pv >> 4;
  int h = rest & 31; int bt = rest >> 5; int t = bt & 7; int b = bt >> 3;
  float4 bias = *(const float4*)(bs + d);
  float4 acc0 = bias, acc1 = bias;
  const float4 zero = make_float4(0.f, 0.f, 0.f, 0.f);
#pragma unroll
  for (int dz = 0; dz < 3; ++dz) {
    int tt = t + dz - 1; if ((unsigned)tt >= (unsigned)cT) continue;
#pragma unroll
    for (int dy = 0; dy < 3; ++dy) {
      int hh = h + dy - 1; if ((unsigned)hh >= (unsigned)cH) continue;
      int base = (tt << 10) + (hh << 5);
      const float* wr = wT + (dz * 9 + dy * 3) * cDI + d;
      float4 wv0 = *(const float4*)(wr);
      float4 wv1 = *(const float4*)(wr + cDI);
      float4 wv2 = *(const float4*)(wr + 2 * cDI);
      size_t rb = ((size_t)b * cL + base) * cDI + d;
      float4 xm1 = (w0 > 0)  ? ld4<0>(xin, rb + (size_t)(w0 - 1) * cDI) : zero;
      float4 x0v = ld4<0>(xin, rb + (size_t)w0 * cDI);
      float4 x1v = ld4<0>(xin, rb + (size_t)(w0 + 1) * cDI);
      float4 x2v = (w0 < 30) ? ld4<0>(xin, rb + (size_t)(w0 + 2) * cDI) : zero;
      acc0.x += wv0.x*xm1.x + wv1.x*x0v.x + wv2.x*x1v.x;
      acc0.y += wv0.y*xm1.y + wv1.y*x0v.y + wv2.y*x1v.y;
      acc0.z += wv0.z*xm1.z + wv1.z*x0v.z + wv2.z*x1v.z;
      acc0.w += wv0.w*xm1.w + wv1.w*x0v.w + wv2.w*x1v.w;
      acc1.x += wv0.x*x0v.x + wv1.x*x1v.x + wv2.x*x2v.x;
      acc1.y += wv0.y*x0v.y + wv1.y*x1v.y + wv2.y*x2v.y;
      acc1.z += wv0.z*x0v.z + wv1.z*x1v.z + wv2.z*x2v.z;
      acc1.w += wv0.w*x0v.w + wv1.w*x1v.w + wv2.w*x2v.w;
    }
  }
  size_t bv0 = (size_t)b * cL + (t << 10) + (h << 5) + w0;
  ushort4 o0, o1;
  o0.x = (unsigned short)f2bf(siluf(acc0.x));
  o0.y = (unsigned short)f2bf(siluf(acc0.y));
  o0.z = (unsigned short)f2bf(siluf(acc0.z));
  o0.w = (unsigned short)f2bf(siluf(acc0.w));
  o1.x = (unsigned short)f2bf(siluf(acc1.x));
  o1.y = (unsigned short)f2bf(siluf(acc1.y));
  o1.z = (unsigned short)f2bf(siluf(acc1.z));
  o1.w = (unsigned short)f2bf(siluf(acc1.w));
  *(ushort4*)(out + bv0 * cDI + d) = o0;
  *(ushort4*)(out + (bv0 + 1) * cDI + d) = o1;
}

// ---------- wave-per-row LayerNorm (C=192): no LDS, no barriers, bf16 out ----------
__global__ void __launch_bounds__(256) lnb_kernel(
    const float* __restrict__ in, const void* __restrict__ g,
    const void* __restrict__ bb, const int* __restrict__ flg,
    unsigned short* __restrict__ out) {
  int pf = flg[1];
  int row = blockIdx.x * 4 + (threadIdx.x >> 6);
  int lane = threadIdx.x & 63;
  const float* x = in + (size_t)row * cC;
  float v0 = x[lane], v1 = x[lane + 64], v2 = x[lane + 128];
  float s1 = v0 + v1 + v2;
  float s2 = v0 * v0 + v1 * v1 + v2 * v2;
#pragma unroll
  for (int off = 32; off > 0; off >>= 1) {
    s1 += __shfl_xor(s1, off);
    s2 += __shfl_xor(s2, off);
  }
  float mean = s1 * (1.f / cC);
  float var = s2 * (1.f / cC) - mean * mean;
  float rstd = rsqrtf(var + 1e-6f);
  unsigned short* o = out + (size_t)row * cC;
  o[lane]       = (unsigned short)f2bf((v0 - mean) * rstd * ldsel(g, lane, pf)       + ldsel(bb, lane, pf));
  o[lane + 64]  = (unsigned short)f2bf((v1 - mean) * rstd * ldsel(g, lane + 64, pf)  + ldsel(bb, lane + 64, pf));
  o[lane + 128] = (unsigned short)f2bf((v2 - mean) * rstd * ldsel(g, lane + 128, pf) + ldsel(bb, lane + 128, pf));
}

// ---------- text conditioning ----------
__global__ void __launch_bounds__(384) text_cond_kernel(
    const void* __restrict__ text, const void* __restrict__ tw,
    const void* __restrict__ tb, const int* __restrict__ flg,
    float* __restrict__ cond) {
  int af = flg[0], pf = flg[1];
  __shared__ float mean[cC];
  int b = blockIdx.x;
  for (int c = threadIdx.x; c < cC; c += 384) {
    float s = 0.f;
    for (int t = 0; t < cLT; ++t) s += ldsel(text, ((size_t)b * cLT + t) * cC + c, af);
    mean[c] = s * (1.f / cLT);
  }
  __syncthreads();
  int di = threadIdx.x;
  float a = ldsel(tb, di, pf);
  for (int c = 0; c < cC; ++c) a += mean[c] * ldsel(tw, di * cC + c, pf);
  cond[b * cDI + di] = siluf(a);
}

// ---------- MFMA GEMM: out = epilogue(A[M,K] @ W[N,K]^T), bf16 compute ----------
// W staging vectorized: 2x float4 (fp32) / 1x 16B bf16x8 (bf16) per k-iter
// (was 8 scalar loads) -- all six GEMMs have (nr*K + wks) 16B-aligned.
template <int MODE, int ABF>
__global__ void __launch_bounds__(256) gemm_mfma_kernel(
    const void* __restrict__ A, const void* __restrict__ W,
    int N, int K, const void* __restrict__ bias, const int* __restrict__ flg,
    const float* __restrict__ extra, float* __restrict__ out,
    unsigned short* __restrict__ out2) {
  constexpr int BM = 128, BN = 64, BK = 32, PK = 40;
  __shared__ short As[BM * PK];
  __shared__ short Bs[BN * PK];
  int pf = flg[1];
  int tid = threadIdx.x;
  int m0 = blockIdx.y * BM, n0 = blockIdx.x * BN;
  int lane = tid & 63, wv = tid >> 6;
  int wm = (wv >> 1) * 64, wn = (wv & 1) * 32;
  int lr = lane & 15, quad = lane >> 4;
  f32x4 acc[4][2];
#pragma unroll
  for (int mi = 0; mi < 4; ++mi)
#pragma unroll
    for (int ni = 0; ni < 2; ++ni) { acc[mi][ni][0]=0.f; acc[mi][ni][1]=0.f; acc[mi][ni][2]=0.f; acc[mi][ni][3]=0.f; }
  int ar = tid >> 1, aks = (tid & 1) * 16;
  int wr = tid >> 2, wks = (tid & 3) * 8;
  for (int k0 = 0; k0 < K; k0 += BK) {
    if (ABF) {
      const unsigned short* ap = (const unsigned short*)A + (size_t)(m0 + ar) * K + k0 + aks;
      short* da = &As[ar * PK + aks];
#pragma unroll
      for (int i = 0; i < 4; ++i)
        *(short4v*)(da + i * 4) = *(const short4v*)(ap + i * 4);
    } else {
      const float* ap = (const float*)A + (size_t)(m0 + ar) * K + k0 + aks;
      short* da = &As[ar * PK + aks];
#pragma unroll
      for (int i = 0; i < 4; ++i) {
        float4 v = ((const float4*)ap)[i];
        short4v h; h.x = f2bf(v.x); h.y = f2bf(v.y); h.z = f2bf(v.z); h.w = f2bf(v.w);
        *(short4v*)(da + i * 4) = h;
      }
    }
    {
      int nr = n0 + wr;
      short* db = &Bs[wr * PK + wks];
      if (nr < N) {
        size_t wi = (size_t)nr * K + k0 + wks;
        if (pf) {
          float4 wv0 = *(const float4*)((const float*)W + wi);
          float4 wv1 = *(const float4*)((const float*)W + wi + 4);
          short4v h0, h1;
          h0.x = f2bf(wv0.x); h0.y = f2bf(wv0.y); h0.z = f2bf(wv0.z); h0.w = f2bf(wv0.w);
          h1.x = f2bf(wv1.x); h1.y = f2bf(wv1.y); h1.z = f2bf(wv1.z); h1.w = f2bf(wv1.w);
          *(short4v*)(db) = h0;
          *(short4v*)(db + 4) = h1;
        } else {
          bf16x8 wv = *(const bf16x8*)((const unsigned short*)W + wi);
          *(bf16x8*)(db) = wv;
        }
      } else {
        short4v z; z.x = 0; z.y = 0; z.z = 0; z.w = 0;
        *(short4v*)(db) = z;
        *(short4v*)(db + 4) = z;
      }
    }
    __syncthreads();
    bf16x8 af[4], bfr[2];
#pragma unroll
    for (int mi = 0; mi < 4; ++mi)
      af[mi] = *(const bf16x8*)&As[(wm + mi * 16 + lr) * PK + quad * 8];
#pragma unroll
    for (int ni = 0; ni < 2; ++ni)
      bfr[ni] = *(const bf16x8*)&Bs[(wn + ni * 16 + lr) * PK + quad * 8];
#pragma unroll
    for (int mi = 0; mi < 4; ++mi)
#pragma unroll
      for (int ni = 0; ni < 2; ++ni)
        acc[mi][ni] = __builtin_amdgcn_mfma_f32_16x16x32_bf16(af[mi], bfr[ni], acc[mi][ni], 0, 0, 0);
    __syncthreads();
  }
#pragma unroll
  for (int mi = 0; mi < 4; ++mi) {
#pragma unroll
    for (int ni = 0; ni < 2; ++ni) {
#pragma unroll
      for (int r = 0; r < 4; ++r) {
        int m = m0 + wm + mi * 16 + quad * 4 + r;
        int n = n0 + wn + ni * 16 + lr;
        float v = acc[mi][ni][r];
        if (MODE == 0) {
          float bvv = ldsel(bias, n, pf);
          int b = m >> 13;
          if (n < cDI)
            ((unsigned short*)out)[(size_t)m * cDI + n] =
                (unsigned short)f2bf(v + bvv + extra[b * cDI + n]);
          else
            out2[(size_t)m * cDI + (n - cDI)] = (unsigned short)f2bf(v + bvv);
        } else if (MODE == 1) {
          if (n < cK * XROW) {
            int k = n / XROW, c = n - k * XROW;
            int b = m >> 13, vv = m & (cL - 1);
            int t = vv >> 10, q = vv & 1023, h = q >> 5, w = q & 31;
            int l1 = (t << 10) + (w << 5) + h;
            int lk = (k == 0) ? vv : (k == 1) ? l1 : (k == 2) ? (cL - 1 - vv) : (cL - 1 - l1);
            out[((size_t)(b * cK + k) * cL + lk) * XSTR + c] = v;
          }
        } else if (MODE == 2) {
          out[(size_t)m * cC + n] = v + extra[(size_t)m * cC + n];
        } else if (MODE == 3) {
          ((unsigned short*)out)[(size_t)m * cHID + n] =
              (unsigned short)f2bf(gelut(v + ldsel(bias, n, pf)));
        } else {
          out[(size_t)m * cC + n] = v + ldsel(bias, n, pf) + extra[(size_t)m * cC + n];
        }
      }
    }
  }
}

// voxel index for scan position l in direction k
DEV int scan_voxel(int k, int l) {
  if (k == 0) return l;
  if (k == 2) return cL - 1 - l;
  int ll = (k == 1) ? l : (cL - 1 - l);
  int t = ll >> 10, q = ll & 1023, w = q >> 5, h = q & 31;
  return (t << 10) + (h << 5) + w;
}

// ---------- register row structs (constant-indexed, SROA-friendly) ----------
struct Row11 { float4 r0, r1, r2, r3, r4, r5, r6, r7, r8, r9, r10; };
struct Row7  { float4 r0, r1, r2, r7, r8, r9, r10; };

DEV Row11 ldrow11(const float* __restrict__ rows, int st) {
  const float4* rp = (const float4*)(rows + st * XSTR);
  Row11 q;
  q.r0 = rp[0]; q.r1 = rp[1]; q.r2 = rp[2]; q.r3 = rp[3]; q.r4 = rp[4];
  q.r5 = rp[5]; q.r6 = rp[6]; q.r7 = rp[7]; q.r8 = rp[8]; q.r9 = rp[9];
  q.r10 = rp[10];
  return q;
}
DEV Row7 ldrow7(const float* __restrict__ rows, int st) {
  const float4* rp = (const float4*)(rows + st * XSTR);
  Row7 q;
  q.r0 = rp[0]; q.r1 = rp[1]; q.r2 = rp[2];
  q.r7 = rp[7]; q.r8 = rp[8]; q.r9 = rp[9]; q.r10 = rp[10];
  return q;
}

// packed dtr dot: 6 packed FMA + horizontal (was 12 scalar)
DEV float dtdot(const Row11& q, const f32x2 (&wp)[6], float dtb) {
  f32x2 acc = mk2(dtb, 0.f);
  acc += mk2(q.r0.x, q.r0.y) * wp[0];
  acc += mk2(q.r0.z, q.r0.w) * wp[1];
  acc += mk2(q.r1.x, q.r1.y) * wp[2];
  acc += mk2(q.r1.z, q.r1.w) * wp[3];
  acc += mk2(q.r2.x, q.r2.y) * wp[4];
  acc += mk2(q.r2.z, q.r2.w) * wp[5];
  return acc[0] + acc[1];
}
DEV float dtdot7(const Row7& q, const f32x2 (&wp)[6], float dtb) {
  f32x2 acc = mk2(dtb, 0.f);
  acc += mk2(q.r0.x, q.r0.y) * wp[0];
  acc += mk2(q.r0.z, q.r0.w) * wp[1];
  acc += mk2(q.r1.x, q.r1.y) * wp[2];
  acc += mk2(q.r1.z, q.r1.w) * wp[3];
  acc += mk2(q.r2.x, q.r2.y) * wp[4];
  acc += mk2(q.r2.z, q.r2.w) * wp[5];
  return acc[0] + acc[1];
}

// packed power chain: pw[i] = (a^(2i+1), a^(2i+2)); 1 scalar + 7 packed muls
DEV void powpk(float a1, f32x2 (&pw)[8]) {
  float a2 = a1 * a1;
  f32x2 sq = mk2(a2, a2);
  pw[0] = mk2(a1, a2);
  pw[1] = pw[0] * sq;
  pw[2] = pw[1] * sq;
  pw[3] = pw[2] * sq;
  pw[4] = pw[3] * sq;
  pw[5] = pw[4] * sq;
  pw[6] = pw[5] * sq;
  pw[7] = pw[6] * sq;
}

// one fast-path scan1 step, packed fp32 throughout
DEV float s1step(const Row11& q, float u,
                 const f32x2 (&wp)[6], float dtb, float ac0, float Dsd,
                 f32x2 (&h)[8], float& P1) {
  float dt = softplusf(dtdot(q, wp, dtb));
  float a1 = exp2f(dt * ac0);
  f32x2 pw[8];
  powpk(a1, pw);
  float dtu = dt * u;
  P1 *= a1;
  f32x2 dtu2 = mk2(dtu, dtu);
  f32x2 B0 = mk2(q.r3.x,q.r3.y), B1 = mk2(q.r3.z,q.r3.w);
  f32x2 B2 = mk2(q.r4.x,q.r4.y), B3 = mk2(q.r4.z,q.r4.w);
  f32x2 B4 = mk2(q.r5.x,q.r5.y), B5 = mk2(q.r5.z,q.r5.w);
  f32x2 B6 = mk2(q.r6.x,q.r6.y), B7 = mk2(q.r6.z,q.r6.w);
  f32x2 C0 = mk2(q.r7.x,q.r7.y), C1 = mk2(q.r7.z,q.r7.w);
  f32x2 C2 = mk2(q.r8.x,q.r8.y), C3 = mk2(q.r8.z,q.r8.w);
  f32x2 C4 = mk2(q.r9.x,q.r9.y), C5 = mk2(q.r9.z,q.r9.w);
  f32x2 C6 = mk2(q.r10.x,q.r10.y), C7 = mk2(q.r10.z,q.r10.w);
  f32x2 y0 = mk2(Dsd * u, 0.f), y1 = mk2(0.f,0.f), y2 = mk2(0.f,0.f), y3 = mk2(0.f,0.f);
  h[0] = h[0]*pw[0] + dtu2*B0; y0 += h[0]*C0;
  h[1] = h[1]*pw[1] + dtu2*B1; y1 += h[1]*C1;
  h[2] = h[2]*pw[2] + dtu2*B2; y2 += h[2]*C2;
  h[3] = h[3]*pw[3] + dtu2*B3; y3 += h[3]*C3;
  h[4] = h[4]*pw[4] + dtu2*B4; y0 += h[4]*C4;
  h[5] = h[5]*pw[5] + dtu2*B5; y1 += h[5]*C5;
  h[6] = h[6]*pw[6] + dtu2*B6; y2 += h[6]*C6;
  h[7] = h[7]*pw[7] + dtu2*B7; y3 += h[7]*C7;
  f32x2 t = (y0 + y1) + (y2 + y3);
  return t[0] + t[1];
}

// one fast-path scan3 step, packed fp32
DEV float s3step(const Row7& q,
                 const f32x2 (&wp)[6], float dtb, float ac0,
                 f32x2 (&g)[8]) {
  float dt = softplusf(dtdot7(q, wp, dtb));
  float a1 = exp2f(dt * ac0);
  f32x2 pw[8];
  powpk(a1, pw);
  f32x2 C0 = mk2(q.r7.x,q.r7.y), C1 = mk2(q.r7.z,q.r7.w);
  f32x2 C2 = mk2(q.r8.x,q.r8.y), C3 = mk2(q.r8.z,q.r8.w);
  f32x2 C4 = mk2(q.r9.x,q.r9.y), C5 = mk2(q.r9.z,q.r9.w);
  f32x2 C6 = mk2(q.r10.x,q.r10.y), C7 = mk2(q.r10.z,q.r10.w);
  f32x2 y0 = mk2(0.f,0.f), y1 = mk2(0.f,0.f), y2 = mk2(0.f,0.f), y3 = mk2(0.f,0.f);
  g[0] *= pw[0]; y0 += g[0]*C0;
  g[1] *= pw[1]; y1 += g[1]*C1;
  g[2] *= pw[2]; y2 += g[2]*C2;
  g[3] *= pw[3]; y3 += g[3]*C3;
  g[4] *= pw[4]; y0 += g[4]*C4;
  g[5] *= pw[5]; y1 += g[5]*C5;
  g[6] *= pw[6]; y2 += g[6]*C6;
  g[7] *= pw[7]; y3 += g[7]*C7;
  f32x2 t = (y0 + y1) + (y2 + y3);
  return t[0] + t[1];
}

// ---------- scan pass 1 (128 thr, 1 ch/thread, bf16 streams, packed fp32) ----------
__global__ void __launch_bounds__(128, 3) scan1_kernel(
    const unsigned short* __restrict__ xch, const float* __restrict__ xdbl,
    const void* __restrict__ dtw, const void* __restrict__ dtbv,
    const void* __restrict__ alog, const void* __restrict__ dsv,
    const int* __restrict__ flg,
    unsigned short* __restrict__ ys0, unsigned short* __restrict__ ys1,
    unsigned short* __restrict__ ys2, unsigned short* __restrict__ ys3,
    unsigned short* __restrict__ hend, unsigned short* __restrict__ pend) {
  __shared__ float rows[SEGLEN * XSTR];   // 64 x 48 floats = 12 KB
  int pf = flg[1];
  int tid = threadIdx.x;
  int d = blockIdx.x * 128 + tid;
  int bks = blockIdx.y;
  int s = bks & (SEG - 1); int bk = bks / SEG; int k = bk & 3; int b = bk >> 2;
  int l0 = s * SEGLEN;
  {
    const float4* src = (const float4*)(xdbl + ((size_t)bk * cL + l0) * XSTR);
    float4* dst = (float4*)rows;
#pragma unroll
    for (int i = 0; i < (SEGLEN * XSTR / 4) / 128; ++i)   // 6 iters
      dst[tid + i * 128] = src[tid + i * 128];
  }
  float wdt[cDTR];
#pragma unroll
  for (int r = 0; r < cDTR; ++r) wdt[r] = ldsel(dtw, (size_t)(k * cDI + d) * cDTR + r, pf);
  f32x2 wp[6];
#pragma unroll
  for (int r = 0; r < 6; ++r) wp[r] = mk2(wdt[2 * r], wdt[2 * r + 1]);
  float dtb = ldsel(dtbv, k * cDI + d, pf);
  float ac[cN];
#pragma unroll
  for (int n = 0; n < cN; ++n)
    ac[n] = -__expf(ldsel(alog, (size_t)(k * cDI + d) * cN + n, pf)) * 1.4426950408889634f;
  bool fast = true;
#pragma unroll
  for (int n = 1; n < cN; ++n)
    fast = fast && (fabsf(ac[n] - (float)(n + 1) * ac[0]) <= 1e-3f * fabsf(ac[n]));
  float Dsd = ldsel(dsv, k * cDI + d, pf);
  size_t so = ((size_t)bks * cDI + d) * cN;
  const unsigned short* xcb = xch + (size_t)b * cL * cDI + d;
  unsigned short* ysk = (k == 0) ? ys0 : (k == 1) ? ys1 : (k == 2) ? ys2 : ys3;
  unsigned short* ysrow = ysk + ((size_t)b * cL + l0) * cDI + d;
  __syncthreads();
  if (fast) {
    float ac0 = ac[0];
    float P1 = 1.f;
    f32x2 h2[8];
#pragma unroll
    for (int i = 0; i < 8; ++i) h2[i] = mk2(0.f, 0.f);
    Row11 qa = ldrow11(rows, 0);
    float u0 = bfu2f(xcb[(size_t)scan_voxel(k, l0) * cDI]);
    float u1 = bfu2f(xcb[(size_t)scan_voxel(k, l0 + 1) * cDI]);
    for (int st = 0; st < SEGLEN; st += 2) {
      Row11 qb = ldrow11(rows, st + 1);
      int p2 = (st + 2 < SEGLEN) ? st + 2 : SEGLEN - 1;
      int p3 = (st + 3 < SEGLEN) ? st + 3 : SEGLEN - 1;
      float nu0 = bfu2f(xcb[(size_t)scan_voxel(k, l0 + p2) * cDI]);
      float nu1 = bfu2f(xcb[(size_t)scan_voxel(k, l0 + p3) * cDI]);
      float ya = s1step(qa, u0, wp, dtb, ac0, Dsd, h2, P1);
      ysrow[(size_t)st * cDI] = (unsigned short)f2bf(ya);
      qa = ldrow11(rows, p2);
      float yb = s1step(qb, u1, wp, dtb, ac0, Dsd, h2, P1);
      ysrow[(size_t)(st + 1) * cDI] = (unsigned short)f2bf(yb);
      u0 = nu0; u1 = nu1;
    }
    float pp = P1;
#pragma unroll
    for (int i = 0; i < 8; ++i) {
      hend[so + 2*i]     = (unsigned short)f2bf(h2[i][0]);
      hend[so + 2*i + 1] = (unsigned short)f2bf(h2[i][1]);
    }
#pragma unroll
    for (int n = 0; n < cN; ++n) {
      pend[so + n] = (unsigned short)f2bf(pp);
      pp *= P1;
    }
  } else {
    float h[cN], P[cN];
#pragma unroll
    for (int n = 0; n < cN; ++n) { h[n] = 0.f; P[n] = 1.f; }
    for (int st = 0; st < SEGLEN; ++st) {
      int l = l0 + st;
      const float4* rp = (const float4*)(rows + st * XSTR);
      float4 q0 = rp[0], q1 = rp[1], q2 = rp[2];
      float s0 = dtb + q0.x*wdt[0] + q0.z*wdt[2] + q1.x*wdt[4] + q1.z*wdt[6] + q2.x*wdt[8] + q2.z*wdt[10];
      float s1 = q0.y*wdt[1] + q0.w*wdt[3] + q1.y*wdt[5] + q1.w*wdt[7] + q2.y*wdt[9] + q2.w*wdt[11];
      float dt = softplusf(s0 + s1);
      float Bv[cN], Cv[cN];
      float4 qb0 = rp[3], qb1 = rp[4], qb2 = rp[5], qb3 = rp[6];
      float4 qc0 = rp[7], qc1 = rp[8], qc2 = rp[9], qc3 = rp[10];
      Bv[0]=qb0.x; Bv[1]=qb0.y; Bv[2]=qb0.z; Bv[3]=qb0.w;
      Bv[4]=qb1.x; Bv[5]=qb1.y; Bv[6]=qb1.z; Bv[7]=qb1.w;
      Bv[8]=qb2.x; Bv[9]=qb2.y; Bv[10]=qb2.z; Bv[11]=qb2.w;
      Bv[12]=qb3.x; Bv[13]=qb3.y; Bv[14]=qb3.z; Bv[15]=qb3.w;
      Cv[0]=qc0.x; Cv[1]=qc0.y; Cv[2]=qc0.z; Cv[3]=qc0.w;
      Cv[4]=qc1.x; Cv[5]=qc1.y; Cv[6]=qc1.z; Cv[7]=qc1.w;
      Cv[8]=qc2.x; Cv[9]=qc2.y; Cv[10]=qc2.z; Cv[11]=qc2.w;
      Cv[12]=qc3.x; Cv[13]=qc3.y; Cv[14]=qc3.z; Cv[15]=qc3.w;
      int v = scan_voxel(k, l);
      float u = bfu2f(xcb[(size_t)v * cDI]);
      float dtu = dt * u;
      float y = Dsd * u;
#pragma unroll
      for (int n = 0; n < cN; ++n) {
        float a = exp2f(dt * ac[n]);
        h[n] = h[n] * a + dtu * Bv[n];
        P[n] *= a;
        y += h[n] * Cv[n];
      }
      ysrow[(size_t)st * cDI] = (unsigned short)f2bf(y);
    }
#pragma unroll
    for (int n = 0; n < cN; ++n) {
      hend[so + n] = (unsigned short)f2bf(h[n]);
      pend[so + n] = (unsigned short)f2bf(P[n]);
    }
  }
}

// ---------- scan pass 2 (serial prefix over segments; fp32 recurrence, bf16 storage) ----------
__global__ void __launch_bounds__(256) scan2_kernel(
    unsigned short* __restrict__ hend, const unsigned short* __restrict__ pend) {
  int tid = blockIdx.x * 256 + threadIdx.x;
  int bk = tid / (cDI * cN); int r = tid - bk * (cDI * cN);
  float g = 0.f;
  for (int s = 0; s < SEG; ++s) {
    size_t o = ((size_t)(bk * SEG + s) * cDI * cN) + r;
    float he = bfu2f(hend[o]), pe = bfu2f(pend[o]);
    hend[o] = (unsigned short)f2bf(g);
    g = pe * g + he;
  }
}

// ---------- scan pass 3 (owned read-add-store; packed fp32) ----------
__global__ void __launch_bounds__(128, 3) scan3_kernel(
    const float* __restrict__ xdbl,
    const void* __restrict__ dtw, const void* __restrict__ dtbv,
    const void* __restrict__ alog, const int* __restrict__ flg,
    const unsigned short* __restrict__ hin,
    unsigned short* __restrict__ ys0, unsigned short* __restrict__ ys1,
    unsigned short* __restrict__ ys2, unsigned short* __restrict__ ys3) {
  int bks = blockIdx.y;
  int s = bks & (SEG - 1);
  if (s == 0) return;
  __shared__ float rows[SEGLEN * XSTR];
  int pf = flg[1];
  int tid = threadIdx.x;
  int d = blockIdx.x * 128 + tid;
  int bk = bks / SEG; int k = bk & 3; int b = bk >> 2;
  int l0 = s * SEGLEN;
  {
    const float4* src = (const float4*)(xdbl + ((size_t)bk * cL + l0) * XSTR);
    float4* dst = (float4*)rows;
#pragma unroll
    for (int i = 0; i < (SEGLEN * XSTR / 4) / 128; ++i)
      dst[tid + i * 128] = src[tid + i * 128];
  }
  float wdt[cDTR];
#pragma unroll
  for (int r = 0; r < cDTR; ++r) wdt[r] = ldsel(dtw, (size_t)(k * cDI + d) * cDTR + r, pf);
  f32x2 wp[6];
#pragma unroll
  for (int r = 0; r < 6; ++r) wp[r] = mk2(wdt[2 * r], wdt[2 * r + 1]);
  float dtb = ldsel(dtbv, k * cDI + d, pf);
  float ac[cN];
#pragma unroll
  for (int n = 0; n < cN; ++n)
    ac[n] = -__expf(ldsel(alog, (size_t)(k * cDI + d) * cN + n, pf)) * 1.4426950408889634f;
  bool fast = true;
#pragma unroll
  for (int n = 1; n < cN; ++n)
    fast = fast && (fabsf(ac[n] - (float)(n + 1) * ac[0]) <= 1e-3f * fabsf(ac[n]));
  size_t so = ((size_t)bks * cDI + d) * cN;
  unsigned short* ysk = (k == 0) ? ys0 : (k == 1) ? ys1 : (k == 2) ? ys2 : ys3;
  unsigned short* ysrow = ysk + ((size_t)b * cL + l0) * cDI + d;
  __syncthreads();
  if (fast) {
    float ac0 = ac[0];
    f32x2 g2[8];
#pragma unroll
    for (int i = 0; i < 8; ++i)
      g2[i] = mk2(bfu2f(hin[so + 2*i]), bfu2f(hin[so + 2*i + 1]));
    Row7 qa = ldrow7(rows, 0);
    for (int st = 0; st < SEGLEN; st += 2) {
      Row7 qb = ldrow7(rows, st + 1);
      int p2 = (st + 2 < SEGLEN) ? st + 2 : SEGLEN - 1;
      float ya = s3step(qa, wp, dtb, ac0, g2);
      size_t ia = (size_t)st * cDI;
      ysrow[ia] = (unsigned short)f2bf(bfu2f(ysrow[ia]) + ya);
      qa = ldrow7(rows, p2);
      float yb = s3step(qb, wp, dtb, ac0, g2);
      size_t ib = (size_t)(st + 1) * cDI;
      ysrow[ib] = (unsigned short)f2bf(bfu2f(ysrow[ib]) + yb);
    }
  } else {
    float g[cN];
#pragma unroll
    for (int n = 0; n < cN; ++n) g[n] = bfu2f(hin[so + n]);
    for (int st = 0; st < SEGLEN; ++st) {
      const float4* rp = (const float4*)(rows + st * XSTR);
      float4 q0 = rp[0], q1 = rp[1], q2 = rp[2];
      float s0 = dtb + q0.x*wdt[0] + q0.z*wdt[2] + q1.x*wdt[4] + q1.z*wdt[6] + q2.x*wdt[8] + q2.z*wdt[10];
      float s1 = q0.y*wdt[1] + q0.w*wdt[3] + q1.y*wdt[5] + q1.w*wdt[7] + q2.y*wdt[9] + q2.w*wdt[11];
      float dt = softplusf(s0 + s1);
      float Cv[cN];
      float4 qc0 = rp[7], qc1 = rp[8], qc2 = rp[9], qc3 = rp[10];
      Cv[0]=qc0.x; Cv[1]=qc0.y; Cv[2]=qc0.z; Cv[3]=qc0.w;
      Cv[4]=qc1.x; Cv[5]=qc1.y; Cv[6]=qc1.z; Cv[7]=qc1.w;
      Cv[8]=qc2.x; Cv[9]=qc2.y; Cv[10]=qc2.z; Cv[11]=qc2.w;
      Cv[12]=qc3.x; Cv[13]=qc3.y; Cv[14]=qc3.z; Cv[15]=qc3.w;
      float y = 0.f;
#pragma unroll
      for (int n = 0; n < cN; ++n) {
        float a = exp2f(dt * ac[n]);
        g[n] *= a;
        y += g[n] * Cv[n];
      }
      size_t ii = (size_t)st * cDI;
      ysrow[ii] = (unsigned short)f2bf(bfu2f(ysrow[ii]) + y);
    }
  }
}

// ---------- merge: wave-per-row gather of 4 dirs + out_norm LN + silu(z) gate ----------
__global__ void __launch_bounds__(256) merge_kernel(
    const unsigned short* __restrict__ ys0, const unsigned short* __restrict__ ys1,
    const unsigned short* __restrict__ ys2, const unsigned short* __restrict__ ys3,
    const unsigned short* __restrict__ zh,
    const void* __restrict__ ong, const void* __restrict__ onb,
    const int* __restrict__ flg, unsigned short* __restrict__ yg) {
  int pf = flg[1];
  int bv = blockIdx.x * 4 + (threadIdx.x >> 6);
  int lane = threadIdx.x & 63;
  int v = bv & (cL - 1); int b = bv >> 13;
  int t = v >> 10, q = v & 1023, hh = q >> 5, ww = q & 31;
  int l1 = (t << 10) + (ww << 5) + hh;
  size_t r0 = ((size_t)b * cL + v) * cDI;
  size_t r1 = ((size_t)b * cL + l1) * cDI;
  size_t r2 = ((size_t)b * cL + (cL - 1 - v)) * cDI;
  size_t r3 = ((size_t)b * cL + (cL - 1 - l1)) * cDI;
  float vals[6]; float s1 = 0.f, s2 = 0.f;
#pragma unroll
  for (int i = 0; i < 6; ++i) {
    int d = lane + i * 64;
    float x = bfu2f(ys0[r0 + d]) + bfu2f(ys1[r1 + d]) +
              bfu2f(ys2[r2 + d]) + bfu2f(ys3[r3 + d]);
    vals[i] = x; s1 += x; s2 += x * x;
  }
#pragma unroll
  for (int off = 32; off > 0; off >>= 1) {
    s1 += __shfl_xor(s1, off);
    s2 += __shfl_xor(s2, off);
  }
  float mean = s1 * (1.f / cDI);
  float var = s2 * (1.f / cDI) - mean * mean;
  float rstd = rsqrtf(var + 1e-6f);
  const unsigned short* zr = zh + (size_t)bv * cDI;
  unsigned short* og = yg + (size_t)bv * cDI;
#pragma unroll
  for (int i = 0; i < 6; ++i) {
    int d = lane + i * 64;
    float xn = (vals[i] - mean) * rstd * ldsel(ong, d, pf) + ldsel(onb, d, pf);
    og[d] = (unsigned short)f2bf(xn * siluf(bfu2f(zr[d])));
  }
}

}  // namespace

extern "C" void kernel_launch(void* const* d_in, const int* in_sizes, int n_in,
                              void* d_out, int out_size, void* d_ws, size_t ws_size,
                              hipStream_t stream) {
  (void)in_sizes; (void)n_in; (void)out_size; (void)ws_size;
  const void* x    = d_in[0];
  const void* text = d_in[1];
  const void* c1w  = d_in[2];
  const void* c1b  = d_in[3];
  const void* c2w  = d_in[4];
  const void* c2b  = d_in[5];
  const void* n1g  = d_in[6];
  const void* n1b  = d_in[7];
  const void* n2g  = d_in[8];
  const void* n2b  = d_in[9];
  const void* ipw  = d_in[10];
  const void* ipb  = d_in[11];
  const void* tpw  = d_in[12];
  const void* tpb  = d_in[13];
  const void* cvw  = d_in[14];
  const void* cvb  = d_in[15];
  const void* xpw  = d_in[16];
  const void* dtw  = d_in[17];
  const void* dtb  = d_in[18];
  const void* alog = d_in[19];
  const void* dsv  = d_in[20];
  const void* ong  = d_in[21];
  const void* onb  = d_in[22];
  const void* opw  = d_in[23];
  const void* f1w  = d_in[24];
  const void* f1b  = d_in[25];
  const void* f2w  = d_in[26];
  const void* f2b  = d_in[27];

  float* Wf = (float*)d_ws;

  // ---- slot arena (~125.9 MB), atomic-free scan + bf16 activations ----
  constexpr size_t oC  = 0;                              // 6,291,456
  constexpr size_t oD  = 6291456;                        // 3,145,728
  constexpr size_t oG  = 9437184;                        // 3,145,728
  constexpr size_t oA  = 12582912;                       // 6,291,456
  constexpr size_t oB  = 18874368;                       // 6,291,456
  constexpr size_t oE  = 25165824;                       // 3,145,728
  constexpr size_t oF  = 28311552;                       // 3,145,728
  constexpr size_t oCO = 31457280;                       // 768 (cond)
  constexpr size_t oFL = 31458048;                       // 4 ints (flags)
  constexpr size_t oWCV = 31458052;                      // 27*384
  constexpr size_t oBCV = 31468420;                      // 384
  constexpr size_t oW1  = 31468804;                      // 27*192
  constexpr size_t oB1  = 31473988;                      // 192
  constexpr size_t oW2  = 31474180;                      // 5184
  constexpr size_t oB2  = 31479364;                      // 192 -> end 31479556
  unsigned short* xch = (unsigned short*)(Wf + oC);            // bf16 silu(dwconv)
  unsigned short* ysd2 = (unsigned short*)(Wf + oC + 3145728); // ystream dir 2
  unsigned short* hbufh = (unsigned short*)(Wf + oC);          // fc1 out bf16
  float* xdbl = Wf + oD;
  unsigned short* ygh  = (unsigned short*)(Wf + oD);           // yg bf16 (after xdbl dead)
  unsigned short* xnh  = (unsigned short*)(Wf + oG);           // LN1 out bf16
  unsigned short* pendp = (unsigned short*)(Wf + oG);          // bf16, after xnh dead
  unsigned short* xib  = (unsigned short*)(Wf + oA);           // in_proj x-half bf16
  unsigned short* ysd0 = (unsigned short*)(Wf + oA);           // ystream dir 0 (xib dead)
  unsigned short* ysd1 = (unsigned short*)(Wf + oA + 3145728); // ystream dir 1
  float* x2   = Wf + oA;   // out_proj output (after ystream dead)
  unsigned short* zh   = (unsigned short*)(Wf + oB);           // z bf16
  unsigned short* ysd3 = (unsigned short*)(Wf + oB + 3145728); // ystream dir 3
  float* x3   = Wf + oB;
  float* x1   = Wf + oE;
  unsigned short* hendp = (unsigned short*)(Wf + oF);          // bf16
  unsigned short* xn2h = (unsigned short*)(Wf + oF);           // LN2 out bf16 (hend dead)
  float* cond = Wf + oCO;
  int*   flg  = (int*)(Wf + oFL);
  float* wcv = Wf + oWCV; float* bcv = Wf + oBCV;
  float* w1t = Wf + oW1;  float* b1t = Wf + oB1;
  float* w2t = Wf + oW2;  float* b2t = Wf + oB2;

  const int cpeBlocks = (cBL * cC / 8) / 256;     // 1536 (2 voxels/thread)
  const int dwBlocks  = (cBL * cDI / 8) / 256;    // 3072 (2 voxels/thread)

  // 0. dtype detection + conv weight prep
  hipLaunchKernelGGL(detect_kernel, dim3(1), dim3(256), 0, stream,
                     (const unsigned short*)x, (const unsigned short*)ipw, flg);
  hipLaunchKernelGGL(prep_kernel, dim3(85), dim3(256), 0, stream,
                     cvw, cvb, c1w, c1b, c2w, c2b, flg, wcv, bcv, w1t, b1t, w2t, b2t);
  // 1. x1 = x + cpe1(x)
  hipLaunchKernelGGL(cpe_kernel, dim3(cpeBlocks), dim3(256), 0, stream,
                     x, w1t, b1t, flg, 0, x1);
  // 2. xnh = bf16(LN1(x1))  (wave-per-row, no barriers)
  hipLaunchKernelGGL(lnb_kernel, dim3(cBL / 4), dim3(256), 0, stream, x1, n1g, n1b, flg, xnh);
  // 3. cond
  hipLaunchKernelGGL(text_cond_kernel, dim3(cB), dim3(384), 0, stream, text, tpw, tpb, flg, cond);
  // 4. in_proj (MFMA, bf16 A): xnh -> xib bf16 (+cond), zh bf16
  hipLaunchKernelGGL((gemm_mfma_kernel<0, 1>), dim3(2 * cDI / 64, cBL / 128), dim3(256), 0, stream,
                     xnh, ipw, 2 * cDI, cC, ipb, flg, cond, (float*)xib, zh);
  // 5. xch = bf16(silu(dwconv(xib)))
  hipLaunchKernelGGL(dwconv_silu_kernel, dim3(dwBlocks), dim3(256), 0, stream,
                     xib, wcv, bcv, xch);
  // 6. x_proj (MFMA, bf16 A, scatter to padded scan rows)
  hipLaunchKernelGGL((gemm_mfma_kernel<1, 1>), dim3((cK * XROW + 63) / 64, cBL / 128), dim3(256), 0, stream,
                     xch, xpw, cK * XROW, cDI, (const void*)nullptr, flg,
                     (const float*)nullptr, xdbl, (unsigned short*)nullptr);
  // 7-9. chunked selective scan (packed fp32 inner loops)
  hipLaunchKernelGGL(scan1_kernel, dim3(cDI / 128, cB * cK * SEG), dim3(128), 0, stream,
                     xch, xdbl, dtw, dtb, alog, dsv, flg,
                     ysd0, ysd1, ysd2, ysd3, hendp, pendp);
  hipLaunchKernelGGL(scan2_kernel, dim3(cB * cK * cDI * cN / 256), dim3(256), 0, stream,
                     hendp, pendp);
  hipLaunchKernelGGL(scan3_kernel, dim3(cDI / 128, cB * cK * SEG), dim3(128), 0, stream,
                     xdbl, dtw, dtb, alog, flg, hendp, ysd0, ysd1, ysd2, ysd3);
  // 10. merge: wave-per-row gather + out_norm + gate -> yg bf16
  hipLaunchKernelGGL(merge_kernel, dim3(cBL / 4), dim3(256), 0, stream,
                     ysd0, ysd1, ysd2, ysd3, zh, ong, onb, flg, ygh);
  // 11. out_proj (bf16 A) + residual(x1) -> x2 fp32
  hipLaunchKernelGGL((gemm_mfma_kernel<2, 1>), dim3(cC / 64, cBL / 128), dim3(256), 0, stream,
                     ygh, opw, cC, cDI, (const void*)nullptr, flg, x1, x2,
                     (unsigned short*)nullptr);
  // 12. x3 = x2 + cpe2(x2)  (flg[2]=1 -> fp32 input path)
  hipLaunchKernelGGL(cpe_kernel, dim3(cpeBlocks), dim3(256), 0, stream,
                     x2, w2t, b2t, flg, 2, x3);
  // 13. xn2h = bf16(LN2(x3))
  hipLaunchKernelGGL(lnb_kernel, dim3(cBL / 4), dim3(256), 0, stream, x3, n2g, n2b, flg, xn2h);
  // 14. fc1 + gelu -> hbufh bf16 (MFMA, bf16 A)
  hipLaunchKernelGGL((gemm_mfma_kernel<3, 1>), dim3(cHID / 64, cBL / 128), dim3(256), 0, stream,
                     xn2h, f1w, cHID, cC, f1b, flg, (const float*)nullptr, (float*)hbufh,
                     (unsigned short*)nullptr);
  // 15. fc2 (bf16 A) + bias + residual(x3) -> d_out fp32 (MFMA)
  hipLaunchKernelGGL((gemm_mfma_kernel<4, 1>), dim3(cC / 64, cBL / 128), dim3(256), 0, stream,
                     hbufh, f2w, cC, cHID, f2b, flg, x3, (float*)d_out,
                     (unsigned short*)nullptr);
}

// Round 14
// 540.898 us; speedup vs baseline: 1.1859x; 1.0168x over previous
//
#include <hip/hip_runtime.h>
#include <hip/hip_bf16.h>

#define DEV __device__ __forceinline__

namespace {

constexpr int cB = 2, cT = 8, cH = 32, cW = 32, cC = 192;
constexpr int cDI = 384, cN = 16, cK = 4, cDTR = 12, cLT = 77, cHID = 768;
constexpr int cL  = cT * cH * cW;      // 8192
constexpr int cBL = cB * cL;           // 16384
constexpr int SEG = 128, SEGLEN = cL / SEG;   // 128 segments x 64 steps
constexpr int XROW = cDTR + 2 * cN;    // 44 live cols
constexpr int XSTR = 48;               // padded row stride (float4-aligned)

typedef __attribute__((ext_vector_type(8))) short bf16x8;
typedef __attribute__((ext_vector_type(4))) float f32x4;
typedef __attribute__((ext_vector_type(2))) float f32x2;
typedef __attribute__((ext_vector_type(4))) short short4v;

// ---------- scalar helpers ----------
DEV float bfu2f(unsigned short u) { return __uint_as_float(((unsigned)u) << 16); }
DEV float ldsel(const void* p, size_t i, int f32) {
  return f32 ? ((const float*)p)[i] : bfu2f(((const unsigned short*)p)[i]);
}
template <int F32>
DEV float4 ld4(const void* p, size_t e) {   // e: element index, multiple of 4
  if (F32) return *(const float4*)((const float*)p + e);
  ushort4 u = *(const ushort4*)((const unsigned short*)p + e);
  return make_float4(bfu2f(u.x), bfu2f(u.y), bfu2f(u.z), bfu2f(u.w));
}
DEV short f2bf(float f) {   // RNE float->bf16 bits
  unsigned u = __float_as_uint(f);
  u += 0x7fffu + ((u >> 16) & 1u);
  return (short)(u >> 16);
}
DEV float siluf(float x) { return x / (1.f + __expf(-x)); }
DEV float softplusf(float x) { return (x > 20.f) ? x : __logf(1.f + __expf(x)); }
DEV float gelut(float x) {            // tanh-approx gelu (JAX default)
  float u = 0.7978845608028654f * (x + 0.044715f * x * x * x);
  float e = __expf(2.f * u);
  float th = 1.f - 2.f / (e + 1.f);
  return 0.5f * x * (1.f + th);
}
DEV f32x2 mk2(float a, float b) { f32x2 v; v[0] = a; v[1] = b; return v; }

// ---------- dtype detector (validated: inputs are fp32) ----------
__global__ void __launch_bounds__(256) detect_kernel(
    const unsigned short* __restrict__ xa, const unsigned short* __restrict__ wp,
    int* __restrict__ flg) {
  __shared__ int cnt[2];
  if (threadIdx.x < 2) cnt[threadIdx.x] = 0;
  __syncthreads();
  int l0 = 0, l1 = 0;
  for (int i = threadIdx.x; i < 1024; i += 256) {
    float v = bfu2f(xa[2 * i]); float a = fabsf(v);
    if (v == 0.f || (a > 1e-8f && a < 1e4f)) l0++;
    float u = bfu2f(wp[2 * i]); float bq = fabsf(u);
    if (u == 0.f || (bq > 1e-8f && bq < 1e4f)) l1++;
  }
  atomicAdd(&cnt[0], l0); atomicAdd(&cnt[1], l1);
  __syncthreads();
  if (threadIdx.x == 0) {
    flg[0] = (cnt[0] < 614) ? 1 : 0;
    flg[1] = (cnt[1] < 614) ? 1 : 0;
    flg[2] = 1;
  }
}

// ---------- conv weight prep: transpose [Ch][27] -> [27][Ch] fp32, decode biases ----------
__global__ void __launch_bounds__(256) prep_kernel(
    const void* __restrict__ cvw, const void* __restrict__ cvb,
    const void* __restrict__ c1w, const void* __restrict__ c1b,
    const void* __restrict__ c2w, const void* __restrict__ c2b,
    const int* __restrict__ flg,
    float* __restrict__ wcv, float* __restrict__ bcv,
    float* __restrict__ w1, float* __restrict__ b1,
    float* __restrict__ w2, float* __restrict__ b2) {
  int pf = flg[1];
  int i = blockIdx.x * 256 + threadIdx.x;
  int r = i;
  if (r < 27 * cDI) { int j = r / cDI, d = r % cDI; wcv[r] = ldsel(cvw, (size_t)d * 27 + j, pf); return; }
  r -= 27 * cDI;
  if (r < cDI) { bcv[r] = ldsel(cvb, r, pf); return; }
  r -= cDI;
  if (r < 27 * cC) { int j = r / cC, c = r % cC; w1[r] = ldsel(c1w, (size_t)c * 27 + j, pf); return; }
  r -= 27 * cC;
  if (r < cC) { b1[r] = ldsel(c1b, r, pf); return; }
  r -= cC;
  if (r < 27 * cC) { int j = r / cC, c = r % cC; w2[r] = ldsel(c2w, (size_t)c * 27 + j, pf); return; }
  r -= 27 * cC;
  if (r < cC) { b2[r] = ldsel(c2b, r, pf); return; }
}

// ---------- CPE (depthwise 3x3x3 + residual), 2 adjacent-w voxels/thread ----------
template <int F32>
DEV void cpe_body(const void* __restrict__ xin, const float* __restrict__ wT,
                  const float* __restrict__ bs, int idx, float* __restrict__ out) {
  int c = (idx % (cC / 4)) * 4; int pv = idx / (cC / 4);   // pv in [0, cBL/2)
  int w0 = (pv & 15) << 1;
  int rest = pv >> 4;
  int h = rest & 31; int bt = rest >> 5; int t = bt & 7; int b = bt >> 3;
  float4 bias = *(const float4*)(bs + c);
  float4 acc0 = bias, acc1 = bias;
  const float4 zero = make_float4(0.f, 0.f, 0.f, 0.f);
#pragma unroll
  for (int dz = 0; dz < 3; ++dz) {
    int tt = t + dz - 1; if ((unsigned)tt >= (unsigned)cT) continue;
#pragma unroll
    for (int dy = 0; dy < 3; ++dy) {
      int hh = h + dy - 1; if ((unsigned)hh >= (unsigned)cH) continue;
      int base = (tt << 10) + (hh << 5);
      const float* wr = wT + (dz * 9 + dy * 3) * cC + c;
      float4 wv0 = *(const float4*)(wr);
      float4 wv1 = *(const float4*)(wr + cC);
      float4 wv2 = *(const float4*)(wr + 2 * cC);
      size_t rb = ((size_t)b * cL + base) * cC + c;
      float4 xm1 = (w0 > 0)  ? ld4<F32>(xin, rb + (size_t)(w0 - 1) * cC) : zero;
      float4 x0v = ld4<F32>(xin, rb + (size_t)w0 * cC);
      float4 x1v = ld4<F32>(xin, rb + (size_t)(w0 + 1) * cC);
      float4 x2v = (w0 < 30) ? ld4<F32>(xin, rb + (size_t)(w0 + 2) * cC) : zero;
      acc0.x += wv0.x*xm1.x + wv1.x*x0v.x + wv2.x*x1v.x;
      acc0.y += wv0.y*xm1.y + wv1.y*x0v.y + wv2.y*x1v.y;
      acc0.z += wv0.z*xm1.z + wv1.z*x0v.z + wv2.z*x1v.z;
      acc0.w += wv0.w*xm1.w + wv1.w*x0v.w + wv2.w*x1v.w;
      acc1.x += wv0.x*x0v.x + wv1.x*x1v.x + wv2.x*x2v.x;
      acc1.y += wv0.y*x0v.y + wv1.y*x1v.y + wv2.y*x2v.y;
      acc1.z += wv0.z*x0v.z + wv1.z*x1v.z + wv2.z*x2v.z;
      acc1.w += wv0.w*x0v.w + wv1.w*x1v.w + wv2.w*x2v.w;
    }
  }
  size_t bv0 = (size_t)b * cL + (t << 10) + (h << 5) + w0;
  float4 r0 = ld4<F32>(xin, bv0 * cC + c);
  float4 r1 = ld4<F32>(xin, (bv0 + 1) * cC + c);
  *(float4*)(out + bv0 * cC + c) =
      make_float4(r0.x + acc0.x, r0.y + acc0.y, r0.z + acc0.z, r0.w + acc0.w);
  *(float4*)(out + (bv0 + 1) * cC + c) =
      make_float4(r1.x + acc1.x, r1.y + acc1.y, r1.z + acc1.z, r1.w + acc1.w);
}

__global__ void __launch_bounds__(256) cpe_kernel(
    const void* __restrict__ xin, const float* __restrict__ wT,
    const float* __restrict__ bs, const int* __restrict__ flg, int afidx,
    float* __restrict__ out) {
  int idx = blockIdx.x * 256 + threadIdx.x;
  if (idx >= cBL * cC / 8) return;
  if (flg[afidx]) cpe_body<1>(xin, wT, bs, idx, out);
  else            cpe_body<0>(xin, wT, bs, idx, out);
}

// ---------- depthwise conv on DI + SiLU: bf16 in/out, 2 adjacent-w voxels/thread ----------
__global__ void __launch_bounds__(256) dwconv_silu_kernel(
    const unsigned short* __restrict__ xin, const float* __restrict__ wT,
    const float* __restrict__ bs, unsigned short* __restrict__ out) {
  int idx = blockIdx.x * 256 + threadIdx.x;
  if (idx >= cBL * cDI / 8) return;
  int d = (idx % (cDI / 4)) * 4; int pv = idx / (cDI / 4);
  int w0 = (pv & 15) << 1;
  int rest = pv >> 4;
  int h = rest & 31; int bt = rest >> 5; int t = bt & 7; int b = bt >> 3;
  float4 bias = *(const float4*)(bs + d);
  float4 acc0 = bias, acc1 = bias;
  const float4 zero = make_float4(0.f, 0.f, 0.f, 0.f);
#pragma unroll
  for (int dz = 0; dz < 3; ++dz) {
    int tt = t + dz - 1; if ((unsigned)tt >= (unsigned)cT) continue;
#pragma unroll
    for (int dy = 0; dy < 3; ++dy) {
      int hh = h + dy - 1; if ((unsigned)hh >= (unsigned)cH) continue;
      int base = (tt << 10) + (hh << 5);
      const float* wr = wT + (dz * 9 + dy * 3) * cDI + d;
      float4 wv0 = *(const float4*)(wr);
      float4 wv1 = *(const float4*)(wr + cDI);
      float4 wv2 = *(const float4*)(wr + 2 * cDI);
      size_t rb = ((size_t)b * cL + base) * cDI + d;
      float4 xm1 = (w0 > 0)  ? ld4<0>(xin, rb + (size_t)(w0 - 1) * cDI) : zero;
      float4 x0v = ld4<0>(xin, rb + (size_t)w0 * cDI);
      float4 x1v = ld4<0>(xin, rb + (size_t)(w0 + 1) * cDI);
      float4 x2v = (w0 < 30) ? ld4<0>(xin, rb + (size_t)(w0 + 2) * cDI) : zero;
      acc0.x += wv0.x*xm1.x + wv1.x*x0v.x + wv2.x*x1v.x;
      acc0.y += wv0.y*xm1.y + wv1.y*x0v.y + wv2.y*x1v.y;
      acc0.z += wv0.z*xm1.z + wv1.z*x0v.z + wv2.z*x1v.z;
      acc0.w += wv0.w*xm1.w + wv1.w*x0v.w + wv2.w*x1v.w;
      acc1.x += wv0.x*x0v.x + wv1.x*x1v.x + wv2.x*x2v.x;
      acc1.y += wv0.y*x0v.y + wv1.y*x1v.y + wv2.y*x2v.y;
      acc1.z += wv0.z*x0v.z + wv1.z*x1v.z + wv2.z*x2v.z;
      acc1.w += wv0.w*x0v.w + wv1.w*x1v.w + wv2.w*x2v.w;
    }
  }
  size_t bv0 = (size_t)b * cL + (t << 10) + (h << 5) + w0;
  ushort4 o0, o1;
  o0.x = (unsigned short)f2bf(siluf(acc0.x));
  o0.y = (unsigned short)f2bf(siluf(acc0.y));
  o0.z = (unsigned short)f2bf(siluf(acc0.z));
  o0.w = (unsigned short)f2bf(siluf(acc0.w));
  o1.x = (unsigned short)f2bf(siluf(acc1.x));
  o1.y = (unsigned short)f2bf(siluf(acc1.y));
  o1.z = (unsigned short)f2bf(siluf(acc1.z));
  o1.w = (unsigned short)f2bf(siluf(acc1.w));
  *(ushort4*)(out + bv0 * cDI + d) = o0;
  *(ushort4*)(out + (bv0 + 1) * cDI + d) = o1;
}

// ---------- wave-per-row LayerNorm (C=192): no LDS, no barriers, bf16 out ----------
__global__ void __launch_bounds__(256) lnb_kernel(
    const float* __restrict__ in, const void* __restrict__ g,
    const void* __restrict__ bb, const int* __restrict__ flg,
    unsigned short* __restrict__ out) {
  int pf = flg[1];
  int row = blockIdx.x * 4 + (threadIdx.x >> 6);
  int lane = threadIdx.x & 63;
  const float* x = in + (size_t)row * cC;
  float v0 = x[lane], v1 = x[lane + 64], v2 = x[lane + 128];
  float s1 = v0 + v1 + v2;
  float s2 = v0 * v0 + v1 * v1 + v2 * v2;
#pragma unroll
  for (int off = 32; off > 0; off >>= 1) {
    s1 += __shfl_xor(s1, off);
    s2 += __shfl_xor(s2, off);
  }
  float mean = s1 * (1.f / cC);
  float var = s2 * (1.f / cC) - mean * mean;
  float rstd = rsqrtf(var + 1e-6f);
  unsigned short* o = out + (size_t)row * cC;
  o[lane]       = (unsigned short)f2bf((v0 - mean) * rstd * ldsel(g, lane, pf)       + ldsel(bb, lane, pf));
  o[lane + 64]  = (unsigned short)f2bf((v1 - mean) * rstd * ldsel(g, lane + 64, pf)  + ldsel(bb, lane + 64, pf));
  o[lane + 128] = (unsigned short)f2bf((v2 - mean) * rstd * ldsel(g, lane + 128, pf) + ldsel(bb, lane + 128, pf));
}

// ---------- text conditioning ----------
__global__ void __launch_bounds__(384) text_cond_kernel(
    const void* __restrict__ text, const void* __restrict__ tw,
    const void* __restrict__ tb, const int* __restrict__ flg,
    float* __restrict__ cond) {
  int af = flg[0], pf = flg[1];
  __shared__ float mean[cC];
  int b = blockIdx.x;
  for (int c = threadIdx.x; c < cC; c += 384) {
    float s = 0.f;
    for (int t = 0; t < cLT; ++t) s += ldsel(text, ((size_t)b * cLT + t) * cC + c, af);
    mean[c] = s * (1.f / cLT);
  }
  __syncthreads();
  int di = threadIdx.x;
  float a = ldsel(tb, di, pf);
  for (int c = 0; c < cC; ++c) a += mean[c] * ldsel(tw, di * cC + c, pf);
  cond[b * cDI + di] = siluf(a);
}

// ---------- MFMA GEMM: out = epilogue(A[M,K]bf16 @ W[N,K]^T), bf16 compute ----------
// BK=64: half the barriers of BK=32 (K=192: 3 iters), 16 MFMA between barriers,
// staging in 16B chunks. K in {192,384,768} all divide 64; accumulation order
// unchanged (k ascending) -> bit-identical results.
template <int MODE>
__global__ void __launch_bounds__(256) gemm_mfma_kernel(
    const void* __restrict__ A, const void* __restrict__ W,
    int N, int K, const void* __restrict__ bias, const int* __restrict__ flg,
    const float* __restrict__ extra, float* __restrict__ out,
    unsigned short* __restrict__ out2) {
  constexpr int BM = 128, BN = 64, BK = 64, PK = 72;
  __shared__ short As[BM * PK];   // 18.4 KB
  __shared__ short Bs[BN * PK];   // 9.2 KB
  int pf = flg[1];
  int tid = threadIdx.x;
  int m0 = blockIdx.y * BM, n0 = blockIdx.x * BN;
  int lane = tid & 63, wv = tid >> 6;
  int wm = (wv >> 1) * 64, wn = (wv & 1) * 32;
  int lr = lane & 15, quad = lane >> 4;
  f32x4 acc[4][2];
#pragma unroll
  for (int mi = 0; mi < 4; ++mi)
#pragma unroll
    for (int ni = 0; ni < 2; ++ni) { acc[mi][ni][0]=0.f; acc[mi][ni][1]=0.f; acc[mi][ni][2]=0.f; acc[mi][ni][3]=0.f; }
  int ar = tid >> 1, aks = (tid & 1) * 32;   // 128 rows x 2 thr, 32 elems each
  int wr = tid >> 2, wks = (tid & 3) * 16;   // 64 rows x 4 thr, 16 elems each
  for (int k0 = 0; k0 < K; k0 += BK) {
    {
      const unsigned short* ap = (const unsigned short*)A + (size_t)(m0 + ar) * K + k0 + aks;
      short* da = &As[ar * PK + aks];
#pragma unroll
      for (int i = 0; i < 4; ++i)
        *(bf16x8*)(da + i * 8) = *(const bf16x8*)(ap + i * 8);
    }
    {
      int nr = n0 + wr;
      short* db = &Bs[wr * PK + wks];
      if (nr < N) {
        size_t wi = (size_t)nr * K + k0 + wks;
        if (pf) {
          float4 wv0 = *(const float4*)((const float*)W + wi);
          float4 wv1 = *(const float4*)((const float*)W + wi + 4);
          float4 wv2 = *(const float4*)((const float*)W + wi + 8);
          float4 wv3 = *(const float4*)((const float*)W + wi + 12);
          short4v h0, h1, h2, h3;
          h0.x = f2bf(wv0.x); h0.y = f2bf(wv0.y); h0.z = f2bf(wv0.z); h0.w = f2bf(wv0.w);
          h1.x = f2bf(wv1.x); h1.y = f2bf(wv1.y); h1.z = f2bf(wv1.z); h1.w = f2bf(wv1.w);
          h2.x = f2bf(wv2.x); h2.y = f2bf(wv2.y); h2.z = f2bf(wv2.z); h2.w = f2bf(wv2.w);
          h3.x = f2bf(wv3.x); h3.y = f2bf(wv3.y); h3.z = f2bf(wv3.z); h3.w = f2bf(wv3.w);
          *(short4v*)(db) = h0;
          *(short4v*)(db + 4) = h1;
          *(short4v*)(db + 8) = h2;
          *(short4v*)(db + 12) = h3;
        } else {
          *(bf16x8*)(db) = *(const bf16x8*)((const unsigned short*)W + wi);
          *(bf16x8*)(db + 8) = *(const bf16x8*)((const unsigned short*)W + wi + 8);
        }
      } else {
        short4v z; z.x = 0; z.y = 0; z.z = 0; z.w = 0;
        *(short4v*)(db) = z;
        *(short4v*)(db + 4) = z;
        *(short4v*)(db + 8) = z;
        *(short4v*)(db + 12) = z;
      }
    }
    __syncthreads();
    bf16x8 af[2][4], bfr[2][2];
#pragma unroll
    for (int kk = 0; kk < 2; ++kk) {
#pragma unroll
      for (int mi = 0; mi < 4; ++mi)
        af[kk][mi] = *(const bf16x8*)&As[(wm + mi * 16 + lr) * PK + kk * 32 + quad * 8];
#pragma unroll
      for (int ni = 0; ni < 2; ++ni)
        bfr[kk][ni] = *(const bf16x8*)&Bs[(wn + ni * 16 + lr) * PK + kk * 32 + quad * 8];
    }
#pragma unroll
    for (int kk = 0; kk < 2; ++kk)
#pragma unroll
      for (int mi = 0; mi < 4; ++mi)
#pragma unroll
        for (int ni = 0; ni < 2; ++ni)
          acc[mi][ni] = __builtin_amdgcn_mfma_f32_16x16x32_bf16(af[kk][mi], bfr[kk][ni], acc[mi][ni], 0, 0, 0);
    __syncthreads();
  }
#pragma unroll
  for (int mi = 0; mi < 4; ++mi) {
#pragma unroll
    for (int ni = 0; ni < 2; ++ni) {
#pragma unroll
      for (int r = 0; r < 4; ++r) {
        int m = m0 + wm + mi * 16 + quad * 4 + r;
        int n = n0 + wn + ni * 16 + lr;
        float v = acc[mi][ni][r];
        if (MODE == 0) {
          float bvv = ldsel(bias, n, pf);
          int b = m >> 13;
          if (n < cDI)
            ((unsigned short*)out)[(size_t)m * cDI + n] =
                (unsigned short)f2bf(v + bvv + extra[b * cDI + n]);
          else
            out2[(size_t)m * cDI + (n - cDI)] = (unsigned short)f2bf(v + bvv);
        } else if (MODE == 1) {
          if (n < cK * XROW) {
            int k = n / XROW, c = n - k * XROW;
            int b = m >> 13, vv = m & (cL - 1);
            int t = vv >> 10, q = vv & 1023, h = q >> 5, w = q & 31;
            int l1 = (t << 10) + (w << 5) + h;
            int lk = (k == 0) ? vv : (k == 1) ? l1 : (k == 2) ? (cL - 1 - vv) : (cL - 1 - l1);
            out[((size_t)(b * cK + k) * cL + lk) * XSTR + c] = v;
          }
        } else if (MODE == 2) {
          out[(size_t)m * cC + n] = v + extra[(size_t)m * cC + n];
        } else if (MODE == 3) {
          ((unsigned short*)out)[(size_t)m * cHID + n] =
              (unsigned short)f2bf(gelut(v + ldsel(bias, n, pf)));
        } else {
          out[(size_t)m * cC + n] = v + ldsel(bias, n, pf) + extra[(size_t)m * cC + n];
        }
      }
    }
  }
}

// voxel index for scan position l in direction k
DEV int scan_voxel(int k, int l) {
  if (k == 0) return l;
  if (k == 2) return cL - 1 - l;
  int ll = (k == 1) ? l : (cL - 1 - l);
  int t = ll >> 10, q = ll & 1023, w = q >> 5, h = q & 31;
  return (t << 10) + (h << 5) + w;
}

// ---------- register row structs (constant-indexed, SROA-friendly) ----------
struct Row11 { float4 r0, r1, r2, r3, r4, r5, r6, r7, r8, r9, r10; };
struct Row7  { float4 r0, r1, r2, r7, r8, r9, r10; };

DEV Row11 ldrow11(const float* __restrict__ rows, int st) {
  const float4* rp = (const float4*)(rows + st * XSTR);
  Row11 q;
  q.r0 = rp[0]; q.r1 = rp[1]; q.r2 = rp[2]; q.r3 = rp[3]; q.r4 = rp[4];
  q.r5 = rp[5]; q.r6 = rp[6]; q.r7 = rp[7]; q.r8 = rp[8]; q.r9 = rp[9];
  q.r10 = rp[10];
  return q;
}
DEV Row7 ldrow7(const float* __restrict__ rows, int st) {
  const float4* rp = (const float4*)(rows + st * XSTR);
  Row7 q;
  q.r0 = rp[0]; q.r1 = rp[1]; q.r2 = rp[2];
  q.r7 = rp[7]; q.r8 = rp[8]; q.r9 = rp[9]; q.r10 = rp[10];
  return q;
}

// packed dtr dot: 6 packed FMA + horizontal (was 12 scalar)
DEV float dtdot(const Row11& q, const f32x2 (&wp)[6], float dtb) {
  f32x2 acc = mk2(dtb, 0.f);
  acc += mk2(q.r0.x, q.r0.y) * wp[0];
  acc += mk2(q.r0.z, q.r0.w) * wp[1];
  acc += mk2(q.r1.x, q.r1.y) * wp[2];
  acc += mk2(q.r1.z, q.r1.w) * wp[3];
  acc += mk2(q.r2.x, q.r2.y) * wp[4];
  acc += mk2(q.r2.z, q.r2.w) * wp[5];
  return acc[0] + acc[1];
}
DEV float dtdot7(const Row7& q, const f32x2 (&wp)[6], float dtb) {
  f32x2 acc = mk2(dtb, 0.f);
  acc += mk2(q.r0.x, q.r0.y) * wp[0];
  acc += mk2(q.r0.z, q.r0.w) * wp[1];
  acc += mk2(q.r1.x, q.r1.y) * wp[2];
  acc += mk2(q.r1.z, q.r1.w) * wp[3];
  acc += mk2(q.r2.x, q.r2.y) * wp[4];
  acc += mk2(q.r2.z, q.r2.w) * wp[5];
  return acc[0] + acc[1];
}

// packed power chain: pw[i] = (a^(2i+1), a^(2i+2)); 1 scalar + 7 packed muls
DEV void powpk(float a1, f32x2 (&pw)[8]) {
  float a2 = a1 * a1;
  f32x2 sq = mk2(a2, a2);
  pw[0] = mk2(a1, a2);
  pw[1] = pw[0] * sq;
  pw[2] = pw[1] * sq;
  pw[3] = pw[2] * sq;
  pw[4] = pw[3] * sq;
  pw[5] = pw[4] * sq;
  pw[6] = pw[5] * sq;
  pw[7] = pw[6] * sq;
}

// one fast-path scan1 step, packed fp32 throughout
DEV float s1step(const Row11& q, float u,
                 const f32x2 (&wp)[6], float dtb, float ac0, float Dsd,
                 f32x2 (&h)[8], float& P1) {
  float dt = softplusf(dtdot(q, wp, dtb));
  float a1 = exp2f(dt * ac0);
  f32x2 pw[8];
  powpk(a1, pw);
  float dtu = dt * u;
  P1 *= a1;
  f32x2 dtu2 = mk2(dtu, dtu);
  f32x2 B0 = mk2(q.r3.x,q.r3.y), B1 = mk2(q.r3.z,q.r3.w);
  f32x2 B2 = mk2(q.r4.x,q.r4.y), B3 = mk2(q.r4.z,q.r4.w);
  f32x2 B4 = mk2(q.r5.x,q.r5.y), B5 = mk2(q.r5.z,q.r5.w);
  f32x2 B6 = mk2(q.r6.x,q.r6.y), B7 = mk2(q.r6.z,q.r6.w);
  f32x2 C0 = mk2(q.r7.x,q.r7.y), C1 = mk2(q.r7.z,q.r7.w);
  f32x2 C2 = mk2(q.r8.x,q.r8.y), C3 = mk2(q.r8.z,q.r8.w);
  f32x2 C4 = mk2(q.r9.x,q.r9.y), C5 = mk2(q.r9.z,q.r9.w);
  f32x2 C6 = mk2(q.r10.x,q.r10.y), C7 = mk2(q.r10.z,q.r10.w);
  f32x2 y0 = mk2(Dsd * u, 0.f), y1 = mk2(0.f,0.f), y2 = mk2(0.f,0.f), y3 = mk2(0.f,0.f);
  h[0] = h[0]*pw[0] + dtu2*B0; y0 += h[0]*C0;
  h[1] = h[1]*pw[1] + dtu2*B1; y1 += h[1]*C1;
  h[2] = h[2]*pw[2] + dtu2*B2; y2 += h[2]*C2;
  h[3] = h[3]*pw[3] + dtu2*B3; y3 += h[3]*C3;
  h[4] = h[4]*pw[4] + dtu2*B4; y0 += h[4]*C4;
  h[5] = h[5]*pw[5] + dtu2*B5; y1 += h[5]*C5;
  h[6] = h[6]*pw[6] + dtu2*B6; y2 += h[6]*C6;
  h[7] = h[7]*pw[7] + dtu2*B7; y3 += h[7]*C7;
  f32x2 t = (y0 + y1) + (y2 + y3);
  return t[0] + t[1];
}

// one fast-path scan3 step, packed fp32
DEV float s3step(const Row7& q,
                 const f32x2 (&wp)[6], float dtb, float ac0,
                 f32x2 (&g)[8]) {
  float dt = softplusf(dtdot7(q, wp, dtb));
  float a1 = exp2f(dt * ac0);
  f32x2 pw[8];
  powpk(a1, pw);
  f32x2 C0 = mk2(q.r7.x,q.r7.y), C1 = mk2(q.r7.z,q.r7.w);
  f32x2 C2 = mk2(q.r8.x,q.r8.y), C3 = mk2(q.r8.z,q.r8.w);
  f32x2 C4 = mk2(q.r9.x,q.r9.y), C5 = mk2(q.r9.z,q.r9.w);
  f32x2 C6 = mk2(q.r10.x,q.r10.y), C7 = mk2(q.r10.z,q.r10.w);
  f32x2 y0 = mk2(0.f,0.f), y1 = mk2(0.f,0.f), y2 = mk2(0.f,0.f), y3 = mk2(0.f,0.f);
  g[0] *= pw[0]; y0 += g[0]*C0;
  g[1] *= pw[1]; y1 += g[1]*C1;
  g[2] *= pw[2]; y2 += g[2]*C2;
  g[3] *= pw[3]; y3 += g[3]*C3;
  g[4] *= pw[4]; y0 += g[4]*C4;
  g[5] *= pw[5]; y1 += g[5]*C5;
  g[6] *= pw[6]; y2 += g[6]*C6;
  g[7] *= pw[7]; y3 += g[7]*C7;
  f32x2 t = (y0 + y1) + (y2 + y3);
  return t[0] + t[1];
}

// ---------- scan pass 1 (128 thr, 1 ch/thread, bf16 streams, packed fp32) ----------
__global__ void __launch_bounds__(128, 3) scan1_kernel(
    const unsigned short* __restrict__ xch, const float* __restrict__ xdbl,
    const void* __restrict__ dtw, const void* __restrict__ dtbv,
    const void* __restrict__ alog, const void* __restrict__ dsv,
    const int* __restrict__ flg,
    unsigned short* __restrict__ ys0, unsigned short* __restrict__ ys1,
    unsigned short* __restrict__ ys2, unsigned short* __restrict__ ys3,
    unsigned short* __restrict__ hend, unsigned short* __restrict__ pend) {
  __shared__ float rows[SEGLEN * XSTR];   // 64 x 48 floats = 12 KB
  int pf = flg[1];
  int tid = threadIdx.x;
  int d = blockIdx.x * 128 + tid;
  int bks = blockIdx.y;
  int s = bks & (SEG - 1); int bk = bks / SEG; int k = bk & 3; int b = bk >> 2;
  int l0 = s * SEGLEN;
  {
    const float4* src = (const float4*)(xdbl + ((size_t)bk * cL + l0) * XSTR);
    float4* dst = (float4*)rows;
#pragma unroll
    for (int i = 0; i < (SEGLEN * XSTR / 4) / 128; ++i)   // 6 iters
      dst[tid + i * 128] = src[tid + i * 128];
  }
  float wdt[cDTR];
#pragma unroll
  for (int r = 0; r < cDTR; ++r) wdt[r] = ldsel(dtw, (size_t)(k * cDI + d) * cDTR + r, pf);
  f32x2 wp[6];
#pragma unroll
  for (int r = 0; r < 6; ++r) wp[r] = mk2(wdt[2 * r], wdt[2 * r + 1]);
  float dtb = ldsel(dtbv, k * cDI + d, pf);
  float ac[cN];
#pragma unroll
  for (int n = 0; n < cN; ++n)
    ac[n] = -__expf(ldsel(alog, (size_t)(k * cDI + d) * cN + n, pf)) * 1.4426950408889634f;
  bool fast = true;
#pragma unroll
  for (int n = 1; n < cN; ++n)
    fast = fast && (fabsf(ac[n] - (float)(n + 1) * ac[0]) <= 1e-3f * fabsf(ac[n]));
  float Dsd = ldsel(dsv, k * cDI + d, pf);
  size_t so = ((size_t)bks * cDI + d) * cN;
  const unsigned short* xcb = xch + (size_t)b * cL * cDI + d;
  unsigned short* ysk = (k == 0) ? ys0 : (k == 1) ? ys1 : (k == 2) ? ys2 : ys3;
  unsigned short* ysrow = ysk + ((size_t)b * cL + l0) * cDI + d;
  __syncthreads();
  if (fast) {
    float ac0 = ac[0];
    float P1 = 1.f;
    f32x2 h2[8];
#pragma unroll
    for (int i = 0; i < 8; ++i) h2[i] = mk2(0.f, 0.f);
    Row11 qa = ldrow11(rows, 0);
    float u0 = bfu2f(xcb[(size_t)scan_voxel(k, l0) * cDI]);
    float u1 = bfu2f(xcb[(size_t)scan_voxel(k, l0 + 1) * cDI]);
    for (int st = 0; st < SEGLEN; st += 2) {
      Row11 qb = ldrow11(rows, st + 1);
      int p2 = (st + 2 < SEGLEN) ? st + 2 : SEGLEN - 1;
      int p3 = (st + 3 < SEGLEN) ? st + 3 : SEGLEN - 1;
      float nu0 = bfu2f(xcb[(size_t)scan_voxel(k, l0 + p2) * cDI]);
      float nu1 = bfu2f(xcb[(size_t)scan_voxel(k, l0 + p3) * cDI]);
      float ya = s1step(qa, u0, wp, dtb, ac0, Dsd, h2, P1);
      ysrow[(size_t)st * cDI] = (unsigned short)f2bf(ya);
      qa = ldrow11(rows, p2);
      float yb = s1step(qb, u1, wp, dtb, ac0, Dsd, h2, P1);
      ysrow[(size_t)(st + 1) * cDI] = (unsigned short)f2bf(yb);
      u0 = nu0; u1 = nu1;
    }
    float pp = P1;
#pragma unroll
    for (int i = 0; i < 8; ++i) {
      hend[so + 2*i]     = (unsigned short)f2bf(h2[i][0]);
      hend[so + 2*i + 1] = (unsigned short)f2bf(h2[i][1]);
    }
#pragma unroll
    for (int n = 0; n < cN; ++n) {
      pend[so + n] = (unsigned short)f2bf(pp);
      pp *= P1;
    }
  } else {
    float h[cN], P[cN];
#pragma unroll
    for (int n = 0; n < cN; ++n) { h[n] = 0.f; P[n] = 1.f; }
    for (int st = 0; st < SEGLEN; ++st) {
      int l = l0 + st;
      const float4* rp = (const float4*)(rows + st * XSTR);
      float4 q0 = rp[0], q1 = rp[1], q2 = rp[2];
      float s0 = dtb + q0.x*wdt[0] + q0.z*wdt[2] + q1.x*wdt[4] + q1.z*wdt[6] + q2.x*wdt[8] + q2.z*wdt[10];
      float s1 = q0.y*wdt[1] + q0.w*wdt[3] + q1.y*wdt[5] + q1.w*wdt[7] + q2.y*wdt[9] + q2.w*wdt[11];
      float dt = softplusf(s0 + s1);
      float Bv[cN], Cv[cN];
      float4 qb0 = rp[3], qb1 = rp[4], qb2 = rp[5], qb3 = rp[6];
      float4 qc0 = rp[7], qc1 = rp[8], qc2 = rp[9], qc3 = rp[10];
      Bv[0]=qb0.x; Bv[1]=qb0.y; Bv[2]=qb0.z; Bv[3]=qb0.w;
      Bv[4]=qb1.x; Bv[5]=qb1.y; Bv[6]=qb1.z; Bv[7]=qb1.w;
      Bv[8]=qb2.x; Bv[9]=qb2.y; Bv[10]=qb2.z; Bv[11]=qb2.w;
      Bv[12]=qb3.x; Bv[13]=qb3.y; Bv[14]=qb3.z; Bv[15]=qb3.w;
      Cv[0]=qc0.x; Cv[1]=qc0.y; Cv[2]=qc0.z; Cv[3]=qc0.w;
      Cv[4]=qc1.x; Cv[5]=qc1.y; Cv[6]=qc1.z; Cv[7]=qc1.w;
      Cv[8]=qc2.x; Cv[9]=qc2.y; Cv[10]=qc2.z; Cv[11]=qc2.w;
      Cv[12]=qc3.x; Cv[13]=qc3.y; Cv[14]=qc3.z; Cv[15]=qc3.w;
      int v = scan_voxel(k, l);
      float u = bfu2f(xcb[(size_t)v * cDI]);
      float dtu = dt * u;
      float y = Dsd * u;
#pragma unroll
      for (int n = 0; n < cN; ++n) {
        float a = exp2f(dt * ac[n]);
        h[n] = h[n] * a + dtu * Bv[n];
        P[n] *= a;
        y += h[n] * Cv[n];
      }
      ysrow[(size_t)st * cDI] = (unsigned short)f2bf(y);
    }
#pragma unroll
    for (int n = 0; n < cN; ++n) {
      hend[so + n] = (unsigned short)f2bf(h[n]);
      pend[so + n] = (unsigned short)f2bf(P[n]);
    }
  }
}

// ---------- scan pass 2 (serial prefix over segments; fp32 recurrence, bf16 storage) ----------
__global__ void __launch_bounds__(256) scan2_kernel(
    unsigned short* __restrict__ hend, const unsigned short* __restrict__ pend) {
  int tid = blockIdx.x * 256 + threadIdx.x;
  int bk = tid / (cDI * cN); int r = tid - bk * (cDI * cN);
  float g = 0.f;
  for (int s = 0; s < SEG; ++s) {
    size_t o = ((size_t)(bk * SEG + s) * cDI * cN) + r;
    float he = bfu2f(hend[o]), pe = bfu2f(pend[o]);
    hend[o] = (unsigned short)f2bf(g);
    g = pe * g + he;
  }
}

// ---------- scan pass 3 (owned read-add-store; packed fp32) ----------
__global__ void __launch_bounds__(128, 3) scan3_kernel(
    const float* __restrict__ xdbl,
    const void* __restrict__ dtw, const void* __restrict__ dtbv,
    const void* __restrict__ alog, const int* __restrict__ flg,
    const unsigned short* __restrict__ hin,
    unsigned short* __restrict__ ys0, unsigned short* __restrict__ ys1,
    unsigned short* __restrict__ ys2, unsigned short* __restrict__ ys3) {
  int bks = blockIdx.y;
  int s = bks & (SEG - 1);
  if (s == 0) return;
  __shared__ float rows[SEGLEN * XSTR];
  int pf = flg[1];
  int tid = threadIdx.x;
  int d = blockIdx.x * 128 + tid;
  int bk = bks / SEG; int k = bk & 3; int b = bk >> 2;
  int l0 = s * SEGLEN;
  {
    const float4* src = (const float4*)(xdbl + ((size_t)bk * cL + l0) * XSTR);
    float4* dst = (float4*)rows;
#pragma unroll
    for (int i = 0; i < (SEGLEN * XSTR / 4) / 128; ++i)
      dst[tid + i * 128] = src[tid + i * 128];
  }
  float wdt[cDTR];
#pragma unroll
  for (int r = 0; r < cDTR; ++r) wdt[r] = ldsel(dtw, (size_t)(k * cDI + d) * cDTR + r, pf);
  f32x2 wp[6];
#pragma unroll
  for (int r = 0; r < 6; ++r) wp[r] = mk2(wdt[2 * r], wdt[2 * r + 1]);
  float dtb = ldsel(dtbv, k * cDI + d, pf);
  float ac[cN];
#pragma unroll
  for (int n = 0; n < cN; ++n)
    ac[n] = -__expf(ldsel(alog, (size_t)(k * cDI + d) * cN + n, pf)) * 1.4426950408889634f;
  bool fast = true;
#pragma unroll
  for (int n = 1; n < cN; ++n)
    fast = fast && (fabsf(ac[n] - (float)(n + 1) * ac[0]) <= 1e-3f * fabsf(ac[n]));
  size_t so = ((size_t)bks * cDI + d) * cN;
  unsigned short* ysk = (k == 0) ? ys0 : (k == 1) ? ys1 : (k == 2) ? ys2 : ys3;
  unsigned short* ysrow = ysk + ((size_t)b * cL + l0) * cDI + d;
  __syncthreads();
  if (fast) {
    float ac0 = ac[0];
    f32x2 g2[8];
#pragma unroll
    for (int i = 0; i < 8; ++i)
      g2[i] = mk2(bfu2f(hin[so + 2*i]), bfu2f(hin[so + 2*i + 1]));
    Row7 qa = ldrow7(rows, 0);
    for (int st = 0; st < SEGLEN; st += 2) {
      Row7 qb = ldrow7(rows, st + 1);
      int p2 = (st + 2 < SEGLEN) ? st + 2 : SEGLEN - 1;
      float ya = s3step(qa, wp, dtb, ac0, g2);
      size_t ia = (size_t)st * cDI;
      ysrow[ia] = (unsigned short)f2bf(bfu2f(ysrow[ia]) + ya);
      qa = ldrow7(rows, p2);
      float yb = s3step(qb, wp, dtb, ac0, g2);
      size_t ib = (size_t)(st + 1) * cDI;
      ysrow[ib] = (unsigned short)f2bf(bfu2f(ysrow[ib]) + yb);
    }
  } else {
    float g[cN];
#pragma unroll
    for (int n = 0; n < cN; ++n) g[n] = bfu2f(hin[so + n]);
    for (int st = 0; st < SEGLEN; ++st) {
      const float4* rp = (const float4*)(rows + st * XSTR);
      float4 q0 = rp[0], q1 = rp[1], q2 = rp[2];
      float s0 = dtb + q0.x*wdt[0] + q0.z*wdt[2] + q1.x*wdt[4] + q1.z*wdt[6] + q2.x*wdt[8] + q2.z*wdt[10];
      float s1 = q0.y*wdt[1] + q0.w*wdt[3] + q1.y*wdt[5] + q1.w*wdt[7] + q2.y*wdt[9] + q2.w*wdt[11];
      float dt = softplusf(s0 + s1);
      float Cv[cN];
      float4 qc0 = rp[7], qc1 = rp[8], qc2 = rp[9], qc3 = rp[10];
      Cv[0]=qc0.x; Cv[1]=qc0.y; Cv[2]=qc0.z; Cv[3]=qc0.w;
      Cv[4]=qc1.x; Cv[5]=qc1.y; Cv[6]=qc1.z; Cv[7]=qc1.w;
      Cv[8]=qc2.x; Cv[9]=qc2.y; Cv[10]=qc2.z; Cv[11]=qc2.w;
      Cv[12]=qc3.x; Cv[13]=qc3.y; Cv[14]=qc3.z; Cv[15]=qc3.w;
      float y = 0.f;
#pragma unroll
      for (int n = 0; n < cN; ++n) {
        float a = exp2f(dt * ac[n]);
        g[n] *= a;
        y += g[n] * Cv[n];
      }
      size_t ii = (size_t)st * cDI;
      ysrow[ii] = (unsigned short)f2bf(bfu2f(ysrow[ii]) + y);
    }
  }
}

// ---------- merge: wave-per-row gather of 4 dirs + out_norm LN + silu(z) gate ----------
__global__ void __launch_bounds__(256) merge_kernel(
    const unsigned short* __restrict__ ys0, const unsigned short* __restrict__ ys1,
    const unsigned short* __restrict__ ys2, const unsigned short* __restrict__ ys3,
    const unsigned short* __restrict__ zh,
    const void* __restrict__ ong, const void* __restrict__ onb,
    const int* __restrict__ flg, unsigned short* __restrict__ yg) {
  int pf = flg[1];
  int bv = blockIdx.x * 4 + (threadIdx.x >> 6);
  int lane = threadIdx.x & 63;
  int v = bv & (cL - 1); int b = bv >> 13;
  int t = v >> 10, q = v & 1023, hh = q >> 5, ww = q & 31;
  int l1 = (t << 10) + (ww << 5) + hh;
  size_t r0 = ((size_t)b * cL + v) * cDI;
  size_t r1 = ((size_t)b * cL + l1) * cDI;
  size_t r2 = ((size_t)b * cL + (cL - 1 - v)) * cDI;
  size_t r3 = ((size_t)b * cL + (cL - 1 - l1)) * cDI;
  float vals[6]; float s1 = 0.f, s2 = 0.f;
#pragma unroll
  for (int i = 0; i < 6; ++i) {
    int d = lane + i * 64;
    float x = bfu2f(ys0[r0 + d]) + bfu2f(ys1[r1 + d]) +
              bfu2f(ys2[r2 + d]) + bfu2f(ys3[r3 + d]);
    vals[i] = x; s1 += x; s2 += x * x;
  }
#pragma unroll
  for (int off = 32; off > 0; off >>= 1) {
    s1 += __shfl_xor(s1, off);
    s2 += __shfl_xor(s2, off);
  }
  float mean = s1 * (1.f / cDI);
  float var = s2 * (1.f / cDI) - mean * mean;
  float rstd = rsqrtf(var + 1e-6f);
  const unsigned short* zr = zh + (size_t)bv * cDI;
  unsigned short* og = yg + (size_t)bv * cDI;
#pragma unroll
  for (int i = 0; i < 6; ++i) {
    int d = lane + i * 64;
    float xn = (vals[i] - mean) * rstd * ldsel(ong, d, pf) + ldsel(onb, d, pf);
    og[d] = (unsigned short)f2bf(xn * siluf(bfu2f(zr[d])));
  }
}

}  // namespace

extern "C" void kernel_launch(void* const* d_in, const int* in_sizes, int n_in,
                              void* d_out, int out_size, void* d_ws, size_t ws_size,
                              hipStream_t stream) {
  (void)in_sizes; (void)n_in; (void)out_size; (void)ws_size;
  const void* x    = d_in[0];
  const void* text = d_in[1];
  const void* c1w  = d_in[2];
  const void* c1b  = d_in[3];
  const void* c2w  = d_in[4];
  const void* c2b  = d_in[5];
  const void* n1g  = d_in[6];
  const void* n1b  = d_in[7];
  const void* n2g  = d_in[8];
  const void* n2b  = d_in[9];
  const void* ipw  = d_in[10];
  const void* ipb  = d_in[11];
  const void* tpw  = d_in[12];
  const void* tpb  = d_in[13];
  const void* cvw  = d_in[14];
  const void* cvb  = d_in[15];
  const void* xpw  = d_in[16];
  const void* dtw  = d_in[17];
  const void* dtb  = d_in[18];
  const void* alog = d_in[19];
  const void* dsv  = d_in[20];
  const void* ong  = d_in[21];
  const void* onb  = d_in[22];
  const void* opw  = d_in[23];
  const void* f1w  = d_in[24];
  const void* f1b  = d_in[25];
  const void* f2w  = d_in[26];
  const void* f2b  = d_in[27];

  float* Wf = (float*)d_ws;

  // ---- slot arena (~125.9 MB), atomic-free scan + bf16 activations ----
  constexpr size_t oC  = 0;                              // 6,291,456
  constexpr size_t oD  = 6291456;                        // 3,145,728
  constexpr size_t oG  = 9437184;                        // 3,145,728
  constexpr size_t oA  = 12582912;                       // 6,291,456
  constexpr size_t oB  = 18874368;                       // 6,291,456
  constexpr size_t oE  = 25165824;                       // 3,145,728
  constexpr size_t oF  = 28311552;                       // 3,145,728
  constexpr size_t oCO = 31457280;                       // 768 (cond)
  constexpr size_t oFL = 31458048;                       // 4 ints (flags)
  constexpr size_t oWCV = 31458052;                      // 27*384
  constexpr size_t oBCV = 31468420;                      // 384
  constexpr size_t oW1  = 31468804;                      // 27*192
  constexpr size_t oB1  = 31473988;                      // 192
  constexpr size_t oW2  = 31474180;                      // 5184
  constexpr size_t oB2  = 31479364;                      // 192 -> end 31479556
  unsigned short* xch = (unsigned short*)(Wf + oC);            // bf16 silu(dwconv)
  unsigned short* ysd2 = (unsigned short*)(Wf + oC + 3145728); // ystream dir 2
  unsigned short* hbufh = (unsigned short*)(Wf + oC);          // fc1 out bf16
  float* xdbl = Wf + oD;
  unsigned short* ygh  = (unsigned short*)(Wf + oD);           // yg bf16 (after xdbl dead)
  unsigned short* xnh  = (unsigned short*)(Wf + oG);           // LN1 out bf16
  unsigned short* pendp = (unsigned short*)(Wf + oG);          // bf16, after xnh dead
  unsigned short* xib  = (unsigned short*)(Wf + oA);           // in_proj x-half bf16
  unsigned short* ysd0 = (unsigned short*)(Wf + oA);           // ystream dir 0 (xib dead)
  unsigned short* ysd1 = (unsigned short*)(Wf + oA + 3145728); // ystream dir 1
  float* x2   = Wf + oA;   // out_proj output (after ystream dead)
  unsigned short* zh   = (unsigned short*)(Wf + oB);           // z bf16
  unsigned short* ysd3 = (unsigned short*)(Wf + oB + 3145728); // ystream dir 3
  float* x3   = Wf + oB;
  float* x1   = Wf + oE;
  unsigned short* hendp = (unsigned short*)(Wf + oF);          // bf16
  unsigned short* xn2h = (unsigned short*)(Wf + oF);           // LN2 out bf16 (hend dead)
  float* cond = Wf + oCO;
  int*   flg  = (int*)(Wf + oFL);
  float* wcv = Wf + oWCV; float* bcv = Wf + oBCV;
  float* w1t = Wf + oW1;  float* b1t = Wf + oB1;
  float* w2t = Wf + oW2;  float* b2t = Wf + oB2;

  const int cpeBlocks = (cBL * cC / 8) / 256;     // 1536 (2 voxels/thread)
  const int dwBlocks  = (cBL * cDI / 8) / 256;    // 3072 (2 voxels/thread)

  // 0. dtype detection + conv weight prep
  hipLaunchKernelGGL(detect_kernel, dim3(1), dim3(256), 0, stream,
                     (const unsigned short*)x, (const unsigned short*)ipw, flg);
  hipLaunchKernelGGL(prep_kernel, dim3(85), dim3(256), 0, stream,
                     cvw, cvb, c1w, c1b, c2w, c2b, flg, wcv, bcv, w1t, b1t, w2t, b2t);
  // 1. x1 = x + cpe1(x)
  hipLaunchKernelGGL(cpe_kernel, dim3(cpeBlocks), dim3(256), 0, stream,
                     x, w1t, b1t, flg, 0, x1);
  // 2. xnh = bf16(LN1(x1))  (wave-per-row, no barriers)
  hipLaunchKernelGGL(lnb_kernel, dim3(cBL / 4), dim3(256), 0, stream, x1, n1g, n1b, flg, xnh);
  // 3. cond
  hipLaunchKernelGGL(text_cond_kernel, dim3(cB), dim3(384), 0, stream, text, tpw, tpb, flg, cond);
  // 4. in_proj (MFMA BK=64): xnh -> xib bf16 (+cond), zh bf16
  hipLaunchKernelGGL((gemm_mfma_kernel<0>), dim3(2 * cDI / 64, cBL / 128), dim3(256), 0, stream,
                     xnh, ipw, 2 * cDI, cC, ipb, flg, cond, (float*)xib, zh);
  // 5. xch = bf16(silu(dwconv(xib)))
  hipLaunchKernelGGL(dwconv_silu_kernel, dim3(dwBlocks), dim3(256), 0, stream,
                     xib, wcv, bcv, xch);
  // 6. x_proj (MFMA BK=64, scatter to padded scan rows)
  hipLaunchKernelGGL((gemm_mfma_kernel<1>), dim3((cK * XROW + 63) / 64, cBL / 128), dim3(256), 0, stream,
                     xch, xpw, cK * XROW, cDI, (const void*)nullptr, flg,
                     (const float*)nullptr, xdbl, (unsigned short*)nullptr);
  // 7-9. chunked selective scan (packed fp32 inner loops)
  hipLaunchKernelGGL(scan1_kernel, dim3(cDI / 128, cB * cK * SEG), dim3(128), 0, stream,
                     xch, xdbl, dtw, dtb, alog, dsv, flg,
                     ysd0, ysd1, ysd2, ysd3, hendp, pendp);
  hipLaunchKernelGGL(scan2_kernel, dim3(cB * cK * cDI * cN / 256), dim3(256), 0, stream,
                     hendp, pendp);
  hipLaunchKernelGGL(scan3_kernel, dim3(cDI / 128, cB * cK * SEG), dim3(128), 0, stream,
                     xdbl, dtw, dtb, alog, flg, hendp, ysd0, ysd1, ysd2, ysd3);
  // 10. merge: wave-per-row gather + out_norm + gate -> yg bf16
  hipLaunchKernelGGL(merge_kernel, dim3(cBL / 4), dim3(256), 0, stream,
                     ysd0, ysd1, ysd2, ysd3, zh, ong, onb, flg, ygh);
  // 11. out_proj (MFMA BK=64) + residual(x1) -> x2 fp32
  hipLaunchKernelGGL((gemm_mfma_kernel<2>), dim3(cC / 64, cBL / 128), dim3(256), 0, stream,
                     ygh, opw, cC, cDI, (const void*)nullptr, flg, x1, x2,
                     (unsigned short*)nullptr);
  // 12. x3 = x2 + cpe2(x2)  (flg[2]=1 -> fp32 input path)
  hipLaunchKernelGGL(cpe_kernel, dim3(cpeBlocks), dim3(256), 0, stream,
                     x2, w2t, b2t, flg, 2, x3);
  // 13. xn2h = bf16(LN2(x3))
  hipLaunchKernelGGL(lnb_kernel, dim3(cBL / 4), dim3(256), 0, stream, x3, n2g, n2b, flg, xn2h);
  // 14. fc1 + gelu -> hbufh bf16 (MFMA BK=64)
  hipLaunchKernelGGL((gemm_mfma_kernel<3>), dim3(cHID / 64, cBL / 128), dim3(256), 0, stream,
                     xn2h, f1w, cHID, cC, f1b, flg, (const float*)nullptr, (float*)hbufh,
                     (unsigned short*)nullptr);
  // 15. fc2 + bias + residual(x3) -> d_out fp32 (MFMA BK=64)
  hipLaunchKernelGGL((gemm_mfma_kernel<4>), dim3(cC / 64, cBL / 128), dim3(256), 0, stream,
                     hbufh, f2w, cC, cHID, f2b, flg, x3, (float*)d_out,
                     (unsigned short*)nullptr);
}

// Round 15
// 536.014 us; speedup vs baseline: 1.1968x; 1.0091x over previous
//
#include <hip/hip_runtime.h>
#include <hip/hip_bf16.h>

#define DEV __device__ __forceinline__

namespace {

constexpr int cB = 2, cT = 8, cH = 32, cW = 32, cC = 192;
constexpr int cDI = 384, cN = 16, cK = 4, cDTR = 12, cLT = 77, cHID = 768;
constexpr int cL  = cT * cH * cW;      // 8192
constexpr int cBL = cB * cL;           // 16384
constexpr int SEG = 128, SEGLEN = cL / SEG;   // 128 segments x 64 steps
constexpr int XROW = cDTR + 2 * cN;    // 44 live cols
constexpr int XSTR = 48;               // padded row stride (float4-aligned)

typedef __attribute__((ext_vector_type(8))) short bf16x8;
typedef __attribute__((ext_vector_type(4))) float f32x4;
typedef __attribute__((ext_vector_type(2))) float f32x2;
typedef __attribute__((ext_vector_type(4))) short short4v;

// ---------- scalar helpers ----------
DEV float bfu2f(unsigned short u) { return __uint_as_float(((unsigned)u) << 16); }
DEV float ldsel(const void* p, size_t i, int f32) {
  return f32 ? ((const float*)p)[i] : bfu2f(((const unsigned short*)p)[i]);
}
template <int F32>
DEV float4 ld4(const void* p, size_t e) {   // e: element index, multiple of 4
  if (F32) return *(const float4*)((const float*)p + e);
  ushort4 u = *(const ushort4*)((const unsigned short*)p + e);
  return make_float4(bfu2f(u.x), bfu2f(u.y), bfu2f(u.z), bfu2f(u.w));
}
DEV short f2bf(float f) {   // RNE float->bf16 bits
  unsigned u = __float_as_uint(f);
  u += 0x7fffu + ((u >> 16) & 1u);
  return (short)(u >> 16);
}
DEV float siluf(float x) { return x / (1.f + __expf(-x)); }
DEV float softplusf(float x) { return (x > 20.f) ? x : __logf(1.f + __expf(x)); }
DEV float gelut(float x) {            // tanh-approx gelu (JAX default)
  float u = 0.7978845608028654f * (x + 0.044715f * x * x * x);
  float e = __expf(2.f * u);
  float th = 1.f - 2.f / (e + 1.f);
  return 0.5f * x * (1.f + th);
}
DEV f32x2 mk2(float a, float b) { f32x2 v; v[0] = a; v[1] = b; return v; }
DEV float4 cfma(float4 acc, float4 w, float4 x) {
  acc.x += w.x * x.x; acc.y += w.y * x.y;
  acc.z += w.z * x.z; acc.w += w.w * x.w;
  return acc;
}

// ---------- dtype detector (validated: inputs are fp32) ----------
__global__ void __launch_bounds__(256) detect_kernel(
    const unsigned short* __restrict__ xa, const unsigned short* __restrict__ wp,
    int* __restrict__ flg) {
  __shared__ int cnt[2];
  if (threadIdx.x < 2) cnt[threadIdx.x] = 0;
  __syncthreads();
  int l0 = 0, l1 = 0;
  for (int i = threadIdx.x; i < 1024; i += 256) {
    float v = bfu2f(xa[2 * i]); float a = fabsf(v);
    if (v == 0.f || (a > 1e-8f && a < 1e4f)) l0++;
    float u = bfu2f(wp[2 * i]); float bq = fabsf(u);
    if (u == 0.f || (bq > 1e-8f && bq < 1e4f)) l1++;
  }
  atomicAdd(&cnt[0], l0); atomicAdd(&cnt[1], l1);
  __syncthreads();
  if (threadIdx.x == 0) {
    flg[0] = (cnt[0] < 614) ? 1 : 0;
    flg[1] = (cnt[1] < 614) ? 1 : 0;
    flg[2] = 1;
  }
}

// ---------- conv weight prep: transpose [Ch][27] -> [27][Ch] fp32, decode biases ----------
__global__ void __launch_bounds__(256) prep_kernel(
    const void* __restrict__ cvw, const void* __restrict__ cvb,
    const void* __restrict__ c1w, const void* __restrict__ c1b,
    const void* __restrict__ c2w, const void* __restrict__ c2b,
    const int* __restrict__ flg,
    float* __restrict__ wcv, float* __restrict__ bcv,
    float* __restrict__ w1, float* __restrict__ b1,
    float* __restrict__ w2, float* __restrict__ b2) {
  int pf = flg[1];
  int i = blockIdx.x * 256 + threadIdx.x;
  int r = i;
  if (r < 27 * cDI) { int j = r / cDI, d = r % cDI; wcv[r] = ldsel(cvw, (size_t)d * 27 + j, pf); return; }
  r -= 27 * cDI;
  if (r < cDI) { bcv[r] = ldsel(cvb, r, pf); return; }
  r -= cDI;
  if (r < 27 * cC) { int j = r / cC, c = r % cC; w1[r] = ldsel(c1w, (size_t)c * 27 + j, pf); return; }
  r -= 27 * cC;
  if (r < cC) { b1[r] = ldsel(c1b, r, pf); return; }
  r -= cC;
  if (r < 27 * cC) { int j = r / cC, c = r % cC; w2[r] = ldsel(c2w, (size_t)c * 27 + j, pf); return; }
  r -= 27 * cC;
  if (r < cC) { b2[r] = ldsel(c2b, r, pf); return; }
}

// ---------- CPE (depthwise 3x3x3 + residual), 2x2 (h x w) voxels/thread ----------
// Per dz the 4 input rows {h0-1..h0+2} x 4 w-cols serve all four outputs:
// input loads per dz drop 24 -> 16 (-33%). dy/dx order per output preserved.
template <int F32>
DEV void cpe_body(const void* __restrict__ xin, const float* __restrict__ wT,
                  const float* __restrict__ bs, int idx, float* __restrict__ out) {
  int c = (idx % (cC / 4)) * 4;
  int rest = idx / (cC / 4);
  int w0 = (rest & 15) << 1; rest >>= 4;
  int h0 = (rest & 15) << 1; rest >>= 4;
  int t = rest & 7; int b = rest >> 3;
  float4 bias = *(const float4*)(bs + c);
  float4 a00 = bias, a01 = bias, a10 = bias, a11 = bias;   // [oh][ow]
  const float4 zero = make_float4(0.f, 0.f, 0.f, 0.f);
#pragma unroll
  for (int dz = 0; dz < 3; ++dz) {
    int tt = t + dz - 1; if ((unsigned)tt >= (unsigned)cT) continue;
#pragma unroll
    for (int rr = 0; rr < 4; ++rr) {   // input rows h0-1 .. h0+2
      int hh = h0 + rr - 1;
      if ((unsigned)hh >= (unsigned)cH) continue;
      size_t rb = ((size_t)b * cL + (tt << 10) + (hh << 5)) * cC + c;
      float4 xm1 = (w0 > 0)  ? ld4<F32>(xin, rb + (size_t)(w0 - 1) * cC) : zero;
      float4 x0v = ld4<F32>(xin, rb + (size_t)w0 * cC);
      float4 x1v = ld4<F32>(xin, rb + (size_t)(w0 + 1) * cC);
      float4 x2v = (w0 < 30) ? ld4<F32>(xin, rb + (size_t)(w0 + 2) * cC) : zero;
      if (rr < 3) {                      // output h0, dy = rr
        const float* wr = wT + (dz * 9 + rr * 3) * cC + c;
        float4 wv0 = *(const float4*)(wr);
        float4 wv1 = *(const float4*)(wr + cC);
        float4 wv2 = *(const float4*)(wr + 2 * cC);
        a00 = cfma(cfma(cfma(a00, wv0, xm1), wv1, x0v), wv2, x1v);
        a01 = cfma(cfma(cfma(a01, wv0, x0v), wv1, x1v), wv2, x2v);
      }
      if (rr >= 1) {                     // output h0+1, dy = rr-1
        const float* wr = wT + (dz * 9 + (rr - 1) * 3) * cC + c;
        float4 wv0 = *(const float4*)(wr);
        float4 wv1 = *(const float4*)(wr + cC);
        float4 wv2 = *(const float4*)(wr + 2 * cC);
        a10 = cfma(cfma(cfma(a10, wv0, xm1), wv1, x0v), wv2, x1v);
        a11 = cfma(cfma(cfma(a11, wv0, x0v), wv1, x1v), wv2, x2v);
      }
    }
  }
  size_t v00 = (size_t)b * cL + (t << 10) + (h0 << 5) + w0;
#pragma unroll
  for (int oh = 0; oh < 2; ++oh) {
#pragma unroll
    for (int ow = 0; ow < 2; ++ow) {
      size_t bv = v00 + (size_t)(oh << 5) + ow;
      float4 acc = (oh == 0) ? (ow == 0 ? a00 : a01) : (ow == 0 ? a10 : a11);
      float4 r0 = ld4<F32>(xin, bv * cC + c);
      *(float4*)(out + bv * cC + c) =
          make_float4(r0.x + acc.x, r0.y + acc.y, r0.z + acc.z, r0.w + acc.w);
    }
  }
}

__global__ void __launch_bounds__(256) cpe_kernel(
    const void* __restrict__ xin, const float* __restrict__ wT,
    const float* __restrict__ bs, const int* __restrict__ flg, int afidx,
    float* __restrict__ out) {
  int idx = blockIdx.x * 256 + threadIdx.x;
  if (idx >= cBL * cC / 16) return;
  if (flg[afidx]) cpe_body<1>(xin, wT, bs, idx, out);
  else            cpe_body<0>(xin, wT, bs, idx, out);
}

// ---------- depthwise conv on DI + SiLU: bf16 in/out, 2x2 voxels/thread ----------
__global__ void __launch_bounds__(256) dwconv_silu_kernel(
    const unsigned short* __restrict__ xin, const float* __restrict__ wT,
    const float* __restrict__ bs, unsigned short* __restrict__ out) {
  int idx = blockIdx.x * 256 + threadIdx.x;
  if (idx >= cBL * cDI / 16) return;
  int d = (idx % (cDI / 4)) * 4;
  int rest = idx / (cDI / 4);
  int w0 = (rest & 15) << 1; rest >>= 4;
  int h0 = (rest & 15) << 1; rest >>= 4;
  int t = rest & 7; int b = rest >> 3;
  float4 bias = *(const float4*)(bs + d);
  float4 a00 = bias, a01 = bias, a10 = bias, a11 = bias;
  const float4 zero = make_float4(0.f, 0.f, 0.f, 0.f);
#pragma unroll
  for (int dz = 0; dz < 3; ++dz) {
    int tt = t + dz - 1; if ((unsigned)tt >= (unsigned)cT) continue;
#pragma unroll
    for (int rr = 0; rr < 4; ++rr) {
      int hh = h0 + rr - 1;
      if ((unsigned)hh >= (unsigned)cH) continue;
      size_t rb = ((size_t)b * cL + (tt << 10) + (hh << 5)) * cDI + d;
      float4 xm1 = (w0 > 0)  ? ld4<0>(xin, rb + (size_t)(w0 - 1) * cDI) : zero;
      float4 x0v = ld4<0>(xin, rb + (size_t)w0 * cDI);
      float4 x1v = ld4<0>(xin, rb + (size_t)(w0 + 1) * cDI);
      float4 x2v = (w0 < 30) ? ld4<0>(xin, rb + (size_t)(w0 + 2) * cDI) : zero;
      if (rr < 3) {
        const float* wr = wT + (dz * 9 + rr * 3) * cDI + d;
        float4 wv0 = *(const float4*)(wr);
        float4 wv1 = *(const float4*)(wr + cDI);
        float4 wv2 = *(const float4*)(wr + 2 * cDI);
        a00 = cfma(cfma(cfma(a00, wv0, xm1), wv1, x0v), wv2, x1v);
        a01 = cfma(cfma(cfma(a01, wv0, x0v), wv1, x1v), wv2, x2v);
      }
      if (rr >= 1) {
        const float* wr = wT + (dz * 9 + (rr - 1) * 3) * cDI + d;
        float4 wv0 = *(const float4*)(wr);
        float4 wv1 = *(const float4*)(wr + cDI);
        float4 wv2 = *(const float4*)(wr + 2 * cDI);
        a10 = cfma(cfma(cfma(a10, wv0, xm1), wv1, x0v), wv2, x1v);
        a11 = cfma(cfma(cfma(a11, wv0, x0v), wv1, x1v), wv2, x2v);
      }
    }
  }
  size_t v00 = (size_t)b * cL + (t << 10) + (h0 << 5) + w0;
#pragma unroll
  for (int oh = 0; oh < 2; ++oh) {
#pragma unroll
    for (int ow = 0; ow < 2; ++ow) {
      size_t bv = v00 + (size_t)(oh << 5) + ow;
      float4 acc = (oh == 0) ? (ow == 0 ? a00 : a01) : (ow == 0 ? a10 : a11);
      ushort4 o;
      o.x = (unsigned short)f2bf(siluf(acc.x));
      o.y = (unsigned short)f2bf(siluf(acc.y));
      o.z = (unsigned short)f2bf(siluf(acc.z));
      o.w = (unsigned short)f2bf(siluf(acc.w));
      *(ushort4*)(out + bv * cDI + d) = o;
    }
  }
}

// ---------- wave-per-row LayerNorm (C=192): no LDS, no barriers, bf16 out ----------
__global__ void __launch_bounds__(256) lnb_kernel(
    const float* __restrict__ in, const void* __restrict__ g,
    const void* __restrict__ bb, const int* __restrict__ flg,
    unsigned short* __restrict__ out) {
  int pf = flg[1];
  int row = blockIdx.x * 4 + (threadIdx.x >> 6);
  int lane = threadIdx.x & 63;
  const float* x = in + (size_t)row * cC;
  float v0 = x[lane], v1 = x[lane + 64], v2 = x[lane + 128];
  float s1 = v0 + v1 + v2;
  float s2 = v0 * v0 + v1 * v1 + v2 * v2;
#pragma unroll
  for (int off = 32; off > 0; off >>= 1) {
    s1 += __shfl_xor(s1, off);
    s2 += __shfl_xor(s2, off);
  }
  float mean = s1 * (1.f / cC);
  float var = s2 * (1.f / cC) - mean * mean;
  float rstd = rsqrtf(var + 1e-6f);
  unsigned short* o = out + (size_t)row * cC;
  o[lane]       = (unsigned short)f2bf((v0 - mean) * rstd * ldsel(g, lane, pf)       + ldsel(bb, lane, pf));
  o[lane + 64]  = (unsigned short)f2bf((v1 - mean) * rstd * ldsel(g, lane + 64, pf)  + ldsel(bb, lane + 64, pf));
  o[lane + 128] = (unsigned short)f2bf((v2 - mean) * rstd * ldsel(g, lane + 128, pf) + ldsel(bb, lane + 128, pf));
}

// ---------- text conditioning ----------
__global__ void __launch_bounds__(384) text_cond_kernel(
    const void* __restrict__ text, const void* __restrict__ tw,
    const void* __restrict__ tb, const int* __restrict__ flg,
    float* __restrict__ cond) {
  int af = flg[0], pf = flg[1];
  __shared__ float mean[cC];
  int b = blockIdx.x;
  for (int c = threadIdx.x; c < cC; c += 384) {
    float s = 0.f;
    for (int t = 0; t < cLT; ++t) s += ldsel(text, ((size_t)b * cLT + t) * cC + c, af);
    mean[c] = s * (1.f / cLT);
  }
  __syncthreads();
  int di = threadIdx.x;
  float a = ldsel(tb, di, pf);
  for (int c = 0; c < cC; ++c) a += mean[c] * ldsel(tw, di * cC + c, pf);
  cond[b * cDI + di] = siluf(a);
}

// ---------- MFMA GEMM: out = epilogue(A[M,K]bf16 @ W[N,K]^T), bf16 compute ----------
// BK=64, BN templated (64 or 128). BN=128 for N=768 GEMMs halves A-panel
// refetch count (12 -> 6 n-blocks). K-order unchanged -> bit-identical.
template <int MODE, int BN>
__global__ void __launch_bounds__(256) gemm_mfma_kernel(
    const void* __restrict__ A, const void* __restrict__ W,
    int N, int K, const void* __restrict__ bias, const int* __restrict__ flg,
    const float* __restrict__ extra, float* __restrict__ out,
    unsigned short* __restrict__ out2) {
  constexpr int BM = 128, BK = 64, PK = 72;
  constexpr int NI = BN / 32;           // n-fragments per wave
  __shared__ short As[BM * PK];
  __shared__ short Bs[BN * PK];
  int pf = flg[1];
  int tid = threadIdx.x;
  int m0 = blockIdx.y * BM, n0 = blockIdx.x * BN;
  int lane = tid & 63, wv = tid >> 6;
  int wm = (wv >> 1) * 64, wn = (wv & 1) * (BN / 2);
  int lr = lane & 15, quad = lane >> 4;
  f32x4 acc[4][NI];
#pragma unroll
  for (int mi = 0; mi < 4; ++mi)
#pragma unroll
    for (int ni = 0; ni < NI; ++ni) { acc[mi][ni][0]=0.f; acc[mi][ni][1]=0.f; acc[mi][ni][2]=0.f; acc[mi][ni][3]=0.f; }
  int ar = tid >> 1, aks = (tid & 1) * 32;   // 128 rows x 2 thr, 32 elems each
  int wr, wks;
  if (BN == 64) { wr = tid >> 2; wks = (tid & 3) * 16; }
  else          { wr = tid >> 1; wks = (tid & 1) * 32; }
  constexpr int BEL = (BN == 64) ? 16 : 32;  // B elems per thread
  for (int k0 = 0; k0 < K; k0 += BK) {
    {
      const unsigned short* ap = (const unsigned short*)A + (size_t)(m0 + ar) * K + k0 + aks;
      short* da = &As[ar * PK + aks];
#pragma unroll
      for (int i = 0; i < 4; ++i)
        *(bf16x8*)(da + i * 8) = *(const bf16x8*)(ap + i * 8);
    }
    {
      int nr = n0 + wr;
      short* db = &Bs[wr * PK + wks];
      if (nr < N) {
        size_t wi = (size_t)nr * K + k0 + wks;
        if (pf) {
#pragma unroll
          for (int i = 0; i < BEL / 4; ++i) {
            float4 wvv = *(const float4*)((const float*)W + wi + i * 4);
            short4v h;
            h.x = f2bf(wvv.x); h.y = f2bf(wvv.y); h.z = f2bf(wvv.z); h.w = f2bf(wvv.w);
            *(short4v*)(db + i * 4) = h;
          }
        } else {
#pragma unroll
          for (int i = 0; i < BEL / 8; ++i)
            *(bf16x8*)(db + i * 8) = *(const bf16x8*)((const unsigned short*)W + wi + i * 8);
        }
      } else {
        short4v z; z.x = 0; z.y = 0; z.z = 0; z.w = 0;
#pragma unroll
        for (int i = 0; i < BEL / 4; ++i)
          *(short4v*)(db + i * 4) = z;
      }
    }
    __syncthreads();
    bf16x8 af[2][4], bfr[2][NI];
#pragma unroll
    for (int kk = 0; kk < 2; ++kk) {
#pragma unroll
      for (int mi = 0; mi < 4; ++mi)
        af[kk][mi] = *(const bf16x8*)&As[(wm + mi * 16 + lr) * PK + kk * 32 + quad * 8];
#pragma unroll
      for (int ni = 0; ni < NI; ++ni)
        bfr[kk][ni] = *(const bf16x8*)&Bs[(wn + ni * 16 + lr) * PK + kk * 32 + quad * 8];
    }
#pragma unroll
    for (int kk = 0; kk < 2; ++kk)
#pragma unroll
      for (int mi = 0; mi < 4; ++mi)
#pragma unroll
        for (int ni = 0; ni < NI; ++ni)
          acc[mi][ni] = __builtin_amdgcn_mfma_f32_16x16x32_bf16(af[kk][mi], bfr[kk][ni], acc[mi][ni], 0, 0, 0);
    __syncthreads();
  }
#pragma unroll
  for (int mi = 0; mi < 4; ++mi) {
#pragma unroll
    for (int ni = 0; ni < NI; ++ni) {
#pragma unroll
      for (int r = 0; r < 4; ++r) {
        int m = m0 + wm + mi * 16 + quad * 4 + r;
        int n = n0 + wn + ni * 16 + lr;
        float v = acc[mi][ni][r];
        if (MODE == 0) {
          float bvv = ldsel(bias, n, pf);
          int b = m >> 13;
          if (n < cDI)
            ((unsigned short*)out)[(size_t)m * cDI + n] =
                (unsigned short)f2bf(v + bvv + extra[b * cDI + n]);
          else
            out2[(size_t)m * cDI + (n - cDI)] = (unsigned short)f2bf(v + bvv);
        } else if (MODE == 1) {
          if (n < cK * XROW) {
            int k = n / XROW, c = n - k * XROW;
            int b = m >> 13, vv = m & (cL - 1);
            int t = vv >> 10, q = vv & 1023, h = q >> 5, w = q & 31;
            int l1 = (t << 10) + (w << 5) + h;
            int lk = (k == 0) ? vv : (k == 1) ? l1 : (k == 2) ? (cL - 1 - vv) : (cL - 1 - l1);
            out[((size_t)(b * cK + k) * cL + lk) * XSTR + c] = v;
          }
        } else if (MODE == 2) {
          out[(size_t)m * cC + n] = v + extra[(size_t)m * cC + n];
        } else if (MODE == 3) {
          ((unsigned short*)out)[(size_t)m * cHID + n] =
              (unsigned short)f2bf(gelut(v + ldsel(bias, n, pf)));
        } else {
          out[(size_t)m * cC + n] = v + ldsel(bias, n, pf) + extra[(size_t)m * cC + n];
        }
      }
    }
  }
}

// voxel index for scan position l in direction k
DEV int scan_voxel(int k, int l) {
  if (k == 0) return l;
  if (k == 2) return cL - 1 - l;
  int ll = (k == 1) ? l : (cL - 1 - l);
  int t = ll >> 10, q = ll & 1023, w = q >> 5, h = q & 31;
  return (t << 10) + (h << 5) + w;
}

// ---------- register row structs (constant-indexed, SROA-friendly) ----------
struct Row11 { float4 r0, r1, r2, r3, r4, r5, r6, r7, r8, r9, r10; };
struct Row7  { float4 r0, r1, r2, r7, r8, r9, r10; };

DEV Row11 ldrow11(const float* __restrict__ rows, int st) {
  const float4* rp = (const float4*)(rows + st * XSTR);
  Row11 q;
  q.r0 = rp[0]; q.r1 = rp[1]; q.r2 = rp[2]; q.r3 = rp[3]; q.r4 = rp[4];
  q.r5 = rp[5]; q.r6 = rp[6]; q.r7 = rp[7]; q.r8 = rp[8]; q.r9 = rp[9];
  q.r10 = rp[10];
  return q;
}
DEV Row7 ldrow7(const float* __restrict__ rows, int st) {
  const float4* rp = (const float4*)(rows + st * XSTR);
  Row7 q;
  q.r0 = rp[0]; q.r1 = rp[1]; q.r2 = rp[2];
  q.r7 = rp[7]; q.r8 = rp[8]; q.r9 = rp[9]; q.r10 = rp[10];
  return q;
}

// packed dtr dot: 6 packed FMA + horizontal (was 12 scalar)
DEV float dtdot(const Row11& q, const f32x2 (&wp)[6], float dtb) {
  f32x2 acc = mk2(dtb, 0.f);
  acc += mk2(q.r0.x, q.r0.y) * wp[0];
  acc += mk2(q.r0.z, q.r0.w) * wp[1];
  acc += mk2(q.r1.x, q.r1.y) * wp[2];
  acc += mk2(q.r1.z, q.r1.w) * wp[3];
  acc += mk2(q.r2.x, q.r2.y) * wp[4];
  acc += mk2(q.r2.z, q.r2.w) * wp[5];
  return acc[0] + acc[1];
}
DEV float dtdot7(const Row7& q, const f32x2 (&wp)[6], float dtb) {
  f32x2 acc = mk2(dtb, 0.f);
  acc += mk2(q.r0.x, q.r0.y) * wp[0];
  acc += mk2(q.r0.z, q.r0.w) * wp[1];
  acc += mk2(q.r1.x, q.r1.y) * wp[2];
  acc += mk2(q.r1.z, q.r1.w) * wp[3];
  acc += mk2(q.r2.x, q.r2.y) * wp[4];
  acc += mk2(q.r2.z, q.r2.w) * wp[5];
  return acc[0] + acc[1];
}

// packed power chain: pw[i] = (a^(2i+1), a^(2i+2)); 1 scalar + 7 packed muls
DEV void powpk(float a1, f32x2 (&pw)[8]) {
  float a2 = a1 * a1;
  f32x2 sq = mk2(a2, a2);
  pw[0] = mk2(a1, a2);
  pw[1] = pw[0] * sq;
  pw[2] = pw[1] * sq;
  pw[3] = pw[2] * sq;
  pw[4] = pw[3] * sq;
  pw[5] = pw[4] * sq;
  pw[6] = pw[5] * sq;
  pw[7] = pw[6] * sq;
}

// one fast-path scan1 step, packed fp32 throughout
DEV float s1step(const Row11& q, float u,
                 const f32x2 (&wp)[6], float dtb, float ac0, float Dsd,
                 f32x2 (&h)[8], float& P1) {
  float dt = softplusf(dtdot(q, wp, dtb));
  float a1 = exp2f(dt * ac0);
  f32x2 pw[8];
  powpk(a1, pw);
  float dtu = dt * u;
  P1 *= a1;
  f32x2 dtu2 = mk2(dtu, dtu);
  f32x2 B0 = mk2(q.r3.x,q.r3.y), B1 = mk2(q.r3.z,q.r3.w);
  f32x2 B2 = mk2(q.r4.x,q.r4.y), B3 = mk2(q.r4.z,q.r4.w);
  f32x2 B4 = mk2(q.r5.x,q.r5.y), B5 = mk2(q.r5.z,q.r5.w);
  f32x2 B6 = mk2(q.r6.x,q.r6.y), B7 = mk2(q.r6.z,q.r6.w);
  f32x2 C0 = mk2(q.r7.x,q.r7.y), C1 = mk2(q.r7.z,q.r7.w);
  f32x2 C2 = mk2(q.r8.x,q.r8.y), C3 = mk2(q.r8.z,q.r8.w);
  f32x2 C4 = mk2(q.r9.x,q.r9.y), C5 = mk2(q.r9.z,q.r9.w);
  f32x2 C6 = mk2(q.r10.x,q.r10.y), C7 = mk2(q.r10.z,q.r10.w);
  f32x2 y0 = mk2(Dsd * u, 0.f), y1 = mk2(0.f,0.f), y2 = mk2(0.f,0.f), y3 = mk2(0.f,0.f);
  h[0] = h[0]*pw[0] + dtu2*B0; y0 += h[0]*C0;
  h[1] = h[1]*pw[1] + dtu2*B1; y1 += h[1]*C1;
  h[2] = h[2]*pw[2] + dtu2*B2; y2 += h[2]*C2;
  h[3] = h[3]*pw[3] + dtu2*B3; y3 += h[3]*C3;
  h[4] = h[4]*pw[4] + dtu2*B4; y0 += h[4]*C4;
  h[5] = h[5]*pw[5] + dtu2*B5; y1 += h[5]*C5;
  h[6] = h[6]*pw[6] + dtu2*B6; y2 += h[6]*C6;
  h[7] = h[7]*pw[7] + dtu2*B7; y3 += h[7]*C7;
  f32x2 t = (y0 + y1) + (y2 + y3);
  return t[0] + t[1];
}

// one fast-path scan3 step, packed fp32
DEV float s3step(const Row7& q,
                 const f32x2 (&wp)[6], float dtb, float ac0,
                 f32x2 (&g)[8]) {
  float dt = softplusf(dtdot7(q, wp, dtb));
  float a1 = exp2f(dt * ac0);
  f32x2 pw[8];
  powpk(a1, pw);
  f32x2 C0 = mk2(q.r7.x,q.r7.y), C1 = mk2(q.r7.z,q.r7.w);
  f32x2 C2 = mk2(q.r8.x,q.r8.y), C3 = mk2(q.r8.z,q.r8.w);
  f32x2 C4 = mk2(q.r9.x,q.r9.y), C5 = mk2(q.r9.z,q.r9.w);
  f32x2 C6 = mk2(q.r10.x,q.r10.y), C7 = mk2(q.r10.z,q.r10.w);
  f32x2 y0 = mk2(0.f,0.f), y1 = mk2(0.f,0.f), y2 = mk2(0.f,0.f), y3 = mk2(0.f,0.f);
  g[0] *= pw[0]; y0 += g[0]*C0;
  g[1] *= pw[1]; y1 += g[1]*C1;
  g[2] *= pw[2]; y2 += g[2]*C2;
  g[3] *= pw[3]; y3 += g[3]*C3;
  g[4] *= pw[4]; y0 += g[4]*C4;
  g[5] *= pw[5]; y1 += g[5]*C5;
  g[6] *= pw[6]; y2 += g[6]*C6;
  g[7] *= pw[7]; y3 += g[7]*C7;
  f32x2 t = (y0 + y1) + (y2 + y3);
  return t[0] + t[1];
}

// ---------- scan pass 1 (128 thr, 1 ch/thread, bf16 streams, packed fp32) ----------
__global__ void __launch_bounds__(128, 3) scan1_kernel(
    const unsigned short* __restrict__ xch, const float* __restrict__ xdbl,
    const void* __restrict__ dtw, const void* __restrict__ dtbv,
    const void* __restrict__ alog, const void* __restrict__ dsv,
    const int* __restrict__ flg,
    unsigned short* __restrict__ ys0, unsigned short* __restrict__ ys1,
    unsigned short* __restrict__ ys2, unsigned short* __restrict__ ys3,
    unsigned short* __restrict__ hend, unsigned short* __restrict__ pend) {
  __shared__ float rows[SEGLEN * XSTR];   // 64 x 48 floats = 12 KB
  int pf = flg[1];
  int tid = threadIdx.x;
  int d = blockIdx.x * 128 + tid;
  int bks = blockIdx.y;
  int s = bks & (SEG - 1); int bk = bks / SEG; int k = bk & 3; int b = bk >> 2;
  int l0 = s * SEGLEN;
  {
    const float4* src = (const float4*)(xdbl + ((size_t)bk * cL + l0) * XSTR);
    float4* dst = (float4*)rows;
#pragma unroll
    for (int i = 0; i < (SEGLEN * XSTR / 4) / 128; ++i)   // 6 iters
      dst[tid + i * 128] = src[tid + i * 128];
  }
  float wdt[cDTR];
#pragma unroll
  for (int r = 0; r < cDTR; ++r) wdt[r] = ldsel(dtw, (size_t)(k * cDI + d) * cDTR + r, pf);
  f32x2 wp[6];
#pragma unroll
  for (int r = 0; r < 6; ++r) wp[r] = mk2(wdt[2 * r], wdt[2 * r + 1]);
  float dtb = ldsel(dtbv, k * cDI + d, pf);
  float ac[cN];
#pragma unroll
  for (int n = 0; n < cN; ++n)
    ac[n] = -__expf(ldsel(alog, (size_t)(k * cDI + d) * cN + n, pf)) * 1.4426950408889634f;
  bool fast = true;
#pragma unroll
  for (int n = 1; n < cN; ++n)
    fast = fast && (fabsf(ac[n] - (float)(n + 1) * ac[0]) <= 1e-3f * fabsf(ac[n]));
  float Dsd = ldsel(dsv, k * cDI + d, pf);
  size_t so = ((size_t)bks * cDI + d) * cN;
  const unsigned short* xcb = xch + (size_t)b * cL * cDI + d;
  unsigned short* ysk = (k == 0) ? ys0 : (k == 1) ? ys1 : (k == 2) ? ys2 : ys3;
  unsigned short* ysrow = ysk + ((size_t)b * cL + l0) * cDI + d;
  __syncthreads();
  if (fast) {
    float ac0 = ac[0];
    float P1 = 1.f;
    f32x2 h2[8];
#pragma unroll
    for (int i = 0; i < 8; ++i) h2[i] = mk2(0.f, 0.f);
    Row11 qa = ldrow11(rows, 0);
    float u0 = bfu2f(xcb[(size_t)scan_voxel(k, l0) * cDI]);
    float u1 = bfu2f(xcb[(size_t)scan_voxel(k, l0 + 1) * cDI]);
    for (int st = 0; st < SEGLEN; st += 2) {
      Row11 qb = ldrow11(rows, st + 1);
      int p2 = (st + 2 < SEGLEN) ? st + 2 : SEGLEN - 1;
      int p3 = (st + 3 < SEGLEN) ? st + 3 : SEGLEN - 1;
      float nu0 = bfu2f(xcb[(size_t)scan_voxel(k, l0 + p2) * cDI]);
      float nu1 = bfu2f(xcb[(size_t)scan_voxel(k, l0 + p3) * cDI]);
      float ya = s1step(qa, u0, wp, dtb, ac0, Dsd, h2, P1);
      ysrow[(size_t)st * cDI] = (unsigned short)f2bf(ya);
      qa = ldrow11(rows, p2);
      float yb = s1step(qb, u1, wp, dtb, ac0, Dsd, h2, P1);
      ysrow[(size_t)(st + 1) * cDI] = (unsigned short)f2bf(yb);
      u0 = nu0; u1 = nu1;
    }
    float pp = P1;
#pragma unroll
    for (int i = 0; i < 8; ++i) {
      hend[so + 2*i]     = (unsigned short)f2bf(h2[i][0]);
      hend[so + 2*i + 1] = (unsigned short)f2bf(h2[i][1]);
    }
#pragma unroll
    for (int n = 0; n < cN; ++n) {
      pend[so + n] = (unsigned short)f2bf(pp);
      pp *= P1;
    }
  } else {
    float h[cN], P[cN];
#pragma unroll
    for (int n = 0; n < cN; ++n) { h[n] = 0.f; P[n] = 1.f; }
    for (int st = 0; st < SEGLEN; ++st) {
      int l = l0 + st;
      const float4* rp = (const float4*)(rows + st * XSTR);
      float4 q0 = rp[0], q1 = rp[1], q2 = rp[2];
      float s0 = dtb + q0.x*wdt[0] + q0.z*wdt[2] + q1.x*wdt[4] + q1.z*wdt[6] + q2.x*wdt[8] + q2.z*wdt[10];
      float s1 = q0.y*wdt[1] + q0.w*wdt[3] + q1.y*wdt[5] + q1.w*wdt[7] + q2.y*wdt[9] + q2.w*wdt[11];
      float dt = softplusf(s0 + s1);
      float Bv[cN], Cv[cN];
      float4 qb0 = rp[3], qb1 = rp[4], qb2 = rp[5], qb3 = rp[6];
      float4 qc0 = rp[7], qc1 = rp[8], qc2 = rp[9], qc3 = rp[10];
      Bv[0]=qb0.x; Bv[1]=qb0.y; Bv[2]=qb0.z; Bv[3]=qb0.w;
      Bv[4]=qb1.x; Bv[5]=qb1.y; Bv[6]=qb1.z; Bv[7]=qb1.w;
      Bv[8]=qb2.x; Bv[9]=qb2.y; Bv[10]=qb2.z; Bv[11]=qb2.w;
      Bv[12]=qb3.x; Bv[13]=qb3.y; Bv[14]=qb3.z; Bv[15]=qb3.w;
      Cv[0]=qc0.x; Cv[1]=qc0.y; Cv[2]=qc0.z; Cv[3]=qc0.w;
      Cv[4]=qc1.x; Cv[5]=qc1.y; Cv[6]=qc1.z; Cv[7]=qc1.w;
      Cv[8]=qc2.x; Cv[9]=qc2.y; Cv[10]=qc2.z; Cv[11]=qc2.w;
      Cv[12]=qc3.x; Cv[13]=qc3.y; Cv[14]=qc3.z; Cv[15]=qc3.w;
      int v = scan_voxel(k, l);
      float u = bfu2f(xcb[(size_t)v * cDI]);
      float dtu = dt * u;
      float y = Dsd * u;
#pragma unroll
      for (int n = 0; n < cN; ++n) {
        float a = exp2f(dt * ac[n]);
        h[n] = h[n] * a + dtu * Bv[n];
        P[n] *= a;
        y += h[n] * Cv[n];
      }
      ysrow[(size_t)st * cDI] = (unsigned short)f2bf(y);
    }
#pragma unroll
    for (int n = 0; n < cN; ++n) {
      hend[so + n] = (unsigned short)f2bf(h[n]);
      pend[so + n] = (unsigned short)f2bf(P[n]);
    }
  }
}

// ---------- scan pass 2 (serial prefix over segments; fp32 recurrence, bf16 storage) ----------
__global__ void __launch_bounds__(256) scan2_kernel(
    unsigned short* __restrict__ hend, const unsigned short* __restrict__ pend) {
  int tid = blockIdx.x * 256 + threadIdx.x;
  int bk = tid / (cDI * cN); int r = tid - bk * (cDI * cN);
  float g = 0.f;
  for (int s = 0; s < SEG; ++s) {
    size_t o = ((size_t)(bk * SEG + s) * cDI * cN) + r;
    float he = bfu2f(hend[o]), pe = bfu2f(pend[o]);
    hend[o] = (unsigned short)f2bf(g);
    g = pe * g + he;
  }
}

// ---------- scan pass 3 (owned read-add-store; packed fp32) ----------
__global__ void __launch_bounds__(128, 3) scan3_kernel(
    const float* __restrict__ xdbl,
    const void* __restrict__ dtw, const void* __restrict__ dtbv,
    const void* __restrict__ alog, const int* __restrict__ flg,
    const unsigned short* __restrict__ hin,
    unsigned short* __restrict__ ys0, unsigned short* __restrict__ ys1,
    unsigned short* __restrict__ ys2, unsigned short* __restrict__ ys3) {
  int bks = blockIdx.y;
  int s = bks & (SEG - 1);
  if (s == 0) return;
  __shared__ float rows[SEGLEN * XSTR];
  int pf = flg[1];
  int tid = threadIdx.x;
  int d = blockIdx.x * 128 + tid;
  int bk = bks / SEG; int k = bk & 3; int b = bk >> 2;
  int l0 = s * SEGLEN;
  {
    const float4* src = (const float4*)(xdbl + ((size_t)bk * cL + l0) * XSTR);
    float4* dst = (float4*)rows;
#pragma unroll
    for (int i = 0; i < (SEGLEN * XSTR / 4) / 128; ++i)
      dst[tid + i * 128] = src[tid + i * 128];
  }
  float wdt[cDTR];
#pragma unroll
  for (int r = 0; r < cDTR; ++r) wdt[r] = ldsel(dtw, (size_t)(k * cDI + d) * cDTR + r, pf);
  f32x2 wp[6];
#pragma unroll
  for (int r = 0; r < 6; ++r) wp[r] = mk2(wdt[2 * r], wdt[2 * r + 1]);
  float dtb = ldsel(dtbv, k * cDI + d, pf);
  float ac[cN];
#pragma unroll
  for (int n = 0; n < cN; ++n)
    ac[n] = -__expf(ldsel(alog, (size_t)(k * cDI + d) * cN + n, pf)) * 1.4426950408889634f;
  bool fast = true;
#pragma unroll
  for (int n = 1; n < cN; ++n)
    fast = fast && (fabsf(ac[n] - (float)(n + 1) * ac[0]) <= 1e-3f * fabsf(ac[n]));
  size_t so = ((size_t)bks * cDI + d) * cN;
  unsigned short* ysk = (k == 0) ? ys0 : (k == 1) ? ys1 : (k == 2) ? ys2 : ys3;
  unsigned short* ysrow = ysk + ((size_t)b * cL + l0) * cDI + d;
  __syncthreads();
  if (fast) {
    float ac0 = ac[0];
    f32x2 g2[8];
#pragma unroll
    for (int i = 0; i < 8; ++i)
      g2[i] = mk2(bfu2f(hin[so + 2*i]), bfu2f(hin[so + 2*i + 1]));
    Row7 qa = ldrow7(rows, 0);
    for (int st = 0; st < SEGLEN; st += 2) {
      Row7 qb = ldrow7(rows, st + 1);
      int p2 = (st + 2 < SEGLEN) ? st + 2 : SEGLEN - 1;
      float ya = s3step(qa, wp, dtb, ac0, g2);
      size_t ia = (size_t)st * cDI;
      ysrow[ia] = (unsigned short)f2bf(bfu2f(ysrow[ia]) + ya);
      qa = ldrow7(rows, p2);
      float yb = s3step(qb, wp, dtb, ac0, g2);
      size_t ib = (size_t)(st + 1) * cDI;
      ysrow[ib] = (unsigned short)f2bf(bfu2f(ysrow[ib]) + yb);
    }
  } else {
    float g[cN];
#pragma unroll
    for (int n = 0; n < cN; ++n) g[n] = bfu2f(hin[so + n]);
    for (int st = 0; st < SEGLEN; ++st) {
      const float4* rp = (const float4*)(rows + st * XSTR);
      float4 q0 = rp[0], q1 = rp[1], q2 = rp[2];
      float s0 = dtb + q0.x*wdt[0] + q0.z*wdt[2] + q1.x*wdt[4] + q1.z*wdt[6] + q2.x*wdt[8] + q2.z*wdt[10];
      float s1 = q0.y*wdt[1] + q0.w*wdt[3] + q1.y*wdt[5] + q1.w*wdt[7] + q2.y*wdt[9] + q2.w*wdt[11];
      float dt = softplusf(s0 + s1);
      float Cv[cN];
      float4 qc0 = rp[7], qc1 = rp[8], qc2 = rp[9], qc3 = rp[10];
      Cv[0]=qc0.x; Cv[1]=qc0.y; Cv[2]=qc0.z; Cv[3]=qc0.w;
      Cv[4]=qc1.x; Cv[5]=qc1.y; Cv[6]=qc1.z; Cv[7]=qc1.w;
      Cv[8]=qc2.x; Cv[9]=qc2.y; Cv[10]=qc2.z; Cv[11]=qc2.w;
      Cv[12]=qc3.x; Cv[13]=qc3.y; Cv[14]=qc3.z; Cv[15]=qc3.w;
      float y = 0.f;
#pragma unroll
      for (int n = 0; n < cN; ++n) {
        float a = exp2f(dt * ac[n]);
        g[n] *= a;
        y += g[n] * Cv[n];
      }
      size_t ii = (size_t)st * cDI;
      ysrow[ii] = (unsigned short)f2bf(bfu2f(ysrow[ii]) + y);
    }
  }
}

// ---------- merge: wave-per-row gather of 4 dirs + out_norm LN + silu(z) gate ----------
__global__ void __launch_bounds__(256) merge_kernel(
    const unsigned short* __restrict__ ys0, const unsigned short* __restrict__ ys1,
    const unsigned short* __restrict__ ys2, const unsigned short* __restrict__ ys3,
    const unsigned short* __restrict__ zh,
    const void* __restrict__ ong, const void* __restrict__ onb,
    const int* __restrict__ flg, unsigned short* __restrict__ yg) {
  int pf = flg[1];
  int bv = blockIdx.x * 4 + (threadIdx.x >> 6);
  int lane = threadIdx.x & 63;
  int v = bv & (cL - 1); int b = bv >> 13;
  int t = v >> 10, q = v & 1023, hh = q >> 5, ww = q & 31;
  int l1 = (t << 10) + (ww << 5) + hh;
  size_t r0 = ((size_t)b * cL + v) * cDI;
  size_t r1 = ((size_t)b * cL + l1) * cDI;
  size_t r2 = ((size_t)b * cL + (cL - 1 - v)) * cDI;
  size_t r3 = ((size_t)b * cL + (cL - 1 - l1)) * cDI;
  float vals[6]; float s1 = 0.f, s2 = 0.f;
#pragma unroll
  for (int i = 0; i < 6; ++i) {
    int d = lane + i * 64;
    float x = bfu2f(ys0[r0 + d]) + bfu2f(ys1[r1 + d]) +
              bfu2f(ys2[r2 + d]) + bfu2f(ys3[r3 + d]);
    vals[i] = x; s1 += x; s2 += x * x;
  }
#pragma unroll
  for (int off = 32; off > 0; off >>= 1) {
    s1 += __shfl_xor(s1, off);
    s2 += __shfl_xor(s2, off);
  }
  float mean = s1 * (1.f / cDI);
  float var = s2 * (1.f / cDI) - mean * mean;
  float rstd = rsqrtf(var + 1e-6f);
  const unsigned short* zr = zh + (size_t)bv * cDI;
  unsigned short* og = yg + (size_t)bv * cDI;
#pragma unroll
  for (int i = 0; i < 6; ++i) {
    int d = lane + i * 64;
    float xn = (vals[i] - mean) * rstd * ldsel(ong, d, pf) + ldsel(onb, d, pf);
    og[d] = (unsigned short)f2bf(xn * siluf(bfu2f(zr[d])));
  }
}

}  // namespace

extern "C" void kernel_launch(void* const* d_in, const int* in_sizes, int n_in,
                              void* d_out, int out_size, void* d_ws, size_t ws_size,
                              hipStream_t stream) {
  (void)in_sizes; (void)n_in; (void)out_size; (void)ws_size;
  const void* x    = d_in[0];
  const void* text = d_in[1];
  const void* c1w  = d_in[2];
  const void* c1b  = d_in[3];
  const void* c2w  = d_in[4];
  const void* c2b  = d_in[5];
  const void* n1g  = d_in[6];
  const void* n1b  = d_in[7];
  const void* n2g  = d_in[8];
  const void* n2b  = d_in[9];
  const void* ipw  = d_in[10];
  const void* ipb  = d_in[11];
  const void* tpw  = d_in[12];
  const void* tpb  = d_in[13];
  const void* cvw  = d_in[14];
  const void* cvb  = d_in[15];
  const void* xpw  = d_in[16];
  const void* dtw  = d_in[17];
  const void* dtb  = d_in[18];
  const void* alog = d_in[19];
  const void* dsv  = d_in[20];
  const void* ong  = d_in[21];
  const void* onb  = d_in[22];
  const void* opw  = d_in[23];
  const void* f1w  = d_in[24];
  const void* f1b  = d_in[25];
  const void* f2w  = d_in[26];
  const void* f2b  = d_in[27];

  float* Wf = (float*)d_ws;

  // ---- slot arena (~125.9 MB), atomic-free scan + bf16 activations ----
  constexpr size_t oC  = 0;                              // 6,291,456
  constexpr size_t oD  = 6291456;                        // 3,145,728
  constexpr size_t oG  = 9437184;                        // 3,145,728
  constexpr size_t oA  = 12582912;                       // 6,291,456
  constexpr size_t oB  = 18874368;                       // 6,291,456
  constexpr size_t oE  = 25165824;                       // 3,145,728
  constexpr size_t oF  = 28311552;                       // 3,145,728
  constexpr size_t oCO = 31457280;                       // 768 (cond)
  constexpr size_t oFL = 31458048;                       // 4 ints (flags)
  constexpr size_t oWCV = 31458052;                      // 27*384
  constexpr size_t oBCV = 31468420;                      // 384
  constexpr size_t oW1  = 31468804;                      // 27*192
  constexpr size_t oB1  = 31473988;                      // 192
  constexpr size_t oW2  = 31474180;                      // 5184
  constexpr size_t oB2  = 31479364;                      // 192 -> end 31479556
  unsigned short* xch = (unsigned short*)(Wf + oC);            // bf16 silu(dwconv)
  unsigned short* ysd2 = (unsigned short*)(Wf + oC + 3145728); // ystream dir 2
  unsigned short* hbufh = (unsigned short*)(Wf + oC);          // fc1 out bf16
  float* xdbl = Wf + oD;
  unsigned short* ygh  = (unsigned short*)(Wf + oD);           // yg bf16 (after xdbl dead)
  unsigned short* xnh  = (unsigned short*)(Wf + oG);           // LN1 out bf16
  unsigned short* pendp = (unsigned short*)(Wf + oG);          // bf16, after xnh dead
  unsigned short* xib  = (unsigned short*)(Wf + oA);           // in_proj x-half bf16
  unsigned short* ysd0 = (unsigned short*)(Wf + oA);           // ystream dir 0 (xib dead)
  unsigned short* ysd1 = (unsigned short*)(Wf + oA + 3145728); // ystream dir 1
  float* x2   = Wf + oA;   // out_proj output (after ystream dead)
  unsigned short* zh   = (unsigned short*)(Wf + oB);           // z bf16
  unsigned short* ysd3 = (unsigned short*)(Wf + oB + 3145728); // ystream dir 3
  float* x3   = Wf + oB;
  float* x1   = Wf + oE;
  unsigned short* hendp = (unsigned short*)(Wf + oF);          // bf16
  unsigned short* xn2h = (unsigned short*)(Wf + oF);           // LN2 out bf16 (hend dead)
  float* cond = Wf + oCO;
  int*   flg  = (int*)(Wf + oFL);
  float* wcv = Wf + oWCV; float* bcv = Wf + oBCV;
  float* w1t = Wf + oW1;  float* b1t = Wf + oB1;
  float* w2t = Wf + oW2;  float* b2t = Wf + oB2;

  const int cpeBlocks = (cBL * cC / 16) / 256;    // 768 (2x2 voxels/thread)
  const int dwBlocks  = (cBL * cDI / 16) / 256;   // 1536 (2x2 voxels/thread)

  // 0. dtype detection + conv weight prep
  hipLaunchKernelGGL(detect_kernel, dim3(1), dim3(256), 0, stream,
                     (const unsigned short*)x, (const unsigned short*)ipw, flg);
  hipLaunchKernelGGL(prep_kernel, dim3(85), dim3(256), 0, stream,
                     cvw, cvb, c1w, c1b, c2w, c2b, flg, wcv, bcv, w1t, b1t, w2t, b2t);
  // 1. x1 = x + cpe1(x)
  hipLaunchKernelGGL(cpe_kernel, dim3(cpeBlocks), dim3(256), 0, stream,
                     x, w1t, b1t, flg, 0, x1);
  // 2. xnh = bf16(LN1(x1))  (wave-per-row, no barriers)
  hipLaunchKernelGGL(lnb_kernel, dim3(cBL / 4), dim3(256), 0, stream, x1, n1g, n1b, flg, xnh);
  // 3. cond
  hipLaunchKernelGGL(text_cond_kernel, dim3(cB), dim3(384), 0, stream, text, tpw, tpb, flg, cond);
  // 4. in_proj (MFMA BK=64, BN=128): xnh -> xib bf16 (+cond), zh bf16
  hipLaunchKernelGGL((gemm_mfma_kernel<0, 128>), dim3(2 * cDI / 128, cBL / 128), dim3(256), 0, stream,
                     xnh, ipw, 2 * cDI, cC, ipb, flg, cond, (float*)xib, zh);
  // 5. xch = bf16(silu(dwconv(xib)))
  hipLaunchKernelGGL(dwconv_silu_kernel, dim3(dwBlocks), dim3(256), 0, stream,
                     xib, wcv, bcv, xch);
  // 6. x_proj (MFMA BK=64, scatter to padded scan rows)
  hipLaunchKernelGGL((gemm_mfma_kernel<1, 64>), dim3((cK * XROW + 63) / 64, cBL / 128), dim3(256), 0, stream,
                     xch, xpw, cK * XROW, cDI, (const void*)nullptr, flg,
                     (const float*)nullptr, xdbl, (unsigned short*)nullptr);
  // 7-9. chunked selective scan (packed fp32 inner loops)
  hipLaunchKernelGGL(scan1_kernel, dim3(cDI / 128, cB * cK * SEG), dim3(128), 0, stream,
                     xch, xdbl, dtw, dtb, alog, dsv, flg,
                     ysd0, ysd1, ysd2, ysd3, hendp, pendp);
  hipLaunchKernelGGL(scan2_kernel, dim3(cB * cK * cDI * cN / 256), dim3(256), 0, stream,
                     hendp, pendp);
  hipLaunchKernelGGL(scan3_kernel, dim3(cDI / 128, cB * cK * SEG), dim3(128), 0, stream,
                     xdbl, dtw, dtb, alog, flg, hendp, ysd0, ysd1, ysd2, ysd3);
  // 10. merge: wave-per-row gather + out_norm + gate -> yg bf16
  hipLaunchKernelGGL(merge_kernel, dim3(cBL / 4), dim3(256), 0, stream,
                     ysd0, ysd1, ysd2, ysd3, zh, ong, onb, flg, ygh);
  // 11. out_proj (MFMA BK=64) + residual(x1) -> x2 fp32
  hipLaunchKernelGGL((gemm_mfma_kernel<2, 64>), dim3(cC / 64, cBL / 128), dim3(256), 0, stream,
                     ygh, opw, cC, cDI, (const void*)nullptr, flg, x1, x2,
                     (unsigned short*)nullptr);
  // 12. x3 = x2 + cpe2(x2)  (flg[2]=1 -> fp32 input path)
  hipLaunchKernelGGL(cpe_kernel, dim3(cpeBlocks), dim3(256), 0, stream,
                     x2, w2t, b2t, flg, 2, x3);
  // 13. xn2h = bf16(LN2(x3))
  hipLaunchKernelGGL(lnb_kernel, dim3(cBL / 4), dim3(256), 0, stream, x3, n2g, n2b, flg, xn2h);
  // 14. fc1 + gelu -> hbufh bf16 (MFMA BK=64, BN=128)
  hipLaunchKernelGGL((gemm_mfma_kernel<3, 128>), dim3(cHID / 128, cBL / 128), dim3(256), 0, stream,
                     xn2h, f1w, cHID, cC, f1b, flg, (const float*)nullptr, (float*)hbufh,
                     (unsigned short*)nullptr);
  // 15. fc2 + bias + residual(x3) -> d_out fp32 (MFMA BK=64)
  hipLaunchKernelGGL((gemm_mfma_kernel<4, 64>), dim3(cC / 64, cBL / 128), dim3(256), 0, stream,
                     hbufh, f2w, cC, cHID, f2b, flg, x3, (float*)d_out,
                     (unsigned short*)nullptr);
}